// Round 8
// baseline (1647.192 us; speedup 1.0000x reference)
//
#include <hip/hip_runtime.h>
#include <hip/hip_bf16.h>
#include <math.h>

typedef __attribute__((ext_vector_type(4))) float f32x4;
typedef __attribute__((ext_vector_type(8))) short s16x8;

#define MAXD 192  // fast-path degree cap for fused softmax (LDS alpha buffer)

// ---------------- CSR-by-dst construction ----------------

__global__ void zero2_kernel(int* __restrict__ a, int* __restrict__ b, int n) {
    int i = blockIdx.x * blockDim.x + threadIdx.x;
    if (i < n) { a[i] = 0; b[i] = 0; }
}

__global__ void hist_kernel(const int* __restrict__ dst, int* __restrict__ counts, int E) {
    int e = blockIdx.x * blockDim.x + threadIdx.x;
    if (e < E) atomicAdd(&counts[dst[e]], 1);
}

#define SCAN_T 1024
__global__ __launch_bounds__(SCAN_T) void scan_kernel(const int* __restrict__ counts,
                                                      int* __restrict__ row_ofs, int Nn) {
    __shared__ int part[SCAN_T];
    int tid = threadIdx.x;
    int chunk = Nn / SCAN_T;
    int base = tid * chunk;
    int sum = 0;
    for (int i = 0; i < chunk; ++i) sum += counts[base + i];
    part[tid] = sum;
    __syncthreads();
    for (int off = 1; off < SCAN_T; off <<= 1) {
        int v = part[tid];
        int u = (tid >= off) ? part[tid - off] : 0;
        __syncthreads();
        part[tid] = v + u;
        __syncthreads();
    }
    if (tid == SCAN_T - 1) row_ofs[Nn] = part[tid];
    int acc = part[tid] - sum;  // exclusive prefix
    for (int i = 0; i < chunk; ++i) { row_ofs[base + i] = acc; acc += counts[base + i]; }
}

__global__ void scatter_kernel(const int* __restrict__ dst, const int* __restrict__ row_ofs,
                               int* __restrict__ cursor, int* __restrict__ perm, int E) {
    int e = blockIdx.x * blockDim.x + threadIdx.x;
    if (e < E) {
        int d = dst[e];
        int pos = atomicAdd(&cursor[d], 1);
        perm[row_ofs[d] + pos] = e;
    }
}

// ---------------- helpers ----------------
__device__ inline unsigned short bf16_bits(float f) {
    __hip_bfloat16 b = __float2bfloat16(f);
    return *reinterpret_cast<unsigned short*>(&b);
}
__device__ inline float bfu(unsigned short u) {
    return __uint_as_float(((unsigned)u) << 16);
}

// ---------------- w_as/w_ad precompute ----------------
__global__ void wvec_kernel(const float* __restrict__ W, const float* __restrict__ a_s,
                            const float* __restrict__ a_d, float* __restrict__ w_as,
                            float* __restrict__ w_ad, int DIN, int H, int C) {
    int gid = blockIdx.x * blockDim.x + threadIdx.x;
    int wid = gid >> 6;
    int lane = threadIdx.x & 63;
    if (wid >= H * DIN) return;
    int h = wid / DIN, i = wid % DIN;
    const float* wp = W + (size_t)i * H * C + (size_t)h * C;
    const float* sp = a_s + (size_t)h * C;
    const float* dp = a_d + (size_t)h * C;
    float ss = 0.f, sd = 0.f;
    for (int c = lane; c < C; c += 64) {
        float v = wp[c];
        ss += v * sp[c];
        sd += v * dp[c];
    }
    #pragma unroll
    for (int off = 32; off > 0; off >>= 1) {
        ss += __shfl_down(ss, off, 64);
        sd += __shfl_down(sd, off, 64);
    }
    if (lane == 0) { w_as[wid] = ss; w_ad[wid] = sd; }
}

// ---------------- layer-1 alpha dots + xb4 emission; one wave per node ----------------
__global__ __launch_bounds__(256) void alpha16_kernel(const float4* __restrict__ x4,
                                                      const float* __restrict__ wv,
                                                      float* __restrict__ as_out,
                                                      float* __restrict__ ad_out,
                                                      ushort4* __restrict__ xb4) {
    __shared__ float ws[16 * 768];
    int tid = threadIdx.x;
    #pragma unroll
    for (int i = 0; i < 12; ++i)
        ((float4*)ws)[tid + i * 256] = ((const float4*)wv)[tid + i * 256];
    __syncthreads();
    int wvid = tid >> 6, lane = tid & 63;
    int n = blockIdx.x * 4 + wvid;
    float4 xr[3];
    #pragma unroll
    for (int r = 0; r < 3; ++r) xr[r] = x4[(size_t)n * 192 + lane + 64 * r];
    // emit bf16 copy of x (saves a separate conversion pass)
    #pragma unroll
    for (int r = 0; r < 3; ++r) {
        ushort4 o;
        o.x = bf16_bits(xr[r].x); o.y = bf16_bits(xr[r].y);
        o.z = bf16_bits(xr[r].z); o.w = bf16_bits(xr[r].w);
        xb4[(size_t)n * 192 + lane + 64 * r] = o;
    }
    #pragma unroll
    for (int j = 0; j < 16; ++j) {
        const float4* wj = (const float4*)(ws + j * 768);
        float s = 0.f;
        #pragma unroll
        for (int r = 0; r < 3; ++r) {
            float4 wc = wj[lane + 64 * r];
            s += xr[r].x * wc.x + xr[r].y * wc.y + xr[r].z * wc.z + xr[r].w * wc.w;
        }
        #pragma unroll
        for (int off = 32; off > 0; off >>= 1) s += __shfl_down(s, off, 64);
        if (lane == 0) {
            if (j < 8) as_out[n * 8 + j] = s;
            else       ad_out[n * 8 + (j - 8)] = s;
        }
    }
}

// ---------------- FUSED: per-node softmax (8 heads) + 8-head aggregation -> zAB bf16 ----------------
__global__ __launch_bounds__(192) void agg8_fused_kernel(
    const ushort4* __restrict__ xb4,  // [N][192] bf16 x (gather-halved)
    const float* __restrict__ as1,    // [N][8]
    const float* __restrict__ ad1,    // [N][8]
    const int* __restrict__ src,
    const int* __restrict__ row_ofs,
    const int* __restrict__ perm,
    float* __restrict__ e1g,          // [E][8] global fallback alpha
    __hip_bfloat16* __restrict__ zAB, // [N][8*768]
    int D4) {
    __shared__ float alds[MAXD * 8];
    __shared__ float mh[8], dh[8];
    int n = blockIdx.x;
    int s = row_ofs[n], t = row_ofs[n + 1];
    int d = t - s;
    int tid = threadIdx.x;
    bool big = d > MAXD;
    if (!big) {
        int eh = tid & 7, ei = tid >> 3;  // ei in 0..23
        float adn = ad1[n * 8 + eh];
        for (int base = 0; base < d; base += 24) {
            int j = base + ei;
            if (j < d) {
                int e = perm[s + j];
                float v = as1[src[e] * 8 + eh] + adn;
                v = v > 0.f ? v : 0.2f * v;
                alds[j * 8 + eh] = v;
            }
        }
        __syncthreads();
        if (tid < 8) {
            float m = -INFINITY;
            for (int j = 0; j < d; ++j) m = fmaxf(m, alds[j * 8 + tid]);
            float den = 0.f;
            for (int j = 0; j < d; ++j) den += __expf(alds[j * 8 + tid] - m);
            mh[tid] = m; dh[tid] = 1.f / (den + 1e-16f);
        }
        __syncthreads();
        for (int base = 0; base < d; base += 24) {
            int j = base + ei;
            if (j < d) alds[j * 8 + eh] = __expf(alds[j * 8 + eh] - mh[eh]) * dh[eh];
        }
        __syncthreads();
    } else {
        if (tid < 8) {
            int hh = tid;
            float adn = ad1[n * 8 + hh];
            float m = -INFINITY;
            for (int j = s; j < t; ++j) {
                float v = as1[src[perm[j]] * 8 + hh] + adn;
                v = v > 0.f ? v : 0.2f * v;
                m = fmaxf(m, v);
            }
            float den = 0.f;
            for (int j = s; j < t; ++j) {
                float v = as1[src[perm[j]] * 8 + hh] + adn;
                v = v > 0.f ? v : 0.2f * v;
                den += __expf(v - m);
            }
            float inv = 1.f / (den + 1e-16f);
            for (int j = s; j < t; ++j) {
                int e = perm[j];
                float v = as1[src[e] * 8 + hh] + adn;
                v = v > 0.f ? v : 0.2f * v;
                e1g[(size_t)e * 8 + hh] = __expf(v - m) * inv;
            }
        }
        __syncthreads();
    }

    // aggregation: thread j handles bf16x4 column j for all 8 heads
    int j = tid;
    float4 acc[8];
    #pragma unroll
    for (int h = 0; h < 8; ++h) acc[h] = make_float4(0.f, 0.f, 0.f, 0.f);
    int k = s;
    for (; k + 1 < t; k += 2) {
        int e0 = perm[k], e1 = perm[k + 1];
        ushort4 u0 = xb4[(size_t)src[e0] * D4 + j];
        ushort4 u1 = xb4[(size_t)src[e1] * D4 + j];
        float4 v0 = make_float4(bfu(u0.x), bfu(u0.y), bfu(u0.z), bfu(u0.w));
        float4 v1 = make_float4(bfu(u1.x), bfu(u1.y), bfu(u1.z), bfu(u1.w));
        const float* a0 = big ? &e1g[(size_t)e0 * 8] : &alds[(k - s) * 8];
        const float* a1 = big ? &e1g[(size_t)e1 * 8] : &alds[(k + 1 - s) * 8];
        #pragma unroll
        for (int h = 0; h < 8; ++h) {
            float a = a0[h], b = a1[h];
            acc[h].x += a * v0.x + b * v1.x;
            acc[h].y += a * v0.y + b * v1.y;
            acc[h].z += a * v0.z + b * v1.z;
            acc[h].w += a * v0.w + b * v1.w;
        }
    }
    if (k < t) {
        int e0 = perm[k];
        ushort4 u0 = xb4[(size_t)src[e0] * D4 + j];
        float4 v0 = make_float4(bfu(u0.x), bfu(u0.y), bfu(u0.z), bfu(u0.w));
        const float* a0 = big ? &e1g[(size_t)e0 * 8] : &alds[(k - s) * 8];
        #pragma unroll
        for (int h = 0; h < 8; ++h) {
            float a = a0[h];
            acc[h].x += a * v0.x; acc[h].y += a * v0.y;
            acc[h].z += a * v0.z; acc[h].w += a * v0.w;
        }
    }
    int D = D4 * 4;
    #pragma unroll
    for (int h = 0; h < 8; ++h) {
        size_t o = (size_t)n * 8 * D + (size_t)h * D + j * 4;
        ushort4 st;
        st.x = bf16_bits(acc[h].x); st.y = bf16_bits(acc[h].y);
        st.z = bf16_bits(acc[h].z); st.w = bf16_bits(acc[h].w);
        *reinterpret_cast<ushort4*>(&zAB[o]) = st;
    }
}

// ---------------- FUSED: layer-2 softmax (H=1) + output aggregation (+bias) ----------------
__global__ __launch_bounds__(192) void out_fused_kernel(
    const ushort4* __restrict__ featb,  // h2b [N][192] bf16 (gather-halved)
    const float* __restrict__ as2,      // [N]
    const float* __restrict__ ad2,      // [N]
    const int* __restrict__ src,
    const int* __restrict__ row_ofs,
    const int* __restrict__ perm,
    float* __restrict__ e2g,            // [E] global fallback alpha
    const float4* __restrict__ bias4,
    float4* __restrict__ out4, int D4) {
    __shared__ float alds[MAXD];
    __shared__ float minv[2];
    int n = blockIdx.x;
    int s = row_ofs[n], t = row_ofs[n + 1];
    int d = t - s;
    int tid = threadIdx.x;
    bool big = d > MAXD;
    if (!big) {
        float adn = ad2[n];
        if (tid < d) {
            float v = as2[src[perm[s + tid]]] + adn;
            v = v > 0.f ? v : 0.2f * v;
            alds[tid] = v;
        }
        __syncthreads();
        if (tid == 0) {
            float m = -INFINITY;
            for (int j = 0; j < d; ++j) m = fmaxf(m, alds[j]);
            float den = 0.f;
            for (int j = 0; j < d; ++j) den += __expf(alds[j] - m);
            minv[0] = m; minv[1] = 1.f / (den + 1e-16f);
        }
        __syncthreads();
        if (tid < d) alds[tid] = __expf(alds[tid] - minv[0]) * minv[1];
        __syncthreads();
    } else {
        if (tid == 0) {
            float adn = ad2[n];
            float m = -INFINITY;
            for (int j = s; j < t; ++j) {
                float v = as2[src[perm[j]]] + adn;
                v = v > 0.f ? v : 0.2f * v;
                m = fmaxf(m, v);
            }
            float den = 0.f;
            for (int j = s; j < t; ++j) {
                float v = as2[src[perm[j]]] + adn;
                v = v > 0.f ? v : 0.2f * v;
                den += __expf(v - m);
            }
            float inv = 1.f / (den + 1e-16f);
            for (int j = s; j < t; ++j) {
                int e = perm[j];
                float v = as2[src[e]] + adn;
                v = v > 0.f ? v : 0.2f * v;
                e2g[e] = __expf(v - m) * inv;
            }
        }
        __syncthreads();
    }

    int j = tid;
    float4 acc = make_float4(0.f, 0.f, 0.f, 0.f);
    int k = s;
    for (; k + 1 < t; k += 2) {
        int e0 = perm[k], e1 = perm[k + 1];
        float a = big ? e2g[e0] : alds[k - s];
        float b = big ? e2g[e1] : alds[k + 1 - s];
        ushort4 u0 = featb[(size_t)src[e0] * D4 + j];
        ushort4 u1 = featb[(size_t)src[e1] * D4 + j];
        acc.x += a * bfu(u0.x) + b * bfu(u1.x);
        acc.y += a * bfu(u0.y) + b * bfu(u1.y);
        acc.z += a * bfu(u0.z) + b * bfu(u1.z);
        acc.w += a * bfu(u0.w) + b * bfu(u1.w);
    }
    if (k < t) {
        int e0 = perm[k];
        float a = big ? e2g[e0] : alds[k - s];
        ushort4 u0 = featb[(size_t)src[e0] * D4 + j];
        acc.x += a * bfu(u0.x); acc.y += a * bfu(u0.y);
        acc.z += a * bfu(u0.z); acc.w += a * bfu(u0.w);
    }
    float4 b = bias4[j];
    acc.x += b.x; acc.y += b.y; acc.z += b.z; acc.w += b.w;
    out4[(size_t)n * D4 + j] = acc;
}

// ---------------- transpose + fp32->bf16 ----------------
__global__ void transpose_bf16_kernel(const float* __restrict__ src, __hip_bfloat16* __restrict__ dst,
                                      int R, int Cc) {
    __shared__ float tile[32][33];
    int bx = blockIdx.x * 32;
    int by = blockIdx.y * 32;
    int tx = threadIdx.x, ty = threadIdx.y;  // 32 x 8
    #pragma unroll
    for (int i = 0; i < 32; i += 8)
        tile[ty + i][tx] = src[(size_t)(by + ty + i) * Cc + (bx + tx)];
    __syncthreads();
    #pragma unroll
    for (int i = 0; i < 32; i += 8)
        dst[(size_t)(bx + ty + i) * R + (by + tx)] = __float2bfloat16(tile[tx][ty + i]);
}

// ---------------- fused: h2 = p0+p1 (split-K S=2) -> bf16; as2/ad2 = h2 . a_s2 / a_d2 ----------------
__global__ __launch_bounds__(192) void reduce_dot_kernel(
    const float4* __restrict__ parts,  // [2][N][192]
    const float4* __restrict__ as_w, const float4* __restrict__ ad_w,
    ushort4* __restrict__ h2b,         // [N][192] bf16 out
    float* __restrict__ as_out, float* __restrict__ ad_out, int NC4) {
    int n = blockIdx.x;
    int j = threadIdx.x;
    size_t idx = (size_t)n * 192 + j;
    float4 a = parts[idx];
    float4 p1 = parts[(size_t)NC4 + idx];
    a.x += p1.x; a.y += p1.y; a.z += p1.z; a.w += p1.w;
    ushort4 st;
    st.x = bf16_bits(a.x); st.y = bf16_bits(a.y);
    st.z = bf16_bits(a.z); st.w = bf16_bits(a.w);
    h2b[idx] = st;
    float4 ws = as_w[j], wd = ad_w[j];
    float ss = a.x * ws.x + a.y * ws.y + a.z * ws.z + a.w * ws.w;
    float sd = a.x * wd.x + a.y * wd.y + a.z * wd.z + a.w * wd.w;
    #pragma unroll
    for (int off = 32; off > 0; off >>= 1) {
        ss += __shfl_down(ss, off, 64);
        sd += __shfl_down(sd, off, 64);
    }
    __shared__ float red_s[3], red_d[3];
    int wv = j >> 6, lane = j & 63;
    if (lane == 0) { red_s[wv] = ss; red_d[wv] = sd; }
    __syncthreads();
    if (j == 0) {
        as_out[n] = red_s[0] + red_s[1] + red_s[2];
        ad_out[n] = red_d[0] + red_d[1] + red_d[2];
    }
}

// ---------------- shared GEMM machinery ----------------
__device__ inline void gload_lds16(const void* g, void* l) {
    __builtin_amdgcn_global_load_lds((const __attribute__((address_space(1))) unsigned int*)g,
                                     (__attribute__((address_space(3))) unsigned int*)l, 16, 0, 0);
}

#define FENCE() asm volatile("" ::: "memory")
#define BAR() do { FENCE(); __builtin_amdgcn_s_barrier(); FENCE(); } while (0)
#define WAIT_LGKM() asm volatile("s_waitcnt lgkmcnt(0)" ::: "memory")
#define WAIT_VM0() asm volatile("s_waitcnt vmcnt(0)" ::: "memory")

// ---------------- GEMM1: 256M x 768N FULL-N tile per head, K=768, single-buffered ----------------
// Per head: o1_h[8192,768] = ELU(zAB_h[8192,768] @ W1T_h[768,768]^T + b1_h).
// Grid = 32 M-tiles x 8 heads = 256 blocks = EXACTLY one full-machine round.
// 1024 threads = 16 waves (4M x 4N); wave tile 64 x 192 (acc 4x12 f32x4 = 192 regs).
// LDS single buffer: A[256][64] (32 KB) + B[768][64] (96 KB) = 128 KiB.
// Rationale: all gemm256 variants sit at staged-bytes/5.6 TB/s (feed-bound). Full-N cuts
// staged bytes 590 -> 393 MB (A staged ONCE; B panel 1.18 MB/head is L2-resident).
// Sync per tile: compute(t) -> BAR -> stage(t+1) -> vmcnt(0) -> BAR  (single buffer, race-free:
// all reads of t retired before BAR since MFMAs consumed them; stage lands before next BAR).
// Swizzle identical to proven BK=64 scheme: LDS(row,cp) = global(row, cp^(row&7)); read
// csw = (logical ^ (ml&7)) — read rows are base+ml with base%16==0 so row&7 == ml&7. 0 conflicts.
#define STAGE768(kt) do { \
    gload_lds16(gA0 + (size_t)(kt) * 64, dA); \
    gload_lds16(gA0 + (size_t)128 * lda + (size_t)(kt) * 64, dA + 8192); \
    _Pragma("unroll") for (int q = 0; q < 6; ++q) \
        gload_lds16(gB0 + (size_t)(q * 128) * ldb + (size_t)(kt) * 64, dB + q * 8192); \
} while (0)

__global__ __launch_bounds__(1024, 1) void gemm768_kernel(
    const __hip_bfloat16* __restrict__ A,   // zAB [8192][6144]
    const __hip_bfloat16* __restrict__ BT,  // W1T [6144][768]
    int lda, int ldb, int ldc,
    const float* __restrict__ bias,         // b1 [6144]
    __hip_bfloat16* __restrict__ Cb,        // o1 [8192][6144]
    long bsA, long bsBT, long bsC, long bsBias) {
    extern __shared__ __align__(16) short lds[];
    short* Asb = lds;            // [256][64] = 16384 shorts = 32 KiB
    short* Bsb = lds + 16384;    // [768][64] = 49152 shorts = 96 KiB

    int lin = blockIdx.x;
    int by = lin & 31;
    int bz = lin >> 5;           // head

    A    += (size_t)bz * bsA;
    BT   += (size_t)bz * bsBT;
    Cb   += (size_t)bz * bsC;
    bias += (size_t)bz * bsBias;

    int tid = threadIdx.x;
    int lane = tid & 63;
    int wid = tid >> 6;     // 0..15
    int wm = wid >> 2;      // 0..3 (M quarter, 64 rows)
    int wn = wid & 3;       // 0..3 (N slice, 192 cols)
    int ml = lane & 15;
    int g  = lane >> 4;     // 0..3

    int row0 = by * 256;

    // staging: 1024 threads, 16B each; A 2 instrs (rows sr, sr+128), B 6 instrs (rows sr+q*128)
    int sr = tid >> 3;                  // 0..127
    int scl = (tid & 7) ^ (sr & 7);     // pre-swizzled logical chunk
    const __hip_bfloat16* gA0 = A + (size_t)(row0 + sr) * lda + scl * 8;
    const __hip_bfloat16* gB0 = BT + (size_t)sr * ldb + scl * 8;
    short* dA = Asb + tid * 8;
    short* dB = Bsb + tid * 8;

    int arb = (wm * 64 + ml) * 64;      // A row base (shorts)
    int brb = (wn * 192 + ml) * 64;     // B row base (shorts)
    int csw0 = ((g) ^ (ml & 7)) * 8;
    int csw1 = ((4 + g) ^ (ml & 7)) * 8;

    f32x4 acc[4][12];
    #pragma unroll
    for (int mi = 0; mi < 4; ++mi)
        #pragma unroll
        for (int nj = 0; nj < 12; ++nj) acc[mi][nj] = (f32x4){0.f, 0.f, 0.f, 0.f};

    s16x8 af[4];
    s16x8 bf[6];

    STAGE768(0);
    WAIT_VM0();
    BAR();

    for (int t = 0; t < 12; ++t) {
        #pragma unroll
        for (int ks = 0; ks < 2; ++ks) {
            int csw = ks ? csw1 : csw0;
            #pragma unroll
            for (int mi = 0; mi < 4; ++mi)
                af[mi] = *(const s16x8*)(Asb + arb + mi * 1024 + csw);
            #pragma unroll
            for (int h = 0; h < 2; ++h) {
                #pragma unroll
                for (int nj = 0; nj < 6; ++nj)
                    bf[nj] = *(const s16x8*)(Bsb + brb + (h * 6 + nj) * 1024 + csw);
                WAIT_LGKM();
                __builtin_amdgcn_s_setprio(1);
                #pragma unroll
                for (int mi = 0; mi < 4; ++mi)
                    #pragma unroll
                    for (int nj = 0; nj < 6; ++nj)
                        acc[mi][h * 6 + nj] = __builtin_amdgcn_mfma_f32_16x16x32_bf16(
                            af[mi], bf[nj], acc[mi][h * 6 + nj], 0, 0, 0);
                __builtin_amdgcn_s_setprio(0);
            }
        }
        BAR();                               // all waves finished reading tile t
        if (t + 1 < 12) {
            STAGE768(t + 1);                 // overwrite single buffer
            WAIT_VM0();
        }
        BAR();                               // buffer ready for tile t+1
    }

    // epilogue: C/D mapping col=lane&15, row=(lane>>4)*4+r
    #pragma unroll
    for (int mi = 0; mi < 4; ++mi)
    #pragma unroll
    for (int nj = 0; nj < 12; ++nj) {
        int row = row0 + wm * 64 + mi * 16 + g * 4;
        int col = wn * 192 + nj * 16 + ml;
        float bv = bias[col];
        #pragma unroll
        for (int r = 0; r < 4; ++r) {
            float v = acc[mi][nj][r] + bv;
            float ev = __expf(v) - 1.f;      // elu (select, no branch)
            v = v > 0.f ? v : ev;
            Cb[(size_t)(row + r) * ldc + col] = __float2bfloat16(v);
        }
    }
}

// ---------------- bf16 MFMA GEMM, 256x192 tile, BK=64 (GEMM2, S=2 -> 256 blocks) ----------------
#define SA192(b, kt) do { \
    _Pragma("unroll") for (int q = 0; q < 4; ++q) \
        gload_lds16(gA0 + (size_t)q * lstrA + (size_t)(kt) * 64, dA + (b) * 16384 + q * 4096); \
} while (0)

#define SB192(b, kt) do { \
    _Pragma("unroll") for (int q = 0; q < 3; ++q) \
        gload_lds16(gB0 + (size_t)q * lstrB + (size_t)(kt) * 64, dB + (b) * 12288 + q * 4096); \
} while (0)

#define LA192(b, MQ) do { \
    const short* _p = Asb + (b) * 16384 + arb + (MQ) * (128 * 64); \
    _Pragma("unroll") for (int mi = 0; mi < 4; ++mi) { \
        af[mi][0] = *(const s16x8*)(_p + mi * (16 * 64) + csw0); \
        af[mi][1] = *(const s16x8*)(_p + mi * (16 * 64) + csw1); \
    } \
} while (0)

#define LB192(b) do { \
    const short* _p = Bsb + (b) * 12288 + brb; \
    _Pragma("unroll") for (int ni = 0; ni < 3; ++ni) { \
        bfr[ni][0] = *(const s16x8*)(_p + ni * (16 * 64) + csw0); \
        bfr[ni][1] = *(const s16x8*)(_p + ni * (16 * 64) + csw1); \
    } \
} while (0)

#define MM192(MQ) do { \
    __builtin_amdgcn_s_setprio(1); \
    _Pragma("unroll") for (int ks = 0; ks < 2; ++ks) \
        _Pragma("unroll") for (int mi = 0; mi < 4; ++mi) \
            _Pragma("unroll") for (int ni = 0; ni < 3; ++ni) \
                acc[MQ][mi][ni] = __builtin_amdgcn_mfma_f32_16x16x32_bf16( \
                    af[mi][ks], bfr[ni][ks], acc[MQ][mi][ni], 0, 0, 0); \
    __builtin_amdgcn_s_setprio(0); \
} while (0)

__global__ __launch_bounds__(512, 2) void gemm192_kernel(
    const __hip_bfloat16* __restrict__ A,   // [M][lda]
    const __hip_bfloat16* __restrict__ BT,  // [N][ldb]
    int lda, int ldb, int ldc,
    int K, int kofs_per_z,
    float* __restrict__ Cf,                 // fp32 out
    long bsC,
    int GX, int GY) {
    extern __shared__ __align__(16) short lds[];
    short* Asb = lds;            // [2][256][64] = 32768 shorts
    short* Bsb = lds + 32768;    // [2][192][64] = 24576 shorts

    int lin = blockIdx.x;
    int xcd = lin & 7;
    int u = lin >> 3;
    int bx = u % GX;
    int cg = u / GX;
    int cc = cg * 8 + xcd;
    int by = cc % GY;
    int bz = cc / GY;

    int kofs = bz * kofs_per_z;
    Cf += (size_t)bz * bsC;

    int tid = threadIdx.x;
    int lane = tid & 63;
    int wid = tid >> 6;
    int wm = wid >> 2;      // 0..1
    int wn = wid & 3;       // 0..3
    int ml = lane & 15;
    int g  = lane >> 4;

    int row0 = by * 256;
    int col0 = bx * 192;

    int sr = tid >> 3;
    int scl = (tid & 7) ^ (sr & 7);
    const __hip_bfloat16* gA0 = A + (size_t)(row0 + sr) * lda + kofs + scl * 8;
    const __hip_bfloat16* gB0 = BT + (size_t)(col0 + sr) * ldb + kofs + scl * 8;
    size_t lstrA = (size_t)64 * lda;
    size_t lstrB = (size_t)64 * ldb;
    short* dA = Asb + tid * 8;
    short* dB = Bsb + tid * 8;

    int arb = (wm * 64 + ml) * 64;
    int brb = (wn * 48 + ml) * 64;
    int csw0 = ((g) ^ (ml & 7)) * 8;
    int csw1 = ((4 + g) ^ (ml & 7)) * 8;

    f32x4 acc[2][4][3];
    #pragma unroll
    for (int a0 = 0; a0 < 2; ++a0)
    #pragma unroll
    for (int b0 = 0; b0 < 4; ++b0)
    #pragma unroll
    for (int c0 = 0; c0 < 3; ++c0) acc[a0][b0][c0] = (f32x4){0.f, 0.f, 0.f, 0.f};

    s16x8 af[4][2];
    s16x8 bfr[3][2];

    int nkt = K / 64;  // 48

    SA192(0, 0); SB192(0, 0);
    WAIT_VM0();
    BAR();

    for (int t = 0; t < nkt; ++t) {
        int cur = t & 1;
        if (t + 1 < nkt) { SA192(cur ^ 1, t + 1); SB192(cur ^ 1, t + 1); }
        LA192(cur, 0); LB192(cur);
        WAIT_LGKM();
        MM192(0);
        LA192(cur, 1);
        WAIT_LGKM();
        MM192(1);
        WAIT_VM0();   // next buffer fully landed (stages had the whole iteration)
        BAR();
    }

    #pragma unroll
    for (int mq = 0; mq < 2; ++mq)
    #pragma unroll
    for (int mi = 0; mi < 4; ++mi)
    #pragma unroll
    for (int ni = 0; ni < 3; ++ni) {
        int row = row0 + mq * 128 + wm * 64 + mi * 16 + g * 4;
        int col = col0 + wn * 48 + ni * 16 + ml;
        #pragma unroll
        for (int r = 0; r < 4; ++r) {
            Cf[(size_t)(row + r) * ldc + col] = acc[mq][mi][ni][r];
        }
    }
}

// ---------------- launch ----------------
extern "C" void kernel_launch(void* const* d_in, const int* in_sizes, int n_in,
                              void* d_out, int out_size, void* d_ws, size_t ws_size,
                              hipStream_t stream) {
    const int N = 8192, E = 65536, DIN = 768, C = 768, H1n = 8;
    const int HC1 = H1n * C;  // 6144

    const float* x    = (const float*)d_in[0];
    const float* W1   = (const float*)d_in[1];
    const float* a_s1 = (const float*)d_in[2];
    const float* a_d1 = (const float*)d_in[3];
    const float* b1   = (const float*)d_in[4];
    const float* W2   = (const float*)d_in[5];
    const float* a_s2 = (const float*)d_in[6];
    const float* a_d2 = (const float*)d_in[7];
    const float* b2   = (const float*)d_in[8];
    const int*   edges = (const int*)d_in[9];
    const int* src = edges;
    const int* dst = edges + E;

    // ---- workspace layout ----
    char* w = (char*)d_ws;
    auto alloc = [&](size_t bytes) -> void* {
        void* p = (void*)w;
        w += (bytes + 255) & ~(size_t)255;
        return p;
    };
    __hip_bfloat16* zAB = (__hip_bfloat16*)alloc((size_t)N * HC1 * 2);      // 100.7 MB
    __hip_bfloat16* o1  = (__hip_bfloat16*)alloc((size_t)N * HC1 * 2);      // 100.7 MB
    ushort4* xb4        = (ushort4*)alloc((size_t)N * DIN * 2);             // 12.6 MB
    ushort4* h2b        = (ushort4*)alloc((size_t)N * C * 2);               // 12.6 MB
    __hip_bfloat16* W1T = (__hip_bfloat16*)alloc((size_t)HC1 * DIN * 2);    // 9.4 MB
    __hip_bfloat16* W2T = (__hip_bfloat16*)alloc((size_t)C * HC1 * 2);      // 9.4 MB
    float* wv      = (float*)alloc((size_t)16 * DIN * 4);
    float* as1     = (float*)alloc((size_t)N * H1n * 4);
    float* ad1     = (float*)alloc((size_t)N * H1n * 4);
    float* e1      = (float*)alloc((size_t)E * H1n * 4);
    float* as2     = (float*)alloc((size_t)N * 4);
    float* ad2     = (float*)alloc((size_t)N * 4);
    float* e2      = (float*)alloc((size_t)E * 4);
    int*   counts  = (int*)alloc((size_t)N * 4);
    int*   cursor  = (int*)alloc((size_t)N * 4);
    int*   row_ofs = (int*)alloc((size_t)(N + 1) * 4);
    int*   perm    = (int*)alloc((size_t)E * 4);

    // split-K partials for GEMM2 (S=2) alias zAB (dead after GEMM1)
    float* partials = (float*)zAB;

    (void)hipFuncSetAttribute((const void*)gemm768_kernel,
                              hipFuncAttributeMaxDynamicSharedMemorySize, 131072);
    (void)hipFuncSetAttribute((const void*)gemm192_kernel,
                              hipFuncAttributeMaxDynamicSharedMemorySize, 131072);

    // ---- CSR by dst ----
    zero2_kernel<<<(N + 255) / 256, 256, 0, stream>>>(counts, cursor, N);
    hist_kernel<<<(E + 255) / 256, 256, 0, stream>>>(dst, counts, E);
    scan_kernel<<<1, SCAN_T, 0, stream>>>(counts, row_ofs, N);
    scatter_kernel<<<(E + 255) / 256, 256, 0, stream>>>(dst, row_ofs, cursor, perm, E);

    // ---- weight transforms (bf16, transposed) ----
    {
        dim3 b(32, 8);
        dim3 g1(HC1 / 32, DIN / 32);
        transpose_bf16_kernel<<<g1, b, 0, stream>>>(W1, W1T, DIN, HC1);
        dim3 g2(C / 32, HC1 / 32);
        transpose_bf16_kernel<<<g2, b, 0, stream>>>(W2, W2T, HC1, C);
    }

    // ---- Layer 1 attention coefficients (+ xb4 emission) ----
    wvec_kernel<<<(H1n * DIN * 64 + 255) / 256, 256, 0, stream>>>(W1, a_s1, a_d1, wv, wv + 8 * DIN, DIN, H1n, C);
    alpha16_kernel<<<N / 4, 256, 0, stream>>>((const float4*)x, wv, as1, ad1, xb4);

    // ---- fused softmax + 8-head aggregation: xb -> zAB (bf16) ----
    agg8_fused_kernel<<<N, 192, 0, stream>>>(xb4, as1, ad1, src, row_ofs, perm,
                                             e1, zAB, DIN / 4);

    // ---- GEMM1: full-N per-head tiles; o1 = ELU(z @ W1 + b1); 256 blocks = 1 round ----
    gemm768_kernel<<<256, 1024, 131072, stream>>>(
        zAB, W1T,
        HC1, DIN, HC1,
        b1, o1,
        /*bsA=*/C, /*bsBT=*/(long)C * DIN, /*bsC=*/C, /*bsBias=*/C);

    // ---- GEMM2: K=6144 split-K S=2 into partials, BN=192, full machine (256 blocks) ----
    {
        int GX = C / 192, GY = N / 256;  // 4 x 32 x 2 = 256 blocks
        int Kslice = HC1 / 2;            // 3072 -> 48 K-tiles/block
        gemm192_kernel<<<GX * GY * 2, 512, 114688, stream>>>(
            o1, W2T,
            HC1, HC1, C,
            Kslice, /*kofs_per_z=*/Kslice,
            partials, /*bsC=*/(long)N * C,
            GX, GY);
    }

    // ---- fused: h2b = bf16(p0 + p1) ; as2/ad2 = h2 . a_s2 / a_d2 ----
    reduce_dot_kernel<<<N, 192, 0, stream>>>((const float4*)partials, (const float4*)a_s2,
                                             (const float4*)a_d2, h2b, as2, ad2, N * C / 4);

    // ---- fused layer-2 softmax + output aggregation ----
    out_fused_kernel<<<N, 192, 0, stream>>>(h2b, as2, ad2, src, row_ofs, perm,
                                            e2, (const float4*)b2, (float4*)d_out, C / 4);
}

// Round 9
// 415.707 us; speedup vs baseline: 3.9624x; 3.9624x over previous
//
#include <hip/hip_runtime.h>
#include <hip/hip_bf16.h>
#include <math.h>

typedef __attribute__((ext_vector_type(4))) float f32x4;
typedef __attribute__((ext_vector_type(8))) short s16x8;

#define MAXD 192  // fast-path degree cap for fused softmax (LDS alpha buffer)

// ---------------- CSR-by-dst construction ----------------

__global__ void zero2_kernel(int* __restrict__ a, int* __restrict__ b, int n) {
    int i = blockIdx.x * blockDim.x + threadIdx.x;
    if (i < n) { a[i] = 0; b[i] = 0; }
}

__global__ void hist_kernel(const int* __restrict__ dst, int* __restrict__ counts, int E) {
    int e = blockIdx.x * blockDim.x + threadIdx.x;
    if (e < E) atomicAdd(&counts[dst[e]], 1);
}

#define SCAN_T 1024
__global__ __launch_bounds__(SCAN_T) void scan_kernel(const int* __restrict__ counts,
                                                      int* __restrict__ row_ofs, int Nn) {
    __shared__ int part[SCAN_T];
    int tid = threadIdx.x;
    int chunk = Nn / SCAN_T;
    int base = tid * chunk;
    int sum = 0;
    for (int i = 0; i < chunk; ++i) sum += counts[base + i];
    part[tid] = sum;
    __syncthreads();
    for (int off = 1; off < SCAN_T; off <<= 1) {
        int v = part[tid];
        int u = (tid >= off) ? part[tid - off] : 0;
        __syncthreads();
        part[tid] = v + u;
        __syncthreads();
    }
    if (tid == SCAN_T - 1) row_ofs[Nn] = part[tid];
    int acc = part[tid] - sum;  // exclusive prefix
    for (int i = 0; i < chunk; ++i) { row_ofs[base + i] = acc; acc += counts[base + i]; }
}

__global__ void scatter_kernel(const int* __restrict__ dst, const int* __restrict__ row_ofs,
                               int* __restrict__ cursor, int* __restrict__ perm, int E) {
    int e = blockIdx.x * blockDim.x + threadIdx.x;
    if (e < E) {
        int d = dst[e];
        int pos = atomicAdd(&cursor[d], 1);
        perm[row_ofs[d] + pos] = e;
    }
}

// ---------------- helpers ----------------
__device__ inline unsigned short bf16_bits(float f) {
    __hip_bfloat16 b = __float2bfloat16(f);
    return *reinterpret_cast<unsigned short*>(&b);
}
__device__ inline float bfu(unsigned short u) {
    return __uint_as_float(((unsigned)u) << 16);
}

// ---------------- w_as/w_ad precompute ----------------
__global__ void wvec_kernel(const float* __restrict__ W, const float* __restrict__ a_s,
                            const float* __restrict__ a_d, float* __restrict__ w_as,
                            float* __restrict__ w_ad, int DIN, int H, int C) {
    int gid = blockIdx.x * blockDim.x + threadIdx.x;
    int wid = gid >> 6;
    int lane = threadIdx.x & 63;
    if (wid >= H * DIN) return;
    int h = wid / DIN, i = wid % DIN;
    const float* wp = W + (size_t)i * H * C + (size_t)h * C;
    const float* sp = a_s + (size_t)h * C;
    const float* dp = a_d + (size_t)h * C;
    float ss = 0.f, sd = 0.f;
    for (int c = lane; c < C; c += 64) {
        float v = wp[c];
        ss += v * sp[c];
        sd += v * dp[c];
    }
    #pragma unroll
    for (int off = 32; off > 0; off >>= 1) {
        ss += __shfl_down(ss, off, 64);
        sd += __shfl_down(sd, off, 64);
    }
    if (lane == 0) { w_as[wid] = ss; w_ad[wid] = sd; }
}

// ---------------- layer-1 alpha dots + xb4 emission; one wave per node ----------------
__global__ __launch_bounds__(256) void alpha16_kernel(const float4* __restrict__ x4,
                                                      const float* __restrict__ wv,
                                                      float* __restrict__ as_out,
                                                      float* __restrict__ ad_out,
                                                      ushort4* __restrict__ xb4) {
    __shared__ float ws[16 * 768];
    int tid = threadIdx.x;
    #pragma unroll
    for (int i = 0; i < 12; ++i)
        ((float4*)ws)[tid + i * 256] = ((const float4*)wv)[tid + i * 256];
    __syncthreads();
    int wvid = tid >> 6, lane = tid & 63;
    int n = blockIdx.x * 4 + wvid;
    float4 xr[3];
    #pragma unroll
    for (int r = 0; r < 3; ++r) xr[r] = x4[(size_t)n * 192 + lane + 64 * r];
    // emit bf16 copy of x (saves a separate conversion pass)
    #pragma unroll
    for (int r = 0; r < 3; ++r) {
        ushort4 o;
        o.x = bf16_bits(xr[r].x); o.y = bf16_bits(xr[r].y);
        o.z = bf16_bits(xr[r].z); o.w = bf16_bits(xr[r].w);
        xb4[(size_t)n * 192 + lane + 64 * r] = o;
    }
    #pragma unroll
    for (int j = 0; j < 16; ++j) {
        const float4* wj = (const float4*)(ws + j * 768);
        float s = 0.f;
        #pragma unroll
        for (int r = 0; r < 3; ++r) {
            float4 wc = wj[lane + 64 * r];
            s += xr[r].x * wc.x + xr[r].y * wc.y + xr[r].z * wc.z + xr[r].w * wc.w;
        }
        #pragma unroll
        for (int off = 32; off > 0; off >>= 1) s += __shfl_down(s, off, 64);
        if (lane == 0) {
            if (j < 8) as_out[n * 8 + j] = s;
            else       ad_out[n * 8 + (j - 8)] = s;
        }
    }
}

// ---------------- FUSED: per-node softmax (8 heads) + 8-head aggregation -> zAB bf16 ----------------
__global__ __launch_bounds__(192) void agg8_fused_kernel(
    const ushort4* __restrict__ xb4,  // [N][192] bf16 x (gather-halved)
    const float* __restrict__ as1,    // [N][8]
    const float* __restrict__ ad1,    // [N][8]
    const int* __restrict__ src,
    const int* __restrict__ row_ofs,
    const int* __restrict__ perm,
    float* __restrict__ e1g,          // [E][8] global fallback alpha
    __hip_bfloat16* __restrict__ zAB, // [N][8*768]
    int D4) {
    __shared__ float alds[MAXD * 8];
    __shared__ float mh[8], dh[8];
    int n = blockIdx.x;
    int s = row_ofs[n], t = row_ofs[n + 1];
    int d = t - s;
    int tid = threadIdx.x;
    bool big = d > MAXD;
    if (!big) {
        int eh = tid & 7, ei = tid >> 3;  // ei in 0..23
        float adn = ad1[n * 8 + eh];
        for (int base = 0; base < d; base += 24) {
            int j = base + ei;
            if (j < d) {
                int e = perm[s + j];
                float v = as1[src[e] * 8 + eh] + adn;
                v = v > 0.f ? v : 0.2f * v;
                alds[j * 8 + eh] = v;
            }
        }
        __syncthreads();
        if (tid < 8) {
            float m = -INFINITY;
            for (int j = 0; j < d; ++j) m = fmaxf(m, alds[j * 8 + tid]);
            float den = 0.f;
            for (int j = 0; j < d; ++j) den += __expf(alds[j * 8 + tid] - m);
            mh[tid] = m; dh[tid] = 1.f / (den + 1e-16f);
        }
        __syncthreads();
        for (int base = 0; base < d; base += 24) {
            int j = base + ei;
            if (j < d) alds[j * 8 + eh] = __expf(alds[j * 8 + eh] - mh[eh]) * dh[eh];
        }
        __syncthreads();
    } else {
        if (tid < 8) {
            int hh = tid;
            float adn = ad1[n * 8 + hh];
            float m = -INFINITY;
            for (int j = s; j < t; ++j) {
                float v = as1[src[perm[j]] * 8 + hh] + adn;
                v = v > 0.f ? v : 0.2f * v;
                m = fmaxf(m, v);
            }
            float den = 0.f;
            for (int j = s; j < t; ++j) {
                float v = as1[src[perm[j]] * 8 + hh] + adn;
                v = v > 0.f ? v : 0.2f * v;
                den += __expf(v - m);
            }
            float inv = 1.f / (den + 1e-16f);
            for (int j = s; j < t; ++j) {
                int e = perm[j];
                float v = as1[src[e] * 8 + hh] + adn;
                v = v > 0.f ? v : 0.2f * v;
                e1g[(size_t)e * 8 + hh] = __expf(v - m) * inv;
            }
        }
        __syncthreads();
    }

    // aggregation: thread j handles bf16x4 column j for all 8 heads.
    // 4-wide edge unroll: 4 outstanding row-gathers per thread (MLP; loop is
    // latency-bound, not BW-bound). Accumulation order within the 4-group is
    // sequential, matching the previous 2-wide order's semantics.
    int j = tid;
    float4 acc[8];
    #pragma unroll
    for (int h = 0; h < 8; ++h) acc[h] = make_float4(0.f, 0.f, 0.f, 0.f);
    int k = s;
    for (; k + 3 < t; k += 4) {
        int e0 = perm[k], e1 = perm[k + 1], e2 = perm[k + 2], e3 = perm[k + 3];
        ushort4 u0 = xb4[(size_t)src[e0] * D4 + j];
        ushort4 u1 = xb4[(size_t)src[e1] * D4 + j];
        ushort4 u2 = xb4[(size_t)src[e2] * D4 + j];
        ushort4 u3 = xb4[(size_t)src[e3] * D4 + j];
        float4 v0 = make_float4(bfu(u0.x), bfu(u0.y), bfu(u0.z), bfu(u0.w));
        float4 v1 = make_float4(bfu(u1.x), bfu(u1.y), bfu(u1.z), bfu(u1.w));
        float4 v2 = make_float4(bfu(u2.x), bfu(u2.y), bfu(u2.z), bfu(u2.w));
        float4 v3 = make_float4(bfu(u3.x), bfu(u3.y), bfu(u3.z), bfu(u3.w));
        const float* a0 = big ? &e1g[(size_t)e0 * 8] : &alds[(k - s) * 8];
        const float* a1 = big ? &e1g[(size_t)e1 * 8] : &alds[(k + 1 - s) * 8];
        const float* a2 = big ? &e1g[(size_t)e2 * 8] : &alds[(k + 2 - s) * 8];
        const float* a3 = big ? &e1g[(size_t)e3 * 8] : &alds[(k + 3 - s) * 8];
        #pragma unroll
        for (int h = 0; h < 8; ++h) {
            float a = a0[h], b = a1[h], c = a2[h], e = a3[h];
            acc[h].x += a * v0.x + b * v1.x + c * v2.x + e * v3.x;
            acc[h].y += a * v0.y + b * v1.y + c * v2.y + e * v3.y;
            acc[h].z += a * v0.z + b * v1.z + c * v2.z + e * v3.z;
            acc[h].w += a * v0.w + b * v1.w + c * v2.w + e * v3.w;
        }
    }
    for (; k < t; ++k) {
        int e0 = perm[k];
        ushort4 u0 = xb4[(size_t)src[e0] * D4 + j];
        float4 v0 = make_float4(bfu(u0.x), bfu(u0.y), bfu(u0.z), bfu(u0.w));
        const float* a0 = big ? &e1g[(size_t)e0 * 8] : &alds[(k - s) * 8];
        #pragma unroll
        for (int h = 0; h < 8; ++h) {
            float a = a0[h];
            acc[h].x += a * v0.x; acc[h].y += a * v0.y;
            acc[h].z += a * v0.z; acc[h].w += a * v0.w;
        }
    }
    int D = D4 * 4;
    #pragma unroll
    for (int h = 0; h < 8; ++h) {
        size_t o = (size_t)n * 8 * D + (size_t)h * D + j * 4;
        ushort4 st;
        st.x = bf16_bits(acc[h].x); st.y = bf16_bits(acc[h].y);
        st.z = bf16_bits(acc[h].z); st.w = bf16_bits(acc[h].w);
        *reinterpret_cast<ushort4*>(&zAB[o]) = st;
    }
}

// ---------------- FUSED: layer-2 softmax (H=1) + output aggregation (+bias) ----------------
__global__ __launch_bounds__(192) void out_fused_kernel(
    const ushort4* __restrict__ featb,  // h2b [N][192] bf16 (gather-halved)
    const float* __restrict__ as2,      // [N]
    const float* __restrict__ ad2,      // [N]
    const int* __restrict__ src,
    const int* __restrict__ row_ofs,
    const int* __restrict__ perm,
    float* __restrict__ e2g,            // [E] global fallback alpha
    const float4* __restrict__ bias4,
    float4* __restrict__ out4, int D4) {
    __shared__ float alds[MAXD];
    __shared__ float minv[2];
    int n = blockIdx.x;
    int s = row_ofs[n], t = row_ofs[n + 1];
    int d = t - s;
    int tid = threadIdx.x;
    bool big = d > MAXD;
    if (!big) {
        float adn = ad2[n];
        if (tid < d) {
            float v = as2[src[perm[s + tid]]] + adn;
            v = v > 0.f ? v : 0.2f * v;
            alds[tid] = v;
        }
        __syncthreads();
        if (tid == 0) {
            float m = -INFINITY;
            for (int j = 0; j < d; ++j) m = fmaxf(m, alds[j]);
            float den = 0.f;
            for (int j = 0; j < d; ++j) den += __expf(alds[j] - m);
            minv[0] = m; minv[1] = 1.f / (den + 1e-16f);
        }
        __syncthreads();
        if (tid < d) alds[tid] = __expf(alds[tid] - minv[0]) * minv[1];
        __syncthreads();
    } else {
        if (tid == 0) {
            float adn = ad2[n];
            float m = -INFINITY;
            for (int j = s; j < t; ++j) {
                float v = as2[src[perm[j]]] + adn;
                v = v > 0.f ? v : 0.2f * v;
                m = fmaxf(m, v);
            }
            float den = 0.f;
            for (int j = s; j < t; ++j) {
                float v = as2[src[perm[j]]] + adn;
                v = v > 0.f ? v : 0.2f * v;
                den += __expf(v - m);
            }
            float inv = 1.f / (den + 1e-16f);
            for (int j = s; j < t; ++j) {
                int e = perm[j];
                float v = as2[src[e]] + adn;
                v = v > 0.f ? v : 0.2f * v;
                e2g[e] = __expf(v - m) * inv;
            }
        }
        __syncthreads();
    }

    // 4-wide edge unroll for gather MLP (same rationale as agg8).
    int j = tid;
    float4 acc = make_float4(0.f, 0.f, 0.f, 0.f);
    int k = s;
    for (; k + 3 < t; k += 4) {
        int e0 = perm[k], e1 = perm[k + 1], e2 = perm[k + 2], e3 = perm[k + 3];
        float a = big ? e2g[e0] : alds[k - s];
        float b = big ? e2g[e1] : alds[k + 1 - s];
        float c = big ? e2g[e2] : alds[k + 2 - s];
        float e = big ? e2g[e3] : alds[k + 3 - s];
        ushort4 u0 = featb[(size_t)src[e0] * D4 + j];
        ushort4 u1 = featb[(size_t)src[e1] * D4 + j];
        ushort4 u2 = featb[(size_t)src[e2] * D4 + j];
        ushort4 u3 = featb[(size_t)src[e3] * D4 + j];
        acc.x += a * bfu(u0.x) + b * bfu(u1.x) + c * bfu(u2.x) + e * bfu(u3.x);
        acc.y += a * bfu(u0.y) + b * bfu(u1.y) + c * bfu(u2.y) + e * bfu(u3.y);
        acc.z += a * bfu(u0.z) + b * bfu(u1.z) + c * bfu(u2.z) + e * bfu(u3.z);
        acc.w += a * bfu(u0.w) + b * bfu(u1.w) + c * bfu(u2.w) + e * bfu(u3.w);
    }
    for (; k < t; ++k) {
        int e0 = perm[k];
        float a = big ? e2g[e0] : alds[k - s];
        ushort4 u0 = featb[(size_t)src[e0] * D4 + j];
        acc.x += a * bfu(u0.x); acc.y += a * bfu(u0.y);
        acc.z += a * bfu(u0.z); acc.w += a * bfu(u0.w);
    }
    float4 b = bias4[j];
    acc.x += b.x; acc.y += b.y; acc.z += b.z; acc.w += b.w;
    out4[(size_t)n * D4 + j] = acc;
}

// ---------------- transpose + fp32->bf16 ----------------
__global__ void transpose_bf16_kernel(const float* __restrict__ src, __hip_bfloat16* __restrict__ dst,
                                      int R, int Cc) {
    __shared__ float tile[32][33];
    int bx = blockIdx.x * 32;
    int by = blockIdx.y * 32;
    int tx = threadIdx.x, ty = threadIdx.y;  // 32 x 8
    #pragma unroll
    for (int i = 0; i < 32; i += 8)
        tile[ty + i][tx] = src[(size_t)(by + ty + i) * Cc + (bx + tx)];
    __syncthreads();
    #pragma unroll
    for (int i = 0; i < 32; i += 8)
        dst[(size_t)(bx + ty + i) * R + (by + tx)] = __float2bfloat16(tile[tx][ty + i]);
}

// ---------------- fused: h2 = p0+p1 (split-K S=2) -> bf16; as2/ad2 = h2 . a_s2 / a_d2 ----------------
__global__ __launch_bounds__(192) void reduce_dot_kernel(
    const float4* __restrict__ parts,  // [2][N][192]
    const float4* __restrict__ as_w, const float4* __restrict__ ad_w,
    ushort4* __restrict__ h2b,         // [N][192] bf16 out
    float* __restrict__ as_out, float* __restrict__ ad_out, int NC4) {
    int n = blockIdx.x;
    int j = threadIdx.x;
    size_t idx = (size_t)n * 192 + j;
    float4 a = parts[idx];
    float4 p1 = parts[(size_t)NC4 + idx];
    a.x += p1.x; a.y += p1.y; a.z += p1.z; a.w += p1.w;
    ushort4 st;
    st.x = bf16_bits(a.x); st.y = bf16_bits(a.y);
    st.z = bf16_bits(a.z); st.w = bf16_bits(a.w);
    h2b[idx] = st;
    float4 ws = as_w[j], wd = ad_w[j];
    float ss = a.x * ws.x + a.y * ws.y + a.z * ws.z + a.w * ws.w;
    float sd = a.x * wd.x + a.y * wd.y + a.z * wd.z + a.w * wd.w;
    #pragma unroll
    for (int off = 32; off > 0; off >>= 1) {
        ss += __shfl_down(ss, off, 64);
        sd += __shfl_down(sd, off, 64);
    }
    __shared__ float red_s[3], red_d[3];
    int wv = j >> 6, lane = j & 63;
    if (lane == 0) { red_s[wv] = ss; red_d[wv] = sd; }
    __syncthreads();
    if (j == 0) {
        as_out[n] = red_s[0] + red_s[1] + red_s[2];
        ad_out[n] = red_d[0] + red_d[1] + red_d[2];
    }
}

// ---------------- shared GEMM machinery ----------------
__device__ inline void gload_lds16(const void* g, void* l) {
    __builtin_amdgcn_global_load_lds((const __attribute__((address_space(1))) unsigned int*)g,
                                     (__attribute__((address_space(3))) unsigned int*)l, 16, 0, 0);
}

#define FENCE() asm volatile("" ::: "memory")
#define BAR() do { FENCE(); __builtin_amdgcn_s_barrier(); FENCE(); } while (0)
#define WAIT_LGKM() asm volatile("s_waitcnt lgkmcnt(0)" ::: "memory")
#define WAIT_LGKM_VM6() asm volatile("s_waitcnt lgkmcnt(0) vmcnt(6)" ::: "memory")
#define WAIT_VM0() asm volatile("s_waitcnt vmcnt(0)" ::: "memory")

// ---------------- bf16 MFMA GEMM, 256x256 tile, 8-phase counted-vmcnt (round-5 best: 105.4us) ----------------
// Session record: 7 structural variants (8-phase/1-bar/panel-affinity/2-phase/BK=32/full-N)
// bracket this kernel at 105-109us; register-expanding variants (dual frag sets, 16-wave
// full-N) spill catastrophically (acc budget: 128 f32/lane MAX for 8-wave blocks).
// This is the measured-best configuration — treat as the session's GEMM1 floor.
#define STAGE_A(b, h, kt) do { \
    const __hip_bfloat16* _s = gA0 + (size_t)(h) * 2 * lstrA + (size_t)(kt) * 64; \
    short* _d = dA + (b) * 16384 + (h) * 8192; \
    gload_lds16(_s, _d); \
    gload_lds16(_s + lstrA, _d + 4096); \
} while (0)

#define STAGE_B(b, h, kt) do { \
    const __hip_bfloat16* _s = gB0 + (size_t)(h) * 2 * lstrB + (size_t)(kt) * 64; \
    short* _d = dB + (b) * 16384 + (h) * 8192; \
    gload_lds16(_s, _d); \
    gload_lds16(_s + lstrB, _d + 4096); \
} while (0)

#define LOAD_A(b, MQ) do { \
    const short* _p = Asb + (b) * 16384 + arb + (MQ) * (128 * 64); \
    _Pragma("unroll") for (int mi = 0; mi < 4; ++mi) { \
        af[mi][0] = *(const s16x8*)(_p + mi * (16 * 64) + csw0); \
        af[mi][1] = *(const s16x8*)(_p + mi * (16 * 64) + csw1); \
    } \
} while (0)

#define LOAD_B(b, NQ) do { \
    const short* _p = Bsb + (b) * 16384 + brb + (NQ) * (128 * 64); \
    _Pragma("unroll") for (int ni = 0; ni < 2; ++ni) { \
        bfr[NQ][ni][0] = *(const s16x8*)(_p + ni * (16 * 64) + csw0); \
        bfr[NQ][ni][1] = *(const s16x8*)(_p + ni * (16 * 64) + csw1); \
    } \
} while (0)

#define MMA(MQ, NQ) do { \
    __builtin_amdgcn_s_setprio(1); \
    _Pragma("unroll") for (int ks = 0; ks < 2; ++ks) \
        _Pragma("unroll") for (int mi = 0; mi < 4; ++mi) \
            _Pragma("unroll") for (int ni = 0; ni < 2; ++ni) \
                acc[MQ][NQ][mi][ni] = __builtin_amdgcn_mfma_f32_16x16x32_bf16( \
                    af[mi][ks], bfr[NQ][ni][ks], acc[MQ][NQ][mi][ni], 0, 0, 0); \
    __builtin_amdgcn_s_setprio(0); \
} while (0)

__global__ __launch_bounds__(512, 2) void gemm256_kernel(
    const __hip_bfloat16* __restrict__ A,   // [M][lda]
    const __hip_bfloat16* __restrict__ BT,  // [N][ldb]
    int lda, int ldb, int ldc,
    int K, int kofs_per_z,
    const float* __restrict__ bias,
    __hip_bfloat16* __restrict__ Cb,        // bf16 out or null
    float* __restrict__ Cf,                 // fp32 out (used if Cb==null)
    int flags,                              // 1 = elu
    long bsA, long bsBT, long bsC, long bsBias,
    int GX, int GY) {
    extern __shared__ __align__(16) short lds[];
    short* Asb = lds;            // [2][256][64]
    short* Bsb = lds + 32768;    // [2][256][64]

    int lin = blockIdx.x;
    int xcd = lin & 7;
    int u = lin >> 3;
    int bx = u % GX;
    int cg = u / GX;
    int cc = cg * 8 + xcd;
    int by = cc % GY;
    int bz = cc / GY;

    int kofs = bz * kofs_per_z;
    A += (size_t)bz * bsA;
    BT += (size_t)bz * bsBT;
    if (Cb) Cb += (size_t)bz * bsC;
    else    Cf += (size_t)bz * bsC;
    if (bias) bias += (size_t)bz * bsBias;

    int tid = threadIdx.x;
    int lane = tid & 63;
    int wid = tid >> 6;
    int wm = wid >> 2;
    int wn = wid & 3;
    int ml = lane & 15;
    int g  = lane >> 4;

    int row0 = by * 256;
    int col0 = bx * 256;

    int sr = tid >> 3;
    int scl = (tid & 7) ^ (sr & 7);
    const __hip_bfloat16* gA0 = A + (size_t)(row0 + sr) * lda + kofs + scl * 8;
    const __hip_bfloat16* gB0 = BT + (size_t)(col0 + sr) * ldb + kofs + scl * 8;
    size_t lstrA = (size_t)64 * lda;
    size_t lstrB = (size_t)64 * ldb;
    short* dA = Asb + tid * 8;
    short* dB = Bsb + tid * 8;

    int arb = (wm * 64 + ml) * 64;
    int brb = (wn * 32 + ml) * 64;
    int csw0 = ((g) ^ (ml & 7)) * 8;
    int csw1 = ((4 + g) ^ (ml & 7)) * 8;

    f32x4 acc[2][2][4][2];
    #pragma unroll
    for (int a0 = 0; a0 < 2; ++a0)
    #pragma unroll
    for (int b0 = 0; b0 < 2; ++b0)
    #pragma unroll
    for (int c0 = 0; c0 < 4; ++c0)
    #pragma unroll
    for (int d0 = 0; d0 < 2; ++d0) acc[a0][b0][c0][d0] = (f32x4){0.f, 0.f, 0.f, 0.f};

    s16x8 af[4][2];
    s16x8 bfr[2][2][2];

    int nkt = K / 64;

    STAGE_A(0, 0, 0); STAGE_B(0, 0, 0); STAGE_A(0, 1, 0); STAGE_B(0, 1, 0);
    STAGE_A(1, 0, 1); STAGE_B(1, 0, 1); STAGE_A(1, 1, 1);
    asm volatile("s_waitcnt vmcnt(6)" ::: "memory");
    BAR();

    for (int i = 0; i < nkt / 2; ++i) {
        int t1 = 2 * i + 1, t2 = 2 * i + 2, t3 = 2 * i + 3;
        bool p2 = t2 < nkt, p3 = t3 < nkt;
        LOAD_A(0, 0); LOAD_B(0, 0);
        STAGE_B(1, 1, t1);
        MMA(0, 0); WAIT_LGKM(); BAR();
        LOAD_B(0, 1);
        if (p2) STAGE_A(0, 0, t2);
        MMA(0, 1); WAIT_LGKM(); BAR();
        LOAD_A(0, 1);
        if (p2) STAGE_B(0, 0, t2);
        MMA(1, 0); WAIT_LGKM(); BAR();
        if (p2) STAGE_A(0, 1, t2);
        MMA(1, 1); WAIT_LGKM_VM6(); BAR();
        LOAD_A(1, 0); LOAD_B(1, 0);
        if (p2) STAGE_B(0, 1, t2);
        MMA(0, 0); WAIT_LGKM(); BAR();
        LOAD_B(1, 1);
        if (p3) STAGE_A(1, 0, t3);
        MMA(0, 1); WAIT_LGKM(); BAR();
        LOAD_A(1, 1);
        if (p3) STAGE_B(1, 0, t3);
        MMA(1, 0); WAIT_LGKM(); BAR();
        if (p3) STAGE_A(1, 1, t3);
        MMA(1, 1); WAIT_LGKM_VM6(); BAR();
    }

    #pragma unroll
    for (int mq = 0; mq < 2; ++mq)
    #pragma unroll
    for (int nq = 0; nq < 2; ++nq)
    #pragma unroll
    for (int mi = 0; mi < 4; ++mi)
    #pragma unroll
    for (int ni = 0; ni < 2; ++ni) {
        int row = row0 + mq * 128 + wm * 64 + mi * 16 + g * 4;
        int col = col0 + nq * 128 + wn * 32 + ni * 16 + ml;
        float bv = bias ? bias[col] : 0.f;
        #pragma unroll
        for (int r = 0; r < 4; ++r) {
            float v = acc[mq][nq][mi][ni][r] + bv;
            if (flags & 1) {
                float ev = __expf(v) - 1.f;
                v = v > 0.f ? v : ev;
            }
            size_t idx = (size_t)(row + r) * ldc + col;
            if (Cb) Cb[idx] = __float2bfloat16(v);
            else    Cf[idx] = v;
        }
    }
}

// ---------------- bf16 MFMA GEMM, 256x192 tile, BK=64 (GEMM2, S=2 -> 256 blocks; round-5 best) ----------------
#define SA192(b, kt) do { \
    _Pragma("unroll") for (int q = 0; q < 4; ++q) \
        gload_lds16(gA0 + (size_t)q * lstrA + (size_t)(kt) * 64, dA + (b) * 16384 + q * 4096); \
} while (0)

#define SB192(b, kt) do { \
    _Pragma("unroll") for (int q = 0; q < 3; ++q) \
        gload_lds16(gB0 + (size_t)q * lstrB + (size_t)(kt) * 64, dB + (b) * 12288 + q * 4096); \
} while (0)

#define LA192(b, MQ) do { \
    const short* _p = Asb + (b) * 16384 + arb + (MQ) * (128 * 64); \
    _Pragma("unroll") for (int mi = 0; mi < 4; ++mi) { \
        af[mi][0] = *(const s16x8*)(_p + mi * (16 * 64) + csw0); \
        af[mi][1] = *(const s16x8*)(_p + mi * (16 * 64) + csw1); \
    } \
} while (0)

#define LB192(b) do { \
    const short* _p = Bsb + (b) * 12288 + brb; \
    _Pragma("unroll") for (int ni = 0; ni < 3; ++ni) { \
        bfr[ni][0] = *(const s16x8*)(_p + ni * (16 * 64) + csw0); \
        bfr[ni][1] = *(const s16x8*)(_p + ni * (16 * 64) + csw1); \
    } \
} while (0)

#define MM192(MQ) do { \
    __builtin_amdgcn_s_setprio(1); \
    _Pragma("unroll") for (int ks = 0; ks < 2; ++ks) \
        _Pragma("unroll") for (int mi = 0; mi < 4; ++mi) \
            _Pragma("unroll") for (int ni = 0; ni < 3; ++ni) \
                acc[MQ][mi][ni] = __builtin_amdgcn_mfma_f32_16x16x32_bf16( \
                    af[mi][ks], bfr[ni][ks], acc[MQ][mi][ni], 0, 0, 0); \
    __builtin_amdgcn_s_setprio(0); \
} while (0)

__global__ __launch_bounds__(512, 2) void gemm192_kernel(
    const __hip_bfloat16* __restrict__ A,   // [M][lda]
    const __hip_bfloat16* __restrict__ BT,  // [N][ldb]
    int lda, int ldb, int ldc,
    int K, int kofs_per_z,
    float* __restrict__ Cf,                 // fp32 out
    long bsC,
    int GX, int GY) {
    extern __shared__ __align__(16) short lds[];
    short* Asb = lds;            // [2][256][64] = 32768 shorts
    short* Bsb = lds + 32768;    // [2][192][64] = 24576 shorts

    int lin = blockIdx.x;
    int xcd = lin & 7;
    int u = lin >> 3;
    int bx = u % GX;
    int cg = u / GX;
    int cc = cg * 8 + xcd;
    int by = cc % GY;
    int bz = cc / GY;

    int kofs = bz * kofs_per_z;
    Cf += (size_t)bz * bsC;

    int tid = threadIdx.x;
    int lane = tid & 63;
    int wid = tid >> 6;
    int wm = wid >> 2;      // 0..1
    int wn = wid & 3;       // 0..3
    int ml = lane & 15;
    int g  = lane >> 4;

    int row0 = by * 256;
    int col0 = bx * 192;

    int sr = tid >> 3;
    int scl = (tid & 7) ^ (sr & 7);
    const __hip_bfloat16* gA0 = A + (size_t)(row0 + sr) * lda + kofs + scl * 8;
    const __hip_bfloat16* gB0 = BT + (size_t)(col0 + sr) * ldb + kofs + scl * 8;
    size_t lstrA = (size_t)64 * lda;
    size_t lstrB = (size_t)64 * ldb;
    short* dA = Asb + tid * 8;
    short* dB = Bsb + tid * 8;

    int arb = (wm * 64 + ml) * 64;
    int brb = (wn * 48 + ml) * 64;
    int csw0 = ((g) ^ (ml & 7)) * 8;
    int csw1 = ((4 + g) ^ (ml & 7)) * 8;

    f32x4 acc[2][4][3];
    #pragma unroll
    for (int a0 = 0; a0 < 2; ++a0)
    #pragma unroll
    for (int b0 = 0; b0 < 4; ++b0)
    #pragma unroll
    for (int c0 = 0; c0 < 3; ++c0) acc[a0][b0][c0] = (f32x4){0.f, 0.f, 0.f, 0.f};

    s16x8 af[4][2];
    s16x8 bfr[3][2];

    int nkt = K / 64;  // 48

    SA192(0, 0); SB192(0, 0);
    WAIT_VM0();
    BAR();

    for (int t = 0; t < nkt; ++t) {
        int cur = t & 1;
        if (t + 1 < nkt) { SA192(cur ^ 1, t + 1); SB192(cur ^ 1, t + 1); }
        LA192(cur, 0); LB192(cur);
        WAIT_LGKM();
        MM192(0);
        LA192(cur, 1);
        WAIT_LGKM();
        MM192(1);
        WAIT_VM0();   // next buffer fully landed (stages had the whole iteration)
        BAR();
    }

    #pragma unroll
    for (int mq = 0; mq < 2; ++mq)
    #pragma unroll
    for (int mi = 0; mi < 4; ++mi)
    #pragma unroll
    for (int ni = 0; ni < 3; ++ni) {
        int row = row0 + mq * 128 + wm * 64 + mi * 16 + g * 4;
        int col = col0 + wn * 48 + ni * 16 + ml;
        #pragma unroll
        for (int r = 0; r < 4; ++r) {
            Cf[(size_t)(row + r) * ldc + col] = acc[mq][mi][ni][r];
        }
    }
}

// ---------------- launch ----------------
extern "C" void kernel_launch(void* const* d_in, const int* in_sizes, int n_in,
                              void* d_out, int out_size, void* d_ws, size_t ws_size,
                              hipStream_t stream) {
    const int N = 8192, E = 65536, DIN = 768, C = 768, H1n = 8;
    const int HC1 = H1n * C;  // 6144

    const float* x    = (const float*)d_in[0];
    const float* W1   = (const float*)d_in[1];
    const float* a_s1 = (const float*)d_in[2];
    const float* a_d1 = (const float*)d_in[3];
    const float* b1   = (const float*)d_in[4];
    const float* W2   = (const float*)d_in[5];
    const float* a_s2 = (const float*)d_in[6];
    const float* a_d2 = (const float*)d_in[7];
    const float* b2   = (const float*)d_in[8];
    const int*   edges = (const int*)d_in[9];
    const int* src = edges;
    const int* dst = edges + E;

    // ---- workspace layout ----
    char* w = (char*)d_ws;
    auto alloc = [&](size_t bytes) -> void* {
        void* p = (void*)w;
        w += (bytes + 255) & ~(size_t)255;
        return p;
    };
    __hip_bfloat16* zAB = (__hip_bfloat16*)alloc((size_t)N * HC1 * 2);      // 100.7 MB
    __hip_bfloat16* o1  = (__hip_bfloat16*)alloc((size_t)N * HC1 * 2);      // 100.7 MB
    ushort4* xb4        = (ushort4*)alloc((size_t)N * DIN * 2);             // 12.6 MB
    ushort4* h2b        = (ushort4*)alloc((size_t)N * C * 2);               // 12.6 MB
    __hip_bfloat16* W1T = (__hip_bfloat16*)alloc((size_t)HC1 * DIN * 2);    // 9.4 MB
    __hip_bfloat16* W2T = (__hip_bfloat16*)alloc((size_t)C * HC1 * 2);      // 9.4 MB
    float* wv      = (float*)alloc((size_t)16 * DIN * 4);
    float* as1     = (float*)alloc((size_t)N * H1n * 4);
    float* ad1     = (float*)alloc((size_t)N * H1n * 4);
    float* e1      = (float*)alloc((size_t)E * H1n * 4);
    float* as2     = (float*)alloc((size_t)N * 4);
    float* ad2     = (float*)alloc((size_t)N * 4);
    float* e2      = (float*)alloc((size_t)E * 4);
    int*   counts  = (int*)alloc((size_t)N * 4);
    int*   cursor  = (int*)alloc((size_t)N * 4);
    int*   row_ofs = (int*)alloc((size_t)(N + 1) * 4);
    int*   perm    = (int*)alloc((size_t)E * 4);

    // split-K partials for GEMM2 (S=2) alias zAB (dead after GEMM1)
    float* partials = (float*)zAB;

    (void)hipFuncSetAttribute((const void*)gemm256_kernel,
                              hipFuncAttributeMaxDynamicSharedMemorySize, 131072);
    (void)hipFuncSetAttribute((const void*)gemm192_kernel,
                              hipFuncAttributeMaxDynamicSharedMemorySize, 131072);

    // ---- CSR by dst ----
    zero2_kernel<<<(N + 255) / 256, 256, 0, stream>>>(counts, cursor, N);
    hist_kernel<<<(E + 255) / 256, 256, 0, stream>>>(dst, counts, E);
    scan_kernel<<<1, SCAN_T, 0, stream>>>(counts, row_ofs, N);
    scatter_kernel<<<(E + 255) / 256, 256, 0, stream>>>(dst, row_ofs, cursor, perm, E);

    // ---- weight transforms (bf16, transposed) ----
    {
        dim3 b(32, 8);
        dim3 g1(HC1 / 32, DIN / 32);
        transpose_bf16_kernel<<<g1, b, 0, stream>>>(W1, W1T, DIN, HC1);
        dim3 g2(C / 32, HC1 / 32);
        transpose_bf16_kernel<<<g2, b, 0, stream>>>(W2, W2T, HC1, C);
    }

    // ---- Layer 1 attention coefficients (+ xb4 emission) ----
    wvec_kernel<<<(H1n * DIN * 64 + 255) / 256, 256, 0, stream>>>(W1, a_s1, a_d1, wv, wv + 8 * DIN, DIN, H1n, C);
    alpha16_kernel<<<N / 4, 256, 0, stream>>>((const float4*)x, wv, as1, ad1, xb4);

    // ---- fused softmax + 8-head aggregation: xb -> zAB (bf16) ----
    agg8_fused_kernel<<<N, 192, 0, stream>>>(xb4, as1, ad1, src, row_ofs, perm,
                                             e1, zAB, DIN / 4);

    // ---- GEMM1: all 8 heads; o1 = ELU(z @ W1 + b1) ----
    {
        int GX = C / 256, GY = N / 256;  // 3 x 32 x 8 heads = 768 blocks
        gemm256_kernel<<<GX * GY * H1n, 512, 131072, stream>>>(
            zAB, W1T,
            HC1, DIN, HC1,
            DIN, /*kofs_per_z=*/0,
            b1, o1, nullptr, /*flags=*/1,
            /*bsA=*/C, /*bsBT=*/(long)C * DIN, /*bsC=*/C, /*bsBias=*/C,
            GX, GY);
    }
    // ---- GEMM2: K=6144 split-K S=2 into partials, BN=192, full machine (256 blocks) ----
    {
        int GX = C / 192, GY = N / 256;  // 4 x 32 x 2 = 256 blocks
        int Kslice = HC1 / 2;            // 3072 -> 48 K-tiles/block
        gemm192_kernel<<<GX * GY * 2, 512, 131072, stream>>>(
            o1, W2T,
            HC1, HC1, C,
            Kslice, /*kofs_per_z=*/Kslice,
            partials, /*bsC=*/(long)N * C,
            GX, GY);
    }

    // ---- fused: h2b = bf16(p0 + p1) ; as2/ad2 = h2 . a_s2 / a_d2 ----
    reduce_dot_kernel<<<N, 192, 0, stream>>>((const float4*)partials, (const float4*)a_s2,
                                             (const float4*)a_d2, h2b, as2, ad2, N * C / 4);

    // ---- fused layer-2 softmax + output aggregation ----
    out_fused_kernel<<<N, 192, 0, stream>>>(h2b, as2, ad2, src, row_ofs, perm,
                                            e2, (const float4*)b2, (float4*)d_out, C / 4);
}

// Round 10
// 404.562 us; speedup vs baseline: 4.0715x; 1.0275x over previous
//
#include <hip/hip_runtime.h>
#include <hip/hip_bf16.h>
#include <math.h>

typedef __attribute__((ext_vector_type(4))) float f32x4;
typedef __attribute__((ext_vector_type(8))) short s16x8;

#define MAXD 192  // fast-path degree cap for fused softmax (LDS alpha buffer)

// ---------------- CSR-by-dst construction ----------------

__global__ void zero2_kernel(int* __restrict__ a, int* __restrict__ b, int n) {
    int i = blockIdx.x * blockDim.x + threadIdx.x;
    if (i < n) { a[i] = 0; b[i] = 0; }
}

__global__ void hist_kernel(const int* __restrict__ dst, int* __restrict__ counts, int E) {
    int e = blockIdx.x * blockDim.x + threadIdx.x;
    if (e < E) atomicAdd(&counts[dst[e]], 1);
}

#define SCAN_T 1024
__global__ __launch_bounds__(SCAN_T) void scan_kernel(const int* __restrict__ counts,
                                                      int* __restrict__ row_ofs, int Nn) {
    __shared__ int part[SCAN_T];
    int tid = threadIdx.x;
    int chunk = Nn / SCAN_T;
    int base = tid * chunk;
    int sum = 0;
    for (int i = 0; i < chunk; ++i) sum += counts[base + i];
    part[tid] = sum;
    __syncthreads();
    for (int off = 1; off < SCAN_T; off <<= 1) {
        int v = part[tid];
        int u = (tid >= off) ? part[tid - off] : 0;
        __syncthreads();
        part[tid] = v + u;
        __syncthreads();
    }
    if (tid == SCAN_T - 1) row_ofs[Nn] = part[tid];
    int acc = part[tid] - sum;  // exclusive prefix
    for (int i = 0; i < chunk; ++i) { row_ofs[base + i] = acc; acc += counts[base + i]; }
}

__global__ void scatter_kernel(const int* __restrict__ dst, const int* __restrict__ row_ofs,
                               int* __restrict__ cursor, int* __restrict__ perm, int E) {
    int e = blockIdx.x * blockDim.x + threadIdx.x;
    if (e < E) {
        int d = dst[e];
        int pos = atomicAdd(&cursor[d], 1);
        perm[row_ofs[d] + pos] = e;
    }
}

// ---------------- helpers ----------------
__device__ inline unsigned short bf16_bits(float f) {
    __hip_bfloat16 b = __float2bfloat16(f);
    return *reinterpret_cast<unsigned short*>(&b);
}
__device__ inline float bfu(unsigned short u) {
    return __uint_as_float(((unsigned)u) << 16);
}

// ---------------- w_as/w_ad precompute ----------------
__global__ void wvec_kernel(const float* __restrict__ W, const float* __restrict__ a_s,
                            const float* __restrict__ a_d, float* __restrict__ w_as,
                            float* __restrict__ w_ad, int DIN, int H, int C) {
    int gid = blockIdx.x * blockDim.x + threadIdx.x;
    int wid = gid >> 6;
    int lane = threadIdx.x & 63;
    if (wid >= H * DIN) return;
    int h = wid / DIN, i = wid % DIN;
    const float* wp = W + (size_t)i * H * C + (size_t)h * C;
    const float* sp = a_s + (size_t)h * C;
    const float* dp = a_d + (size_t)h * C;
    float ss = 0.f, sd = 0.f;
    for (int c = lane; c < C; c += 64) {
        float v = wp[c];
        ss += v * sp[c];
        sd += v * dp[c];
    }
    #pragma unroll
    for (int off = 32; off > 0; off >>= 1) {
        ss += __shfl_down(ss, off, 64);
        sd += __shfl_down(sd, off, 64);
    }
    if (lane == 0) { w_as[wid] = ss; w_ad[wid] = sd; }
}

// ---------------- layer-1 alpha dots + xb4 emission; one wave per node ----------------
__global__ __launch_bounds__(256) void alpha16_kernel(const float4* __restrict__ x4,
                                                      const float* __restrict__ wv,
                                                      float* __restrict__ as_out,
                                                      float* __restrict__ ad_out,
                                                      ushort4* __restrict__ xb4) {
    __shared__ float ws[16 * 768];
    int tid = threadIdx.x;
    #pragma unroll
    for (int i = 0; i < 12; ++i)
        ((float4*)ws)[tid + i * 256] = ((const float4*)wv)[tid + i * 256];
    __syncthreads();
    int wvid = tid >> 6, lane = tid & 63;
    int n = blockIdx.x * 4 + wvid;
    float4 xr[3];
    #pragma unroll
    for (int r = 0; r < 3; ++r) xr[r] = x4[(size_t)n * 192 + lane + 64 * r];
    // emit bf16 copy of x (saves a separate conversion pass)
    #pragma unroll
    for (int r = 0; r < 3; ++r) {
        ushort4 o;
        o.x = bf16_bits(xr[r].x); o.y = bf16_bits(xr[r].y);
        o.z = bf16_bits(xr[r].z); o.w = bf16_bits(xr[r].w);
        xb4[(size_t)n * 192 + lane + 64 * r] = o;
    }
    #pragma unroll
    for (int j = 0; j < 16; ++j) {
        const float4* wj = (const float4*)(ws + j * 768);
        float s = 0.f;
        #pragma unroll
        for (int r = 0; r < 3; ++r) {
            float4 wc = wj[lane + 64 * r];
            s += xr[r].x * wc.x + xr[r].y * wc.y + xr[r].z * wc.z + xr[r].w * wc.w;
        }
        #pragma unroll
        for (int off = 32; off > 0; off >>= 1) s += __shfl_down(s, off, 64);
        if (lane == 0) {
            if (j < 8) as_out[n * 8 + j] = s;
            else       ad_out[n * 8 + (j - 8)] = s;
        }
    }
}

// ---------------- FUSED: per-node softmax (8 heads) + 8-head aggregation -> zAB bf16 ----------------
__global__ __launch_bounds__(192) void agg8_fused_kernel(
    const ushort4* __restrict__ xb4,  // [N][192] bf16 x (gather-halved)
    const float* __restrict__ as1,    // [N][8]
    const float* __restrict__ ad1,    // [N][8]
    const int* __restrict__ src,
    const int* __restrict__ row_ofs,
    const int* __restrict__ perm,
    float* __restrict__ e1g,          // [E][8] global fallback alpha
    __hip_bfloat16* __restrict__ zAB, // [N][8*768]
    int D4) {
    __shared__ float alds[MAXD * 8];
    __shared__ float mh[8], dh[8];
    int n = blockIdx.x;
    int s = row_ofs[n], t = row_ofs[n + 1];
    int d = t - s;
    int tid = threadIdx.x;
    bool big = d > MAXD;
    if (!big) {
        int eh = tid & 7, ei = tid >> 3;  // ei in 0..23
        float adn = ad1[n * 8 + eh];
        for (int base = 0; base < d; base += 24) {
            int j = base + ei;
            if (j < d) {
                int e = perm[s + j];
                float v = as1[src[e] * 8 + eh] + adn;
                v = v > 0.f ? v : 0.2f * v;
                alds[j * 8 + eh] = v;
            }
        }
        __syncthreads();
        if (tid < 8) {
            float m = -INFINITY;
            for (int j = 0; j < d; ++j) m = fmaxf(m, alds[j * 8 + tid]);
            float den = 0.f;
            for (int j = 0; j < d; ++j) den += __expf(alds[j * 8 + tid] - m);
            mh[tid] = m; dh[tid] = 1.f / (den + 1e-16f);
        }
        __syncthreads();
        for (int base = 0; base < d; base += 24) {
            int j = base + ei;
            if (j < d) alds[j * 8 + eh] = __expf(alds[j * 8 + eh] - mh[eh]) * dh[eh];
        }
        __syncthreads();
    } else {
        if (tid < 8) {
            int hh = tid;
            float adn = ad1[n * 8 + hh];
            float m = -INFINITY;
            for (int j = s; j < t; ++j) {
                float v = as1[src[perm[j]] * 8 + hh] + adn;
                v = v > 0.f ? v : 0.2f * v;
                m = fmaxf(m, v);
            }
            float den = 0.f;
            for (int j = s; j < t; ++j) {
                float v = as1[src[perm[j]] * 8 + hh] + adn;
                v = v > 0.f ? v : 0.2f * v;
                den += __expf(v - m);
            }
            float inv = 1.f / (den + 1e-16f);
            for (int j = s; j < t; ++j) {
                int e = perm[j];
                float v = as1[src[e] * 8 + hh] + adn;
                v = v > 0.f ? v : 0.2f * v;
                e1g[(size_t)e * 8 + hh] = __expf(v - m) * inv;
            }
        }
        __syncthreads();
    }

    // aggregation: thread j handles bf16x4 column j for all 8 heads.
    // 2-wide edge loop (round-5 proven form; 4-wide unroll measured -10us: register
    // pressure cut resident blocks on this latency-bound 192-thread kernel).
    int j = tid;
    float4 acc[8];
    #pragma unroll
    for (int h = 0; h < 8; ++h) acc[h] = make_float4(0.f, 0.f, 0.f, 0.f);
    int k = s;
    for (; k + 1 < t; k += 2) {
        int e0 = perm[k], e1 = perm[k + 1];
        ushort4 u0 = xb4[(size_t)src[e0] * D4 + j];
        ushort4 u1 = xb4[(size_t)src[e1] * D4 + j];
        float4 v0 = make_float4(bfu(u0.x), bfu(u0.y), bfu(u0.z), bfu(u0.w));
        float4 v1 = make_float4(bfu(u1.x), bfu(u1.y), bfu(u1.z), bfu(u1.w));
        const float* a0 = big ? &e1g[(size_t)e0 * 8] : &alds[(k - s) * 8];
        const float* a1 = big ? &e1g[(size_t)e1 * 8] : &alds[(k + 1 - s) * 8];
        #pragma unroll
        for (int h = 0; h < 8; ++h) {
            float a = a0[h], b = a1[h];
            acc[h].x += a * v0.x + b * v1.x;
            acc[h].y += a * v0.y + b * v1.y;
            acc[h].z += a * v0.z + b * v1.z;
            acc[h].w += a * v0.w + b * v1.w;
        }
    }
    if (k < t) {
        int e0 = perm[k];
        ushort4 u0 = xb4[(size_t)src[e0] * D4 + j];
        float4 v0 = make_float4(bfu(u0.x), bfu(u0.y), bfu(u0.z), bfu(u0.w));
        const float* a0 = big ? &e1g[(size_t)e0 * 8] : &alds[(k - s) * 8];
        #pragma unroll
        for (int h = 0; h < 8; ++h) {
            float a = a0[h];
            acc[h].x += a * v0.x; acc[h].y += a * v0.y;
            acc[h].z += a * v0.z; acc[h].w += a * v0.w;
        }
    }
    int D = D4 * 4;
    #pragma unroll
    for (int h = 0; h < 8; ++h) {
        size_t o = (size_t)n * 8 * D + (size_t)h * D + j * 4;
        ushort4 st;
        st.x = bf16_bits(acc[h].x); st.y = bf16_bits(acc[h].y);
        st.z = bf16_bits(acc[h].z); st.w = bf16_bits(acc[h].w);
        *reinterpret_cast<ushort4*>(&zAB[o]) = st;
    }
}

// ---------------- FUSED: layer-2 softmax (H=1) + output aggregation (+bias) ----------------
__global__ __launch_bounds__(192) void out_fused_kernel(
    const ushort4* __restrict__ featb,  // h2b [N][192] bf16 (gather-halved)
    const float* __restrict__ as2,      // [N]
    const float* __restrict__ ad2,      // [N]
    const int* __restrict__ src,
    const int* __restrict__ row_ofs,
    const int* __restrict__ perm,
    float* __restrict__ e2g,            // [E] global fallback alpha
    const float4* __restrict__ bias4,
    float4* __restrict__ out4, int D4) {
    __shared__ float alds[MAXD];
    __shared__ float minv[2];
    int n = blockIdx.x;
    int s = row_ofs[n], t = row_ofs[n + 1];
    int d = t - s;
    int tid = threadIdx.x;
    bool big = d > MAXD;
    if (!big) {
        float adn = ad2[n];
        if (tid < d) {
            float v = as2[src[perm[s + tid]]] + adn;
            v = v > 0.f ? v : 0.2f * v;
            alds[tid] = v;
        }
        __syncthreads();
        if (tid == 0) {
            float m = -INFINITY;
            for (int j = 0; j < d; ++j) m = fmaxf(m, alds[j]);
            float den = 0.f;
            for (int j = 0; j < d; ++j) den += __expf(alds[j] - m);
            minv[0] = m; minv[1] = 1.f / (den + 1e-16f);
        }
        __syncthreads();
        if (tid < d) alds[tid] = __expf(alds[tid] - minv[0]) * minv[1];
        __syncthreads();
    } else {
        if (tid == 0) {
            float adn = ad2[n];
            float m = -INFINITY;
            for (int j = s; j < t; ++j) {
                float v = as2[src[perm[j]]] + adn;
                v = v > 0.f ? v : 0.2f * v;
                m = fmaxf(m, v);
            }
            float den = 0.f;
            for (int j = s; j < t; ++j) {
                float v = as2[src[perm[j]]] + adn;
                v = v > 0.f ? v : 0.2f * v;
                den += __expf(v - m);
            }
            float inv = 1.f / (den + 1e-16f);
            for (int j = s; j < t; ++j) {
                int e = perm[j];
                float v = as2[src[e]] + adn;
                v = v > 0.f ? v : 0.2f * v;
                e2g[e] = __expf(v - m) * inv;
            }
        }
        __syncthreads();
    }

    int j = tid;
    float4 acc = make_float4(0.f, 0.f, 0.f, 0.f);
    int k = s;
    for (; k + 1 < t; k += 2) {
        int e0 = perm[k], e1 = perm[k + 1];
        float a = big ? e2g[e0] : alds[k - s];
        float b = big ? e2g[e1] : alds[k + 1 - s];
        ushort4 u0 = featb[(size_t)src[e0] * D4 + j];
        ushort4 u1 = featb[(size_t)src[e1] * D4 + j];
        acc.x += a * bfu(u0.x) + b * bfu(u1.x);
        acc.y += a * bfu(u0.y) + b * bfu(u1.y);
        acc.z += a * bfu(u0.z) + b * bfu(u1.z);
        acc.w += a * bfu(u0.w) + b * bfu(u1.w);
    }
    if (k < t) {
        int e0 = perm[k];
        float a = big ? e2g[e0] : alds[k - s];
        ushort4 u0 = featb[(size_t)src[e0] * D4 + j];
        acc.x += a * bfu(u0.x); acc.y += a * bfu(u0.y);
        acc.z += a * bfu(u0.z); acc.w += a * bfu(u0.w);
    }
    float4 b = bias4[j];
    acc.x += b.x; acc.y += b.y; acc.z += b.z; acc.w += b.w;
    out4[(size_t)n * D4 + j] = acc;
}

// ---------------- transpose + fp32->bf16 ----------------
__global__ void transpose_bf16_kernel(const float* __restrict__ src, __hip_bfloat16* __restrict__ dst,
                                      int R, int Cc) {
    __shared__ float tile[32][33];
    int bx = blockIdx.x * 32;
    int by = blockIdx.y * 32;
    int tx = threadIdx.x, ty = threadIdx.y;  // 32 x 8
    #pragma unroll
    for (int i = 0; i < 32; i += 8)
        tile[ty + i][tx] = src[(size_t)(by + ty + i) * Cc + (bx + tx)];
    __syncthreads();
    #pragma unroll
    for (int i = 0; i < 32; i += 8)
        dst[(size_t)(bx + ty + i) * R + (by + tx)] = __float2bfloat16(tile[tx][ty + i]);
}

// ---------------- fused: h2 = p0+p1 (split-K S=2, bf16 partials) ; as2/ad2 dots ----------------
// Partials are bf16 (halves gemm192 write + this kernel's read; rounding each partial
// before the sum adds <=1 bf16 ulp vs the existing post-sum bf16 rounding of h2b).
__global__ __launch_bounds__(192) void reduce_dot_kernel(
    const ushort4* __restrict__ parts,  // [2][N][192] bf16x4
    const float4* __restrict__ as_w, const float4* __restrict__ ad_w,
    ushort4* __restrict__ h2b,          // [N][192] bf16 out
    float* __restrict__ as_out, float* __restrict__ ad_out, int NC4) {
    int n = blockIdx.x;
    int j = threadIdx.x;
    size_t idx = (size_t)n * 192 + j;
    ushort4 q0 = parts[idx];
    ushort4 q1 = parts[(size_t)NC4 + idx];
    float4 a;
    a.x = bfu(q0.x) + bfu(q1.x);
    a.y = bfu(q0.y) + bfu(q1.y);
    a.z = bfu(q0.z) + bfu(q1.z);
    a.w = bfu(q0.w) + bfu(q1.w);
    ushort4 st;
    st.x = bf16_bits(a.x); st.y = bf16_bits(a.y);
    st.z = bf16_bits(a.z); st.w = bf16_bits(a.w);
    h2b[idx] = st;
    float4 ws = as_w[j], wd = ad_w[j];
    float ss = a.x * ws.x + a.y * ws.y + a.z * ws.z + a.w * ws.w;
    float sd = a.x * wd.x + a.y * wd.y + a.z * wd.z + a.w * wd.w;
    #pragma unroll
    for (int off = 32; off > 0; off >>= 1) {
        ss += __shfl_down(ss, off, 64);
        sd += __shfl_down(sd, off, 64);
    }
    __shared__ float red_s[3], red_d[3];
    int wv = j >> 6, lane = j & 63;
    if (lane == 0) { red_s[wv] = ss; red_d[wv] = sd; }
    __syncthreads();
    if (j == 0) {
        as_out[n] = red_s[0] + red_s[1] + red_s[2];
        ad_out[n] = red_d[0] + red_d[1] + red_d[2];
    }
}

// ---------------- shared GEMM machinery ----------------
__device__ inline void gload_lds16(const void* g, void* l) {
    __builtin_amdgcn_global_load_lds((const __attribute__((address_space(1))) unsigned int*)g,
                                     (__attribute__((address_space(3))) unsigned int*)l, 16, 0, 0);
}

#define FENCE() asm volatile("" ::: "memory")
#define BAR() do { FENCE(); __builtin_amdgcn_s_barrier(); FENCE(); } while (0)
#define WAIT_LGKM() asm volatile("s_waitcnt lgkmcnt(0)" ::: "memory")
#define WAIT_LGKM_VM6() asm volatile("s_waitcnt lgkmcnt(0) vmcnt(6)" ::: "memory")
#define WAIT_VM0() asm volatile("s_waitcnt vmcnt(0)" ::: "memory")

// ---------------- bf16 MFMA GEMM, 256x256 tile, 8-phase counted-vmcnt (round-5/9 best: ~105us) ----------------
// Session record: 7 structural variants (8-phase/1-bar/panel-affinity/2-phase/BK=32/full-N)
// bracket this kernel at 105-109us; register-expanding variants spill catastrophically
// (acc budget: 128 f32/lane MAX for 8-wave blocks). Measured-best configuration.
#define STAGE_A(b, h, kt) do { \
    const __hip_bfloat16* _s = gA0 + (size_t)(h) * 2 * lstrA + (size_t)(kt) * 64; \
    short* _d = dA + (b) * 16384 + (h) * 8192; \
    gload_lds16(_s, _d); \
    gload_lds16(_s + lstrA, _d + 4096); \
} while (0)

#define STAGE_B(b, h, kt) do { \
    const __hip_bfloat16* _s = gB0 + (size_t)(h) * 2 * lstrB + (size_t)(kt) * 64; \
    short* _d = dB + (b) * 16384 + (h) * 8192; \
    gload_lds16(_s, _d); \
    gload_lds16(_s + lstrB, _d + 4096); \
} while (0)

#define LOAD_A(b, MQ) do { \
    const short* _p = Asb + (b) * 16384 + arb + (MQ) * (128 * 64); \
    _Pragma("unroll") for (int mi = 0; mi < 4; ++mi) { \
        af[mi][0] = *(const s16x8*)(_p + mi * (16 * 64) + csw0); \
        af[mi][1] = *(const s16x8*)(_p + mi * (16 * 64) + csw1); \
    } \
} while (0)

#define LOAD_B(b, NQ) do { \
    const short* _p = Bsb + (b) * 16384 + brb + (NQ) * (128 * 64); \
    _Pragma("unroll") for (int ni = 0; ni < 2; ++ni) { \
        bfr[NQ][ni][0] = *(const s16x8*)(_p + ni * (16 * 64) + csw0); \
        bfr[NQ][ni][1] = *(const s16x8*)(_p + ni * (16 * 64) + csw1); \
    } \
} while (0)

#define MMA(MQ, NQ) do { \
    __builtin_amdgcn_s_setprio(1); \
    _Pragma("unroll") for (int ks = 0; ks < 2; ++ks) \
        _Pragma("unroll") for (int mi = 0; mi < 4; ++mi) \
            _Pragma("unroll") for (int ni = 0; ni < 2; ++ni) \
                acc[MQ][NQ][mi][ni] = __builtin_amdgcn_mfma_f32_16x16x32_bf16( \
                    af[mi][ks], bfr[NQ][ni][ks], acc[MQ][NQ][mi][ni], 0, 0, 0); \
    __builtin_amdgcn_s_setprio(0); \
} while (0)

__global__ __launch_bounds__(512, 2) void gemm256_kernel(
    const __hip_bfloat16* __restrict__ A,   // [M][lda]
    const __hip_bfloat16* __restrict__ BT,  // [N][ldb]
    int lda, int ldb, int ldc,
    int K, int kofs_per_z,
    const float* __restrict__ bias,
    __hip_bfloat16* __restrict__ Cb,        // bf16 out or null
    float* __restrict__ Cf,                 // fp32 out (used if Cb==null)
    int flags,                              // 1 = elu
    long bsA, long bsBT, long bsC, long bsBias,
    int GX, int GY) {
    extern __shared__ __align__(16) short lds[];
    short* Asb = lds;            // [2][256][64]
    short* Bsb = lds + 32768;    // [2][256][64]

    int lin = blockIdx.x;
    int xcd = lin & 7;
    int u = lin >> 3;
    int bx = u % GX;
    int cg = u / GX;
    int cc = cg * 8 + xcd;
    int by = cc % GY;
    int bz = cc / GY;

    int kofs = bz * kofs_per_z;
    A += (size_t)bz * bsA;
    BT += (size_t)bz * bsBT;
    if (Cb) Cb += (size_t)bz * bsC;
    else    Cf += (size_t)bz * bsC;
    if (bias) bias += (size_t)bz * bsBias;

    int tid = threadIdx.x;
    int lane = tid & 63;
    int wid = tid >> 6;
    int wm = wid >> 2;
    int wn = wid & 3;
    int ml = lane & 15;
    int g  = lane >> 4;

    int row0 = by * 256;
    int col0 = bx * 256;

    int sr = tid >> 3;
    int scl = (tid & 7) ^ (sr & 7);
    const __hip_bfloat16* gA0 = A + (size_t)(row0 + sr) * lda + kofs + scl * 8;
    const __hip_bfloat16* gB0 = BT + (size_t)(col0 + sr) * ldb + kofs + scl * 8;
    size_t lstrA = (size_t)64 * lda;
    size_t lstrB = (size_t)64 * ldb;
    short* dA = Asb + tid * 8;
    short* dB = Bsb + tid * 8;

    int arb = (wm * 64 + ml) * 64;
    int brb = (wn * 32 + ml) * 64;
    int csw0 = ((g) ^ (ml & 7)) * 8;
    int csw1 = ((4 + g) ^ (ml & 7)) * 8;

    f32x4 acc[2][2][4][2];
    #pragma unroll
    for (int a0 = 0; a0 < 2; ++a0)
    #pragma unroll
    for (int b0 = 0; b0 < 2; ++b0)
    #pragma unroll
    for (int c0 = 0; c0 < 4; ++c0)
    #pragma unroll
    for (int d0 = 0; d0 < 2; ++d0) acc[a0][b0][c0][d0] = (f32x4){0.f, 0.f, 0.f, 0.f};

    s16x8 af[4][2];
    s16x8 bfr[2][2][2];

    int nkt = K / 64;

    STAGE_A(0, 0, 0); STAGE_B(0, 0, 0); STAGE_A(0, 1, 0); STAGE_B(0, 1, 0);
    STAGE_A(1, 0, 1); STAGE_B(1, 0, 1); STAGE_A(1, 1, 1);
    asm volatile("s_waitcnt vmcnt(6)" ::: "memory");
    BAR();

    for (int i = 0; i < nkt / 2; ++i) {
        int t1 = 2 * i + 1, t2 = 2 * i + 2, t3 = 2 * i + 3;
        bool p2 = t2 < nkt, p3 = t3 < nkt;
        LOAD_A(0, 0); LOAD_B(0, 0);
        STAGE_B(1, 1, t1);
        MMA(0, 0); WAIT_LGKM(); BAR();
        LOAD_B(0, 1);
        if (p2) STAGE_A(0, 0, t2);
        MMA(0, 1); WAIT_LGKM(); BAR();
        LOAD_A(0, 1);
        if (p2) STAGE_B(0, 0, t2);
        MMA(1, 0); WAIT_LGKM(); BAR();
        if (p2) STAGE_A(0, 1, t2);
        MMA(1, 1); WAIT_LGKM_VM6(); BAR();
        LOAD_A(1, 0); LOAD_B(1, 0);
        if (p2) STAGE_B(0, 1, t2);
        MMA(0, 0); WAIT_LGKM(); BAR();
        LOAD_B(1, 1);
        if (p3) STAGE_A(1, 0, t3);
        MMA(0, 1); WAIT_LGKM(); BAR();
        LOAD_A(1, 1);
        if (p3) STAGE_B(1, 0, t3);
        MMA(1, 0); WAIT_LGKM(); BAR();
        if (p3) STAGE_A(1, 1, t3);
        MMA(1, 1); WAIT_LGKM_VM6(); BAR();
    }

    #pragma unroll
    for (int mq = 0; mq < 2; ++mq)
    #pragma unroll
    for (int nq = 0; nq < 2; ++nq)
    #pragma unroll
    for (int mi = 0; mi < 4; ++mi)
    #pragma unroll
    for (int ni = 0; ni < 2; ++ni) {
        int row = row0 + mq * 128 + wm * 64 + mi * 16 + g * 4;
        int col = col0 + nq * 128 + wn * 32 + ni * 16 + ml;
        float bv = bias ? bias[col] : 0.f;
        #pragma unroll
        for (int r = 0; r < 4; ++r) {
            float v = acc[mq][nq][mi][ni][r] + bv;
            if (flags & 1) {
                float ev = __expf(v) - 1.f;
                v = v > 0.f ? v : ev;
            }
            size_t idx = (size_t)(row + r) * ldc + col;
            if (Cb) Cb[idx] = __float2bfloat16(v);
            else    Cf[idx] = v;
        }
    }
}

// ---------------- bf16 MFMA GEMM, 256x192 tile, BK=64 (GEMM2, S=2 -> 256 blocks; bf16 partials out) ----------------
#define SA192(b, kt) do { \
    _Pragma("unroll") for (int q = 0; q < 4; ++q) \
        gload_lds16(gA0 + (size_t)q * lstrA + (size_t)(kt) * 64, dA + (b) * 16384 + q * 4096); \
} while (0)

#define SB192(b, kt) do { \
    _Pragma("unroll") for (int q = 0; q < 3; ++q) \
        gload_lds16(gB0 + (size_t)q * lstrB + (size_t)(kt) * 64, dB + (b) * 12288 + q * 4096); \
} while (0)

#define LA192(b, MQ) do { \
    const short* _p = Asb + (b) * 16384 + arb + (MQ) * (128 * 64); \
    _Pragma("unroll") for (int mi = 0; mi < 4; ++mi) { \
        af[mi][0] = *(const s16x8*)(_p + mi * (16 * 64) + csw0); \
        af[mi][1] = *(const s16x8*)(_p + mi * (16 * 64) + csw1); \
    } \
} while (0)

#define LB192(b) do { \
    const short* _p = Bsb + (b) * 12288 + brb; \
    _Pragma("unroll") for (int ni = 0; ni < 3; ++ni) { \
        bfr[ni][0] = *(const s16x8*)(_p + ni * (16 * 64) + csw0); \
        bfr[ni][1] = *(const s16x8*)(_p + ni * (16 * 64) + csw1); \
    } \
} while (0)

#define MM192(MQ) do { \
    __builtin_amdgcn_s_setprio(1); \
    _Pragma("unroll") for (int ks = 0; ks < 2; ++ks) \
        _Pragma("unroll") for (int mi = 0; mi < 4; ++mi) \
            _Pragma("unroll") for (int ni = 0; ni < 3; ++ni) \
                acc[MQ][mi][ni] = __builtin_amdgcn_mfma_f32_16x16x32_bf16( \
                    af[mi][ks], bfr[ni][ks], acc[MQ][mi][ni], 0, 0, 0); \
    __builtin_amdgcn_s_setprio(0); \
} while (0)

__global__ __launch_bounds__(512, 2) void gemm192_kernel(
    const __hip_bfloat16* __restrict__ A,   // [M][lda]
    const __hip_bfloat16* __restrict__ BT,  // [N][ldb]
    int lda, int ldb, int ldc,
    int K, int kofs_per_z,
    __hip_bfloat16* __restrict__ Cb,        // bf16 partials out
    long bsC,
    int GX, int GY) {
    extern __shared__ __align__(16) short lds[];
    short* Asb = lds;            // [2][256][64] = 32768 shorts
    short* Bsb = lds + 32768;    // [2][192][64] = 24576 shorts

    int lin = blockIdx.x;
    int xcd = lin & 7;
    int u = lin >> 3;
    int bx = u % GX;
    int cg = u / GX;
    int cc = cg * 8 + xcd;
    int by = cc % GY;
    int bz = cc / GY;

    int kofs = bz * kofs_per_z;
    Cb += (size_t)bz * bsC;

    int tid = threadIdx.x;
    int lane = tid & 63;
    int wid = tid >> 6;
    int wm = wid >> 2;      // 0..1
    int wn = wid & 3;       // 0..3
    int ml = lane & 15;
    int g  = lane >> 4;

    int row0 = by * 256;
    int col0 = bx * 192;

    int sr = tid >> 3;
    int scl = (tid & 7) ^ (sr & 7);
    const __hip_bfloat16* gA0 = A + (size_t)(row0 + sr) * lda + kofs + scl * 8;
    const __hip_bfloat16* gB0 = BT + (size_t)(col0 + sr) * ldb + kofs + scl * 8;
    size_t lstrA = (size_t)64 * lda;
    size_t lstrB = (size_t)64 * ldb;
    short* dA = Asb + tid * 8;
    short* dB = Bsb + tid * 8;

    int arb = (wm * 64 + ml) * 64;
    int brb = (wn * 48 + ml) * 64;
    int csw0 = ((g) ^ (ml & 7)) * 8;
    int csw1 = ((4 + g) ^ (ml & 7)) * 8;

    f32x4 acc[2][4][3];
    #pragma unroll
    for (int a0 = 0; a0 < 2; ++a0)
    #pragma unroll
    for (int b0 = 0; b0 < 4; ++b0)
    #pragma unroll
    for (int c0 = 0; c0 < 3; ++c0) acc[a0][b0][c0] = (f32x4){0.f, 0.f, 0.f, 0.f};

    s16x8 af[4][2];
    s16x8 bfr[3][2];

    int nkt = K / 64;  // 48

    SA192(0, 0); SB192(0, 0);
    WAIT_VM0();
    BAR();

    for (int t = 0; t < nkt; ++t) {
        int cur = t & 1;
        if (t + 1 < nkt) { SA192(cur ^ 1, t + 1); SB192(cur ^ 1, t + 1); }
        LA192(cur, 0); LB192(cur);
        WAIT_LGKM();
        MM192(0);
        LA192(cur, 1);
        WAIT_LGKM();
        MM192(1);
        WAIT_VM0();   // next buffer fully landed (stages had the whole iteration)
        BAR();
    }

    #pragma unroll
    for (int mq = 0; mq < 2; ++mq)
    #pragma unroll
    for (int mi = 0; mi < 4; ++mi)
    #pragma unroll
    for (int ni = 0; ni < 3; ++ni) {
        int row = row0 + mq * 128 + wm * 64 + mi * 16 + g * 4;
        int col = col0 + wn * 48 + ni * 16 + ml;
        #pragma unroll
        for (int r = 0; r < 4; ++r) {
            Cb[(size_t)(row + r) * ldc + col] = __float2bfloat16(acc[mq][mi][ni][r]);
        }
    }
}

// ---------------- launch ----------------
extern "C" void kernel_launch(void* const* d_in, const int* in_sizes, int n_in,
                              void* d_out, int out_size, void* d_ws, size_t ws_size,
                              hipStream_t stream) {
    const int N = 8192, E = 65536, DIN = 768, C = 768, H1n = 8;
    const int HC1 = H1n * C;  // 6144

    const float* x    = (const float*)d_in[0];
    const float* W1   = (const float*)d_in[1];
    const float* a_s1 = (const float*)d_in[2];
    const float* a_d1 = (const float*)d_in[3];
    const float* b1   = (const float*)d_in[4];
    const float* W2   = (const float*)d_in[5];
    const float* a_s2 = (const float*)d_in[6];
    const float* a_d2 = (const float*)d_in[7];
    const float* b2   = (const float*)d_in[8];
    const int*   edges = (const int*)d_in[9];
    const int* src = edges;
    const int* dst = edges + E;

    // ---- workspace layout ----
    char* w = (char*)d_ws;
    auto alloc = [&](size_t bytes) -> void* {
        void* p = (void*)w;
        w += (bytes + 255) & ~(size_t)255;
        return p;
    };
    __hip_bfloat16* zAB = (__hip_bfloat16*)alloc((size_t)N * HC1 * 2);      // 100.7 MB
    __hip_bfloat16* o1  = (__hip_bfloat16*)alloc((size_t)N * HC1 * 2);      // 100.7 MB
    ushort4* xb4        = (ushort4*)alloc((size_t)N * DIN * 2);             // 12.6 MB
    ushort4* h2b        = (ushort4*)alloc((size_t)N * C * 2);               // 12.6 MB
    __hip_bfloat16* W1T = (__hip_bfloat16*)alloc((size_t)HC1 * DIN * 2);    // 9.4 MB
    __hip_bfloat16* W2T = (__hip_bfloat16*)alloc((size_t)C * HC1 * 2);      // 9.4 MB
    float* wv      = (float*)alloc((size_t)16 * DIN * 4);
    float* as1     = (float*)alloc((size_t)N * H1n * 4);
    float* ad1     = (float*)alloc((size_t)N * H1n * 4);
    float* e1      = (float*)alloc((size_t)E * H1n * 4);
    float* as2     = (float*)alloc((size_t)N * 4);
    float* ad2     = (float*)alloc((size_t)N * 4);
    float* e2      = (float*)alloc((size_t)E * 4);
    int*   counts  = (int*)alloc((size_t)N * 4);
    int*   cursor  = (int*)alloc((size_t)N * 4);
    int*   row_ofs = (int*)alloc((size_t)(N + 1) * 4);
    int*   perm    = (int*)alloc((size_t)E * 4);

    // split-K bf16 partials (S=2) alias zAB (dead after GEMM1): 2*12.6 = 25 MB << 100 MB
    __hip_bfloat16* partials = zAB;

    (void)hipFuncSetAttribute((const void*)gemm256_kernel,
                              hipFuncAttributeMaxDynamicSharedMemorySize, 131072);
    (void)hipFuncSetAttribute((const void*)gemm192_kernel,
                              hipFuncAttributeMaxDynamicSharedMemorySize, 131072);

    // ---- CSR by dst ----
    zero2_kernel<<<(N + 255) / 256, 256, 0, stream>>>(counts, cursor, N);
    hist_kernel<<<(E + 255) / 256, 256, 0, stream>>>(dst, counts, E);
    scan_kernel<<<1, SCAN_T, 0, stream>>>(counts, row_ofs, N);
    scatter_kernel<<<(E + 255) / 256, 256, 0, stream>>>(dst, row_ofs, cursor, perm, E);

    // ---- weight transforms (bf16, transposed) ----
    {
        dim3 b(32, 8);
        dim3 g1(HC1 / 32, DIN / 32);
        transpose_bf16_kernel<<<g1, b, 0, stream>>>(W1, W1T, DIN, HC1);
        dim3 g2(C / 32, HC1 / 32);
        transpose_bf16_kernel<<<g2, b, 0, stream>>>(W2, W2T, HC1, C);
    }

    // ---- Layer 1 attention coefficients (+ xb4 emission) ----
    wvec_kernel<<<(H1n * DIN * 64 + 255) / 256, 256, 0, stream>>>(W1, a_s1, a_d1, wv, wv + 8 * DIN, DIN, H1n, C);
    alpha16_kernel<<<N / 4, 256, 0, stream>>>((const float4*)x, wv, as1, ad1, xb4);

    // ---- fused softmax + 8-head aggregation: xb -> zAB (bf16) ----
    agg8_fused_kernel<<<N, 192, 0, stream>>>(xb4, as1, ad1, src, row_ofs, perm,
                                             e1, zAB, DIN / 4);

    // ---- GEMM1: all 8 heads; o1 = ELU(z @ W1 + b1) ----
    {
        int GX = C / 256, GY = N / 256;  // 3 x 32 x 8 heads = 768 blocks
        gemm256_kernel<<<GX * GY * H1n, 512, 131072, stream>>>(
            zAB, W1T,
            HC1, DIN, HC1,
            DIN, /*kofs_per_z=*/0,
            b1, o1, nullptr, /*flags=*/1,
            /*bsA=*/C, /*bsBT=*/(long)C * DIN, /*bsC=*/C, /*bsBias=*/C,
            GX, GY);
    }
    // ---- GEMM2: K=6144 split-K S=2 into bf16 partials, BN=192, full machine (256 blocks) ----
    {
        int GX = C / 192, GY = N / 256;  // 4 x 32 x 2 = 256 blocks
        int Kslice = HC1 / 2;            // 3072 -> 48 K-tiles/block
        gemm192_kernel<<<GX * GY * 2, 512, 131072, stream>>>(
            o1, W2T,
            HC1, HC1, C,
            Kslice, /*kofs_per_z=*/Kslice,
            partials, /*bsC=*/(long)N * C,
            GX, GY);
    }

    // ---- fused: h2b = bf16(p0 + p1) ; as2/ad2 = h2 . a_s2 / a_d2 ----
    reduce_dot_kernel<<<N, 192, 0, stream>>>((const ushort4*)partials, (const float4*)a_s2,
                                             (const float4*)a_d2, h2b, as2, ad2, N * C / 4);

    // ---- fused layer-2 softmax + output aggregation ----
    out_fused_kernel<<<N, 192, 0, stream>>>(h2b, as2, ad2, src, row_ofs, perm,
                                            e2, (const float4*)b2, (float4*)d_out, C / 4);
}

// Round 11
// 397.536 us; speedup vs baseline: 4.1435x; 1.0177x over previous
//
#include <hip/hip_runtime.h>
#include <hip/hip_bf16.h>
#include <math.h>

typedef __attribute__((ext_vector_type(4))) float f32x4;
typedef __attribute__((ext_vector_type(8))) short s16x8;

#define MAXD 192  // fast-path degree cap for fused softmax (LDS alpha buffer)

// ---------------- CSR-by-dst construction ----------------

__global__ void hist_kernel(const int* __restrict__ dst, int* __restrict__ counts, int E) {
    int e = blockIdx.x * blockDim.x + threadIdx.x;
    if (e < E) atomicAdd(&counts[dst[e]], 1);
}

#define SCAN_T 1024
__global__ __launch_bounds__(SCAN_T) void scan_kernel(const int* __restrict__ counts,
                                                      int* __restrict__ row_ofs, int Nn) {
    __shared__ int part[SCAN_T];
    int tid = threadIdx.x;
    int chunk = Nn / SCAN_T;
    int base = tid * chunk;
    int sum = 0;
    for (int i = 0; i < chunk; ++i) sum += counts[base + i];
    part[tid] = sum;
    __syncthreads();
    for (int off = 1; off < SCAN_T; off <<= 1) {
        int v = part[tid];
        int u = (tid >= off) ? part[tid - off] : 0;
        __syncthreads();
        part[tid] = v + u;
        __syncthreads();
    }
    if (tid == SCAN_T - 1) row_ofs[Nn] = part[tid];
    int acc = part[tid] - sum;  // exclusive prefix
    for (int i = 0; i < chunk; ++i) { row_ofs[base + i] = acc; acc += counts[base + i]; }
}

__global__ void scatter_kernel(const int* __restrict__ dst, const int* __restrict__ row_ofs,
                               int* __restrict__ cursor, int* __restrict__ perm, int E) {
    int e = blockIdx.x * blockDim.x + threadIdx.x;
    if (e < E) {
        int d = dst[e];
        int pos = atomicAdd(&cursor[d], 1);
        perm[row_ofs[d] + pos] = e;
    }
}

// ---------------- helpers ----------------
__device__ inline unsigned short bf16_bits(float f) {
    __hip_bfloat16 b = __float2bfloat16(f);
    return *reinterpret_cast<unsigned short*>(&b);
}
__device__ inline float bfu(unsigned short u) {
    return __uint_as_float(((unsigned)u) << 16);
}

// ---------------- MERGED preprocessing: zero2 + transpose(W1) + transpose(W2) + wvec ----------------
// All four are mutually independent; merging cuts 3 launch gaps and lets them co-schedule.
// Bodies are byte-identical to the previous separate kernels (bit-identical outputs).
__device__ inline void transpose_body(const float* __restrict__ src, __hip_bfloat16* __restrict__ dst,
                                      int R, int Cc, int bx, int by, int tx, int ty,
                                      float (*tile)[33]) {
    #pragma unroll
    for (int i = 0; i < 32; i += 8)
        tile[ty + i][tx] = src[(size_t)(by + ty + i) * Cc + (bx + tx)];
    __syncthreads();
    #pragma unroll
    for (int i = 0; i < 32; i += 8)
        dst[(size_t)(bx + ty + i) * R + (by + tx)] = __float2bfloat16(tile[tx][ty + i]);
}

__global__ __launch_bounds__(256) void prep_kernel(
    const float* __restrict__ W1, const float* __restrict__ W2,
    __hip_bfloat16* __restrict__ W1T, __hip_bfloat16* __restrict__ W2T,
    const float* __restrict__ a_s1, const float* __restrict__ a_d1,
    float* __restrict__ w_as, float* __restrict__ w_ad,
    int* __restrict__ counts, int* __restrict__ cursor,
    int DIN, int H, int C, int Nn) {
    __shared__ float tile[32][33];
    int bid = blockIdx.x;
    int tid = threadIdx.x;
    // W1 transpose: src [768][6144], grid 192x24 (col-tiles fastest)
    if (bid < 4608) {
        int bx = (bid % 192) * 32;
        int by = (bid / 192) * 32;
        transpose_body(W1, W1T, DIN, H * C, bx, by, tid & 31, tid >> 5, tile);
        return;
    }
    bid -= 4608;
    // W2 transpose: src [6144][768], grid 24x192
    if (bid < 4608) {
        int bx = (bid % 24) * 32;
        int by = (bid / 24) * 32;
        transpose_body(W2, W2T, H * C, C, bx, by, tid & 31, tid >> 5, tile);
        return;
    }
    bid -= 4608;
    // wvec: 1536 blocks x 256 = 6144 waves, one per (h,i)
    if (bid < 1536) {
        int gid = bid * 256 + tid;
        int wid = gid >> 6;
        int lane = tid & 63;
        if (wid >= H * DIN) return;
        int h = wid / DIN, i = wid % DIN;
        const float* wp = W1 + (size_t)i * H * C + (size_t)h * C;
        const float* sp = a_s1 + (size_t)h * C;
        const float* dp = a_d1 + (size_t)h * C;
        float ss = 0.f, sd = 0.f;
        for (int c = lane; c < C; c += 64) {
            float v = wp[c];
            ss += v * sp[c];
            sd += v * dp[c];
        }
        #pragma unroll
        for (int off = 32; off > 0; off >>= 1) {
            ss += __shfl_down(ss, off, 64);
            sd += __shfl_down(sd, off, 64);
        }
        if (lane == 0) { w_as[wid] = ss; w_ad[wid] = sd; }
        return;
    }
    bid -= 1536;
    // zero counts/cursor: 32 blocks
    {
        int i = bid * 256 + tid;
        if (i < Nn) { counts[i] = 0; cursor[i] = 0; }
    }
}

// ---------------- layer-1 alpha dots + xb4 emission; one wave per node ----------------
__global__ __launch_bounds__(256) void alpha16_kernel(const float4* __restrict__ x4,
                                                      const float* __restrict__ wv,
                                                      float* __restrict__ as_out,
                                                      float* __restrict__ ad_out,
                                                      ushort4* __restrict__ xb4) {
    __shared__ float ws[16 * 768];
    int tid = threadIdx.x;
    #pragma unroll
    for (int i = 0; i < 12; ++i)
        ((float4*)ws)[tid + i * 256] = ((const float4*)wv)[tid + i * 256];
    __syncthreads();
    int wvid = tid >> 6, lane = tid & 63;
    int n = blockIdx.x * 4 + wvid;
    float4 xr[3];
    #pragma unroll
    for (int r = 0; r < 3; ++r) xr[r] = x4[(size_t)n * 192 + lane + 64 * r];
    // emit bf16 copy of x (saves a separate conversion pass)
    #pragma unroll
    for (int r = 0; r < 3; ++r) {
        ushort4 o;
        o.x = bf16_bits(xr[r].x); o.y = bf16_bits(xr[r].y);
        o.z = bf16_bits(xr[r].z); o.w = bf16_bits(xr[r].w);
        xb4[(size_t)n * 192 + lane + 64 * r] = o;
    }
    #pragma unroll
    for (int j = 0; j < 16; ++j) {
        const float4* wj = (const float4*)(ws + j * 768);
        float s = 0.f;
        #pragma unroll
        for (int r = 0; r < 3; ++r) {
            float4 wc = wj[lane + 64 * r];
            s += xr[r].x * wc.x + xr[r].y * wc.y + xr[r].z * wc.z + xr[r].w * wc.w;
        }
        #pragma unroll
        for (int off = 32; off > 0; off >>= 1) s += __shfl_down(s, off, 64);
        if (lane == 0) {
            if (j < 8) as_out[n * 8 + j] = s;
            else       ad_out[n * 8 + (j - 8)] = s;
        }
    }
}

// ---------------- FUSED: per-node softmax (8 heads) + 8-head aggregation -> zAB bf16 ----------------
__global__ __launch_bounds__(192) void agg8_fused_kernel(
    const ushort4* __restrict__ xb4,  // [N][192] bf16 x (gather-halved)
    const float* __restrict__ as1,    // [N][8]
    const float* __restrict__ ad1,    // [N][8]
    const int* __restrict__ src,
    const int* __restrict__ row_ofs,
    const int* __restrict__ perm,
    float* __restrict__ e1g,          // [E][8] global fallback alpha
    __hip_bfloat16* __restrict__ zAB, // [N][8*768]
    int D4) {
    __shared__ float alds[MAXD * 8];
    __shared__ float mh[8], dh[8];
    int n = blockIdx.x;
    int s = row_ofs[n], t = row_ofs[n + 1];
    int d = t - s;
    int tid = threadIdx.x;
    bool big = d > MAXD;
    if (!big) {
        int eh = tid & 7, ei = tid >> 3;  // ei in 0..23
        float adn = ad1[n * 8 + eh];
        for (int base = 0; base < d; base += 24) {
            int j = base + ei;
            if (j < d) {
                int e = perm[s + j];
                float v = as1[src[e] * 8 + eh] + adn;
                v = v > 0.f ? v : 0.2f * v;
                alds[j * 8 + eh] = v;
            }
        }
        __syncthreads();
        if (tid < 8) {
            float m = -INFINITY;
            for (int j = 0; j < d; ++j) m = fmaxf(m, alds[j * 8 + tid]);
            float den = 0.f;
            for (int j = 0; j < d; ++j) den += __expf(alds[j * 8 + tid] - m);
            mh[tid] = m; dh[tid] = 1.f / (den + 1e-16f);
        }
        __syncthreads();
        for (int base = 0; base < d; base += 24) {
            int j = base + ei;
            if (j < d) alds[j * 8 + eh] = __expf(alds[j * 8 + eh] - mh[eh]) * dh[eh];
        }
        __syncthreads();
    } else {
        if (tid < 8) {
            int hh = tid;
            float adn = ad1[n * 8 + hh];
            float m = -INFINITY;
            for (int j = s; j < t; ++j) {
                float v = as1[src[perm[j]] * 8 + hh] + adn;
                v = v > 0.f ? v : 0.2f * v;
                m = fmaxf(m, v);
            }
            float den = 0.f;
            for (int j = s; j < t; ++j) {
                float v = as1[src[perm[j]] * 8 + hh] + adn;
                v = v > 0.f ? v : 0.2f * v;
                den += __expf(v - m);
            }
            float inv = 1.f / (den + 1e-16f);
            for (int j = s; j < t; ++j) {
                int e = perm[j];
                float v = as1[src[e] * 8 + hh] + adn;
                v = v > 0.f ? v : 0.2f * v;
                e1g[(size_t)e * 8 + hh] = __expf(v - m) * inv;
            }
        }
        __syncthreads();
    }

    // aggregation: thread j handles bf16x4 column j for all 8 heads.
    // 2-wide edge loop (proven form; 4-wide unroll measured -10us from reg pressure).
    int j = tid;
    float4 acc[8];
    #pragma unroll
    for (int h = 0; h < 8; ++h) acc[h] = make_float4(0.f, 0.f, 0.f, 0.f);
    int k = s;
    for (; k + 1 < t; k += 2) {
        int e0 = perm[k], e1 = perm[k + 1];
        ushort4 u0 = xb4[(size_t)src[e0] * D4 + j];
        ushort4 u1 = xb4[(size_t)src[e1] * D4 + j];
        float4 v0 = make_float4(bfu(u0.x), bfu(u0.y), bfu(u0.z), bfu(u0.w));
        float4 v1 = make_float4(bfu(u1.x), bfu(u1.y), bfu(u1.z), bfu(u1.w));
        const float* a0 = big ? &e1g[(size_t)e0 * 8] : &alds[(k - s) * 8];
        const float* a1 = big ? &e1g[(size_t)e1 * 8] : &alds[(k + 1 - s) * 8];
        #pragma unroll
        for (int h = 0; h < 8; ++h) {
            float a = a0[h], b = a1[h];
            acc[h].x += a * v0.x + b * v1.x;
            acc[h].y += a * v0.y + b * v1.y;
            acc[h].z += a * v0.z + b * v1.z;
            acc[h].w += a * v0.w + b * v1.w;
        }
    }
    if (k < t) {
        int e0 = perm[k];
        ushort4 u0 = xb4[(size_t)src[e0] * D4 + j];
        float4 v0 = make_float4(bfu(u0.x), bfu(u0.y), bfu(u0.z), bfu(u0.w));
        const float* a0 = big ? &e1g[(size_t)e0 * 8] : &alds[(k - s) * 8];
        #pragma unroll
        for (int h = 0; h < 8; ++h) {
            float a = a0[h];
            acc[h].x += a * v0.x; acc[h].y += a * v0.y;
            acc[h].z += a * v0.z; acc[h].w += a * v0.w;
        }
    }
    int D = D4 * 4;
    #pragma unroll
    for (int h = 0; h < 8; ++h) {
        size_t o = (size_t)n * 8 * D + (size_t)h * D + j * 4;
        ushort4 st;
        st.x = bf16_bits(acc[h].x); st.y = bf16_bits(acc[h].y);
        st.z = bf16_bits(acc[h].z); st.w = bf16_bits(acc[h].w);
        *reinterpret_cast<ushort4*>(&zAB[o]) = st;
    }
}

// ---------------- FUSED: layer-2 softmax (H=1) + output aggregation (+bias) ----------------
__global__ __launch_bounds__(192) void out_fused_kernel(
    const ushort4* __restrict__ featb,  // h2b [N][192] bf16 (gather-halved)
    const float* __restrict__ as2,      // [N]
    const float* __restrict__ ad2,      // [N]
    const int* __restrict__ src,
    const int* __restrict__ row_ofs,
    const int* __restrict__ perm,
    float* __restrict__ e2g,            // [E] global fallback alpha
    const float4* __restrict__ bias4,
    float4* __restrict__ out4, int D4) {
    __shared__ float alds[MAXD];
    __shared__ float minv[2];
    int n = blockIdx.x;
    int s = row_ofs[n], t = row_ofs[n + 1];
    int d = t - s;
    int tid = threadIdx.x;
    bool big = d > MAXD;
    if (!big) {
        float adn = ad2[n];
        if (tid < d) {
            float v = as2[src[perm[s + tid]]] + adn;
            v = v > 0.f ? v : 0.2f * v;
            alds[tid] = v;
        }
        __syncthreads();
        if (tid == 0) {
            float m = -INFINITY;
            for (int j = 0; j < d; ++j) m = fmaxf(m, alds[j]);
            float den = 0.f;
            for (int j = 0; j < d; ++j) den += __expf(alds[j] - m);
            minv[0] = m; minv[1] = 1.f / (den + 1e-16f);
        }
        __syncthreads();
        if (tid < d) alds[tid] = __expf(alds[tid] - minv[0]) * minv[1];
        __syncthreads();
    } else {
        if (tid == 0) {
            float adn = ad2[n];
            float m = -INFINITY;
            for (int j = s; j < t; ++j) {
                float v = as2[src[perm[j]]] + adn;
                v = v > 0.f ? v : 0.2f * v;
                m = fmaxf(m, v);
            }
            float den = 0.f;
            for (int j = s; j < t; ++j) {
                float v = as2[src[perm[j]]] + adn;
                v = v > 0.f ? v : 0.2f * v;
                den += __expf(v - m);
            }
            float inv = 1.f / (den + 1e-16f);
            for (int j = s; j < t; ++j) {
                int e = perm[j];
                float v = as2[src[e]] + adn;
                v = v > 0.f ? v : 0.2f * v;
                e2g[e] = __expf(v - m) * inv;
            }
        }
        __syncthreads();
    }

    int j = tid;
    float4 acc = make_float4(0.f, 0.f, 0.f, 0.f);
    int k = s;
    for (; k + 1 < t; k += 2) {
        int e0 = perm[k], e1 = perm[k + 1];
        float a = big ? e2g[e0] : alds[k - s];
        float b = big ? e2g[e1] : alds[k + 1 - s];
        ushort4 u0 = featb[(size_t)src[e0] * D4 + j];
        ushort4 u1 = featb[(size_t)src[e1] * D4 + j];
        acc.x += a * bfu(u0.x) + b * bfu(u1.x);
        acc.y += a * bfu(u0.y) + b * bfu(u1.y);
        acc.z += a * bfu(u0.z) + b * bfu(u1.z);
        acc.w += a * bfu(u0.w) + b * bfu(u1.w);
    }
    if (k < t) {
        int e0 = perm[k];
        float a = big ? e2g[e0] : alds[k - s];
        ushort4 u0 = featb[(size_t)src[e0] * D4 + j];
        acc.x += a * bfu(u0.x); acc.y += a * bfu(u0.y);
        acc.z += a * bfu(u0.z); acc.w += a * bfu(u0.w);
    }
    float4 b = bias4[j];
    acc.x += b.x; acc.y += b.y; acc.z += b.z; acc.w += b.w;
    out4[(size_t)n * D4 + j] = acc;
}

// ---------------- fused: h2 = p0+p1 (split-K S=2, bf16 partials) ; as2/ad2 dots ----------------
__global__ __launch_bounds__(192) void reduce_dot_kernel(
    const ushort4* __restrict__ parts,  // [2][N][192] bf16x4
    const float4* __restrict__ as_w, const float4* __restrict__ ad_w,
    ushort4* __restrict__ h2b,          // [N][192] bf16 out
    float* __restrict__ as_out, float* __restrict__ ad_out, int NC4) {
    int n = blockIdx.x;
    int j = threadIdx.x;
    size_t idx = (size_t)n * 192 + j;
    ushort4 q0 = parts[idx];
    ushort4 q1 = parts[(size_t)NC4 + idx];
    float4 a;
    a.x = bfu(q0.x) + bfu(q1.x);
    a.y = bfu(q0.y) + bfu(q1.y);
    a.z = bfu(q0.z) + bfu(q1.z);
    a.w = bfu(q0.w) + bfu(q1.w);
    ushort4 st;
    st.x = bf16_bits(a.x); st.y = bf16_bits(a.y);
    st.z = bf16_bits(a.z); st.w = bf16_bits(a.w);
    h2b[idx] = st;
    float4 ws = as_w[j], wd = ad_w[j];
    float ss = a.x * ws.x + a.y * ws.y + a.z * ws.z + a.w * ws.w;
    float sd = a.x * wd.x + a.y * wd.y + a.z * wd.z + a.w * wd.w;
    #pragma unroll
    for (int off = 32; off > 0; off >>= 1) {
        ss += __shfl_down(ss, off, 64);
        sd += __shfl_down(sd, off, 64);
    }
    __shared__ float red_s[3], red_d[3];
    int wv = j >> 6, lane = j & 63;
    if (lane == 0) { red_s[wv] = ss; red_d[wv] = sd; }
    __syncthreads();
    if (j == 0) {
        as_out[n] = red_s[0] + red_s[1] + red_s[2];
        ad_out[n] = red_d[0] + red_d[1] + red_d[2];
    }
}

// ---------------- shared GEMM machinery ----------------
__device__ inline void gload_lds16(const void* g, void* l) {
    __builtin_amdgcn_global_load_lds((const __attribute__((address_space(1))) unsigned int*)g,
                                     (__attribute__((address_space(3))) unsigned int*)l, 16, 0, 0);
}

#define FENCE() asm volatile("" ::: "memory")
#define BAR() do { FENCE(); __builtin_amdgcn_s_barrier(); FENCE(); } while (0)
#define WAIT_LGKM() asm volatile("s_waitcnt lgkmcnt(0)" ::: "memory")
#define WAIT_LGKM_VM6() asm volatile("s_waitcnt lgkmcnt(0) vmcnt(6)" ::: "memory")
#define WAIT_VM0() asm volatile("s_waitcnt vmcnt(0)" ::: "memory")

// ---------------- bf16 MFMA GEMM, 256x256 tile, 8-phase counted-vmcnt (session best: ~105us) ----------------
// 7 structural variants bracket this at 105-109us; register-expanding variants spill
// (acc budget: 128 f32/lane MAX for 8-wave blocks). Measured-best configuration.
#define STAGE_A(b, h, kt) do { \
    const __hip_bfloat16* _s = gA0 + (size_t)(h) * 2 * lstrA + (size_t)(kt) * 64; \
    short* _d = dA + (b) * 16384 + (h) * 8192; \
    gload_lds16(_s, _d); \
    gload_lds16(_s + lstrA, _d + 4096); \
} while (0)

#define STAGE_B(b, h, kt) do { \
    const __hip_bfloat16* _s = gB0 + (size_t)(h) * 2 * lstrB + (size_t)(kt) * 64; \
    short* _d = dB + (b) * 16384 + (h) * 8192; \
    gload_lds16(_s, _d); \
    gload_lds16(_s + lstrB, _d + 4096); \
} while (0)

#define LOAD_A(b, MQ) do { \
    const short* _p = Asb + (b) * 16384 + arb + (MQ) * (128 * 64); \
    _Pragma("unroll") for (int mi = 0; mi < 4; ++mi) { \
        af[mi][0] = *(const s16x8*)(_p + mi * (16 * 64) + csw0); \
        af[mi][1] = *(const s16x8*)(_p + mi * (16 * 64) + csw1); \
    } \
} while (0)

#define LOAD_B(b, NQ) do { \
    const short* _p = Bsb + (b) * 16384 + brb + (NQ) * (128 * 64); \
    _Pragma("unroll") for (int ni = 0; ni < 2; ++ni) { \
        bfr[NQ][ni][0] = *(const s16x8*)(_p + ni * (16 * 64) + csw0); \
        bfr[NQ][ni][1] = *(const s16x8*)(_p + ni * (16 * 64) + csw1); \
    } \
} while (0)

#define MMA(MQ, NQ) do { \
    __builtin_amdgcn_s_setprio(1); \
    _Pragma("unroll") for (int ks = 0; ks < 2; ++ks) \
        _Pragma("unroll") for (int mi = 0; mi < 4; ++mi) \
            _Pragma("unroll") for (int ni = 0; ni < 2; ++ni) \
                acc[MQ][NQ][mi][ni] = __builtin_amdgcn_mfma_f32_16x16x32_bf16( \
                    af[mi][ks], bfr[NQ][ni][ks], acc[MQ][NQ][mi][ni], 0, 0, 0); \
    __builtin_amdgcn_s_setprio(0); \
} while (0)

__global__ __launch_bounds__(512, 2) void gemm256_kernel(
    const __hip_bfloat16* __restrict__ A,   // [M][lda]
    const __hip_bfloat16* __restrict__ BT,  // [N][ldb]
    int lda, int ldb, int ldc,
    int K, int kofs_per_z,
    const float* __restrict__ bias,
    __hip_bfloat16* __restrict__ Cb,        // bf16 out or null
    float* __restrict__ Cf,                 // fp32 out (used if Cb==null)
    int flags,                              // 1 = elu
    long bsA, long bsBT, long bsC, long bsBias,
    int GX, int GY) {
    extern __shared__ __align__(16) short lds[];
    short* Asb = lds;            // [2][256][64]
    short* Bsb = lds + 32768;    // [2][256][64]

    int lin = blockIdx.x;
    int xcd = lin & 7;
    int u = lin >> 3;
    int bx = u % GX;
    int cg = u / GX;
    int cc = cg * 8 + xcd;
    int by = cc % GY;
    int bz = cc / GY;

    int kofs = bz * kofs_per_z;
    A += (size_t)bz * bsA;
    BT += (size_t)bz * bsBT;
    if (Cb) Cb += (size_t)bz * bsC;
    else    Cf += (size_t)bz * bsC;
    if (bias) bias += (size_t)bz * bsBias;

    int tid = threadIdx.x;
    int lane = tid & 63;
    int wid = tid >> 6;
    int wm = wid >> 2;
    int wn = wid & 3;
    int ml = lane & 15;
    int g  = lane >> 4;

    int row0 = by * 256;
    int col0 = bx * 256;

    int sr = tid >> 3;
    int scl = (tid & 7) ^ (sr & 7);
    const __hip_bfloat16* gA0 = A + (size_t)(row0 + sr) * lda + kofs + scl * 8;
    const __hip_bfloat16* gB0 = BT + (size_t)(col0 + sr) * ldb + kofs + scl * 8;
    size_t lstrA = (size_t)64 * lda;
    size_t lstrB = (size_t)64 * ldb;
    short* dA = Asb + tid * 8;
    short* dB = Bsb + tid * 8;

    int arb = (wm * 64 + ml) * 64;
    int brb = (wn * 32 + ml) * 64;
    int csw0 = ((g) ^ (ml & 7)) * 8;
    int csw1 = ((4 + g) ^ (ml & 7)) * 8;

    f32x4 acc[2][2][4][2];
    #pragma unroll
    for (int a0 = 0; a0 < 2; ++a0)
    #pragma unroll
    for (int b0 = 0; b0 < 2; ++b0)
    #pragma unroll
    for (int c0 = 0; c0 < 4; ++c0)
    #pragma unroll
    for (int d0 = 0; d0 < 2; ++d0) acc[a0][b0][c0][d0] = (f32x4){0.f, 0.f, 0.f, 0.f};

    s16x8 af[4][2];
    s16x8 bfr[2][2][2];

    int nkt = K / 64;

    STAGE_A(0, 0, 0); STAGE_B(0, 0, 0); STAGE_A(0, 1, 0); STAGE_B(0, 1, 0);
    STAGE_A(1, 0, 1); STAGE_B(1, 0, 1); STAGE_A(1, 1, 1);
    asm volatile("s_waitcnt vmcnt(6)" ::: "memory");
    BAR();

    for (int i = 0; i < nkt / 2; ++i) {
        int t1 = 2 * i + 1, t2 = 2 * i + 2, t3 = 2 * i + 3;
        bool p2 = t2 < nkt, p3 = t3 < nkt;
        LOAD_A(0, 0); LOAD_B(0, 0);
        STAGE_B(1, 1, t1);
        MMA(0, 0); WAIT_LGKM(); BAR();
        LOAD_B(0, 1);
        if (p2) STAGE_A(0, 0, t2);
        MMA(0, 1); WAIT_LGKM(); BAR();
        LOAD_A(0, 1);
        if (p2) STAGE_B(0, 0, t2);
        MMA(1, 0); WAIT_LGKM(); BAR();
        if (p2) STAGE_A(0, 1, t2);
        MMA(1, 1); WAIT_LGKM_VM6(); BAR();
        LOAD_A(1, 0); LOAD_B(1, 0);
        if (p2) STAGE_B(0, 1, t2);
        MMA(0, 0); WAIT_LGKM(); BAR();
        LOAD_B(1, 1);
        if (p3) STAGE_A(1, 0, t3);
        MMA(0, 1); WAIT_LGKM(); BAR();
        LOAD_A(1, 1);
        if (p3) STAGE_B(1, 0, t3);
        MMA(1, 0); WAIT_LGKM(); BAR();
        if (p3) STAGE_A(1, 1, t3);
        MMA(1, 1); WAIT_LGKM_VM6(); BAR();
    }

    #pragma unroll
    for (int mq = 0; mq < 2; ++mq)
    #pragma unroll
    for (int nq = 0; nq < 2; ++nq)
    #pragma unroll
    for (int mi = 0; mi < 4; ++mi)
    #pragma unroll
    for (int ni = 0; ni < 2; ++ni) {
        int row = row0 + mq * 128 + wm * 64 + mi * 16 + g * 4;
        int col = col0 + nq * 128 + wn * 32 + ni * 16 + ml;
        float bv = bias ? bias[col] : 0.f;
        #pragma unroll
        for (int r = 0; r < 4; ++r) {
            float v = acc[mq][nq][mi][ni][r] + bv;
            if (flags & 1) {
                float ev = __expf(v) - 1.f;
                v = v > 0.f ? v : ev;
            }
            size_t idx = (size_t)(row + r) * ldc + col;
            if (Cb) Cb[idx] = __float2bfloat16(v);
            else    Cf[idx] = v;
        }
    }
}

// ---------------- bf16 MFMA GEMM, 256x192 tile, BK=64 (GEMM2, S=2 -> 256 blocks; bf16 partials out) ----------------
#define SA192(b, kt) do { \
    _Pragma("unroll") for (int q = 0; q < 4; ++q) \
        gload_lds16(gA0 + (size_t)q * lstrA + (size_t)(kt) * 64, dA + (b) * 16384 + q * 4096); \
} while (0)

#define SB192(b, kt) do { \
    _Pragma("unroll") for (int q = 0; q < 3; ++q) \
        gload_lds16(gB0 + (size_t)q * lstrB + (size_t)(kt) * 64, dB + (b) * 12288 + q * 4096); \
} while (0)

#define LA192(b, MQ) do { \
    const short* _p = Asb + (b) * 16384 + arb + (MQ) * (128 * 64); \
    _Pragma("unroll") for (int mi = 0; mi < 4; ++mi) { \
        af[mi][0] = *(const s16x8*)(_p + mi * (16 * 64) + csw0); \
        af[mi][1] = *(const s16x8*)(_p + mi * (16 * 64) + csw1); \
    } \
} while (0)

#define LB192(b) do { \
    const short* _p = Bsb + (b) * 12288 + brb; \
    _Pragma("unroll") for (int ni = 0; ni < 3; ++ni) { \
        bfr[ni][0] = *(const s16x8*)(_p + ni * (16 * 64) + csw0); \
        bfr[ni][1] = *(const s16x8*)(_p + ni * (16 * 64) + csw1); \
    } \
} while (0)

#define MM192(MQ) do { \
    __builtin_amdgcn_s_setprio(1); \
    _Pragma("unroll") for (int ks = 0; ks < 2; ++ks) \
        _Pragma("unroll") for (int mi = 0; mi < 4; ++mi) \
            _Pragma("unroll") for (int ni = 0; ni < 3; ++ni) \
                acc[MQ][mi][ni] = __builtin_amdgcn_mfma_f32_16x16x32_bf16( \
                    af[mi][ks], bfr[ni][ks], acc[MQ][mi][ni], 0, 0, 0); \
    __builtin_amdgcn_s_setprio(0); \
} while (0)

__global__ __launch_bounds__(512, 2) void gemm192_kernel(
    const __hip_bfloat16* __restrict__ A,   // [M][lda]
    const __hip_bfloat16* __restrict__ BT,  // [N][ldb]
    int lda, int ldb, int ldc,
    int K, int kofs_per_z,
    __hip_bfloat16* __restrict__ Cb,        // bf16 partials out
    long bsC,
    int GX, int GY) {
    extern __shared__ __align__(16) short lds[];
    short* Asb = lds;            // [2][256][64] = 32768 shorts
    short* Bsb = lds + 32768;    // [2][192][64] = 24576 shorts

    int lin = blockIdx.x;
    int xcd = lin & 7;
    int u = lin >> 3;
    int bx = u % GX;
    int cg = u / GX;
    int cc = cg * 8 + xcd;
    int by = cc % GY;
    int bz = cc / GY;

    int kofs = bz * kofs_per_z;
    Cb += (size_t)bz * bsC;

    int tid = threadIdx.x;
    int lane = tid & 63;
    int wid = tid >> 6;
    int wm = wid >> 2;      // 0..1
    int wn = wid & 3;       // 0..3
    int ml = lane & 15;
    int g  = lane >> 4;

    int row0 = by * 256;
    int col0 = bx * 192;

    int sr = tid >> 3;
    int scl = (tid & 7) ^ (sr & 7);
    const __hip_bfloat16* gA0 = A + (size_t)(row0 + sr) * lda + kofs + scl * 8;
    const __hip_bfloat16* gB0 = BT + (size_t)(col0 + sr) * ldb + kofs + scl * 8;
    size_t lstrA = (size_t)64 * lda;
    size_t lstrB = (size_t)64 * ldb;
    short* dA = Asb + tid * 8;
    short* dB = Bsb + tid * 8;

    int arb = (wm * 64 + ml) * 64;
    int brb = (wn * 48 + ml) * 64;
    int csw0 = ((g) ^ (ml & 7)) * 8;
    int csw1 = ((4 + g) ^ (ml & 7)) * 8;

    f32x4 acc[2][4][3];
    #pragma unroll
    for (int a0 = 0; a0 < 2; ++a0)
    #pragma unroll
    for (int b0 = 0; b0 < 4; ++b0)
    #pragma unroll
    for (int c0 = 0; c0 < 3; ++c0) acc[a0][b0][c0] = (f32x4){0.f, 0.f, 0.f, 0.f};

    s16x8 af[4][2];
    s16x8 bfr[3][2];

    int nkt = K / 64;  // 48

    SA192(0, 0); SB192(0, 0);
    WAIT_VM0();
    BAR();

    for (int t = 0; t < nkt; ++t) {
        int cur = t & 1;
        if (t + 1 < nkt) { SA192(cur ^ 1, t + 1); SB192(cur ^ 1, t + 1); }
        LA192(cur, 0); LB192(cur);
        WAIT_LGKM();
        MM192(0);
        LA192(cur, 1);
        WAIT_LGKM();
        MM192(1);
        WAIT_VM0();   // next buffer fully landed (stages had the whole iteration)
        BAR();
    }

    #pragma unroll
    for (int mq = 0; mq < 2; ++mq)
    #pragma unroll
    for (int mi = 0; mi < 4; ++mi)
    #pragma unroll
    for (int ni = 0; ni < 3; ++ni) {
        int row = row0 + mq * 128 + wm * 64 + mi * 16 + g * 4;
        int col = col0 + wn * 48 + ni * 16 + ml;
        #pragma unroll
        for (int r = 0; r < 4; ++r) {
            Cb[(size_t)(row + r) * ldc + col] = __float2bfloat16(acc[mq][mi][ni][r]);
        }
    }
}

// ---------------- launch ----------------
extern "C" void kernel_launch(void* const* d_in, const int* in_sizes, int n_in,
                              void* d_out, int out_size, void* d_ws, size_t ws_size,
                              hipStream_t stream) {
    const int N = 8192, E = 65536, DIN = 768, C = 768, H1n = 8;
    const int HC1 = H1n * C;  // 6144

    const float* x    = (const float*)d_in[0];
    const float* W1   = (const float*)d_in[1];
    const float* a_s1 = (const float*)d_in[2];
    const float* a_d1 = (const float*)d_in[3];
    const float* b1   = (const float*)d_in[4];
    const float* W2   = (const float*)d_in[5];
    const float* a_s2 = (const float*)d_in[6];
    const float* a_d2 = (const float*)d_in[7];
    const float* b2   = (const float*)d_in[8];
    const int*   edges = (const int*)d_in[9];
    const int* src = edges;
    const int* dst = edges + E;

    // ---- workspace layout ----
    char* w = (char*)d_ws;
    auto alloc = [&](size_t bytes) -> void* {
        void* p = (void*)w;
        w += (bytes + 255) & ~(size_t)255;
        return p;
    };
    __hip_bfloat16* zAB = (__hip_bfloat16*)alloc((size_t)N * HC1 * 2);      // 100.7 MB
    __hip_bfloat16* o1  = (__hip_bfloat16*)alloc((size_t)N * HC1 * 2);      // 100.7 MB
    ushort4* xb4        = (ushort4*)alloc((size_t)N * DIN * 2);             // 12.6 MB
    ushort4* h2b        = (ushort4*)alloc((size_t)N * C * 2);               // 12.6 MB
    __hip_bfloat16* W1T = (__hip_bfloat16*)alloc((size_t)HC1 * DIN * 2);    // 9.4 MB
    __hip_bfloat16* W2T = (__hip_bfloat16*)alloc((size_t)C * HC1 * 2);      // 9.4 MB
    float* wv      = (float*)alloc((size_t)16 * DIN * 4);
    float* as1     = (float*)alloc((size_t)N * H1n * 4);
    float* ad1     = (float*)alloc((size_t)N * H1n * 4);
    float* e1      = (float*)alloc((size_t)E * H1n * 4);
    float* as2     = (float*)alloc((size_t)N * 4);
    float* ad2     = (float*)alloc((size_t)N * 4);
    float* e2      = (float*)alloc((size_t)E * 4);
    int*   counts  = (int*)alloc((size_t)N * 4);
    int*   cursor  = (int*)alloc((size_t)N * 4);
    int*   row_ofs = (int*)alloc((size_t)(N + 1) * 4);
    int*   perm    = (int*)alloc((size_t)E * 4);

    // split-K bf16 partials (S=2) alias zAB (dead after GEMM1): 2*12.6 = 25 MB << 100 MB
    __hip_bfloat16* partials = zAB;

    (void)hipFuncSetAttribute((const void*)gemm256_kernel,
                              hipFuncAttributeMaxDynamicSharedMemorySize, 131072);
    (void)hipFuncSetAttribute((const void*)gemm192_kernel,
                              hipFuncAttributeMaxDynamicSharedMemorySize, 131072);

    // ---- merged preprocessing: zero + W1/W2 transpose + wvec (one launch) ----
    // 4608 (W1T) + 4608 (W2T) + 1536 (wvec) + 32 (zero) = 10784 blocks
    prep_kernel<<<10784, 256, 0, stream>>>(W1, W2, W1T, W2T, a_s1, a_d1,
                                           wv, wv + 8 * DIN, counts, cursor,
                                           DIN, H1n, C, N);

    // ---- Layer 1 attention coefficients (+ xb4 emission) ----
    alpha16_kernel<<<N / 4, 256, 0, stream>>>((const float4*)x, wv, as1, ad1, xb4);

    // ---- CSR by dst ----
    hist_kernel<<<(E + 255) / 256, 256, 0, stream>>>(dst, counts, E);
    scan_kernel<<<1, SCAN_T, 0, stream>>>(counts, row_ofs, N);
    scatter_kernel<<<(E + 255) / 256, 256, 0, stream>>>(dst, row_ofs, cursor, perm, E);

    // ---- fused softmax + 8-head aggregation: xb -> zAB (bf16) ----
    agg8_fused_kernel<<<N, 192, 0, stream>>>(xb4, as1, ad1, src, row_ofs, perm,
                                             e1, zAB, DIN / 4);

    // ---- GEMM1: all 8 heads; o1 = ELU(z @ W1 + b1) ----
    {
        int GX = C / 256, GY = N / 256;  // 3 x 32 x 8 heads = 768 blocks
        gemm256_kernel<<<GX * GY * H1n, 512, 131072, stream>>>(
            zAB, W1T,
            HC1, DIN, HC1,
            DIN, /*kofs_per_z=*/0,
            b1, o1, nullptr, /*flags=*/1,
            /*bsA=*/C, /*bsBT=*/(long)C * DIN, /*bsC=*/C, /*bsBias=*/C,
            GX, GY);
    }
    // ---- GEMM2: K=6144 split-K S=2 into bf16 partials, BN=192, full machine (256 blocks) ----
    {
        int GX = C / 192, GY = N / 256;  // 4 x 32 x 2 = 256 blocks
        int Kslice = HC1 / 2;            // 3072 -> 48 K-tiles/block
        gemm192_kernel<<<GX * GY * 2, 512, 131072, stream>>>(
            o1, W2T,
            HC1, HC1, C,
            Kslice, /*kofs_per_z=*/Kslice,
            partials, /*bsC=*/(long)N * C,
            GX, GY);
    }

    // ---- fused: h2b = bf16(p0 + p1) ; as2/ad2 = h2 . a_s2 / a_d2 ----
    reduce_dot_kernel<<<N, 192, 0, stream>>>((const ushort4*)partials, (const float4*)a_s2,
                                             (const float4*)a_d2, h2b, as2, ad2, N * C / 4);

    // ---- fused layer-2 softmax + output aggregation ----
    out_fused_kernel<<<N, 192, 0, stream>>>(h2b, as2, ad2, src, row_ofs, perm,
                                            e2, (const float4*)b2, (float4*)d_out, C / 4);
}

// Round 13
// 391.658 us; speedup vs baseline: 4.2057x; 1.0150x over previous
//
#include <hip/hip_runtime.h>
#include <hip/hip_bf16.h>
#include <math.h>

typedef __attribute__((ext_vector_type(4))) float f32x4;
typedef __attribute__((ext_vector_type(8))) short s16x8;

#define MAXD 192  // fast-path degree cap for fused softmax (LDS alpha buffer)

// ---------------- CSR-by-dst construction ----------------

__global__ void hist_kernel(const int* __restrict__ dst, int* __restrict__ counts, int E) {
    int e = blockIdx.x * blockDim.x + threadIdx.x;
    if (e < E) atomicAdd(&counts[dst[e]], 1);
}

#define SCAN_T 1024
__global__ __launch_bounds__(SCAN_T) void scan_kernel(const int* __restrict__ counts,
                                                      int* __restrict__ row_ofs, int Nn) {
    __shared__ int part[SCAN_T];
    int tid = threadIdx.x;
    int chunk = Nn / SCAN_T;
    int base = tid * chunk;
    int sum = 0;
    for (int i = 0; i < chunk; ++i) sum += counts[base + i];
    part[tid] = sum;
    __syncthreads();
    for (int off = 1; off < SCAN_T; off <<= 1) {
        int v = part[tid];
        int u = (tid >= off) ? part[tid - off] : 0;
        __syncthreads();
        part[tid] = v + u;
        __syncthreads();
    }
    if (tid == SCAN_T - 1) row_ofs[Nn] = part[tid];
    int acc = part[tid] - sum;  // exclusive prefix
    for (int i = 0; i < chunk; ++i) { row_ofs[base + i] = acc; acc += counts[base + i]; }
}

__global__ void scatter_kernel(const int* __restrict__ dst, const int* __restrict__ row_ofs,
                               int* __restrict__ cursor, int* __restrict__ perm, int E) {
    int e = blockIdx.x * blockDim.x + threadIdx.x;
    if (e < E) {
        int d = dst[e];
        int pos = atomicAdd(&cursor[d], 1);
        perm[row_ofs[d] + pos] = e;
    }
}

// ---------------- helpers ----------------
__device__ inline unsigned short bf16_bits(float f) {
    __hip_bfloat16 b = __float2bfloat16(f);
    return *reinterpret_cast<unsigned short*>(&b);
}
__device__ inline float bfu(unsigned short u) {
    return __uint_as_float(((unsigned)u) << 16);
}

// ---------------- MERGED preprocessing: zero2 + transpose(W1) + transpose(W2) + wvec ----------------
// (round-11 proven form; no hipMemsetAsync — avoids graph-capture risk)
__device__ inline void transpose_body(const float* __restrict__ src, __hip_bfloat16* __restrict__ dst,
                                      int R, int Cc, int bx, int by, int tx, int ty,
                                      float (*tile)[33]) {
    #pragma unroll
    for (int i = 0; i < 32; i += 8)
        tile[ty + i][tx] = src[(size_t)(by + ty + i) * Cc + (bx + tx)];
    __syncthreads();
    #pragma unroll
    for (int i = 0; i < 32; i += 8)
        dst[(size_t)(bx + ty + i) * R + (by + tx)] = __float2bfloat16(tile[tx][ty + i]);
}

__global__ __launch_bounds__(256) void prep_kernel(
    const float* __restrict__ W1, const float* __restrict__ W2,
    __hip_bfloat16* __restrict__ W1T, __hip_bfloat16* __restrict__ W2T,
    const float* __restrict__ a_s1, const float* __restrict__ a_d1,
    float* __restrict__ w_as, float* __restrict__ w_ad,
    int* __restrict__ counts, int* __restrict__ cursor,
    int DIN, int H, int C, int Nn) {
    __shared__ float tile[32][33];
    int bid = blockIdx.x;
    int tid = threadIdx.x;
    // W1 transpose: src [768][6144], grid 192x24
    if (bid < 4608) {
        int bx = (bid % 192) * 32;
        int by = (bid / 192) * 32;
        transpose_body(W1, W1T, DIN, H * C, bx, by, tid & 31, tid >> 5, tile);
        return;
    }
    bid -= 4608;
    // W2 transpose: src [6144][768], grid 24x192
    if (bid < 4608) {
        int bx = (bid % 24) * 32;
        int by = (bid / 24) * 32;
        transpose_body(W2, W2T, H * C, C, bx, by, tid & 31, tid >> 5, tile);
        return;
    }
    bid -= 4608;
    // wvec: 1536 blocks x 256 = 6144 waves, one per (h,i)
    if (bid < 1536) {
        int gid = bid * 256 + tid;
        int wid = gid >> 6;
        int lane = tid & 63;
        if (wid >= H * DIN) return;
        int h = wid / DIN, i = wid % DIN;
        const float* wp = W1 + (size_t)i * H * C + (size_t)h * C;
        const float* sp = a_s1 + (size_t)h * C;
        const float* dp = a_d1 + (size_t)h * C;
        float ss = 0.f, sd = 0.f;
        for (int c = lane; c < C; c += 64) {
            float v = wp[c];
            ss += v * sp[c];
            sd += v * dp[c];
        }
        #pragma unroll
        for (int off = 32; off > 0; off >>= 1) {
            ss += __shfl_down(ss, off, 64);
            sd += __shfl_down(sd, off, 64);
        }
        if (lane == 0) { w_as[wid] = ss; w_ad[wid] = sd; }
        return;
    }
    bid -= 1536;
    // zero counts/cursor: 32 blocks
    {
        int i = bid * 256 + tid;
        if (i < Nn) { counts[i] = 0; cursor[i] = 0; }
    }
}

// ---------------- layer-1 alpha dots + xb4 emission; one wave per node ----------------
__global__ __launch_bounds__(256) void alpha16_kernel(const float4* __restrict__ x4,
                                                      const float* __restrict__ wv,
                                                      float* __restrict__ as_out,
                                                      float* __restrict__ ad_out,
                                                      ushort4* __restrict__ xb4) {
    __shared__ float ws[16 * 768];
    int tid = threadIdx.x;
    #pragma unroll
    for (int i = 0; i < 12; ++i)
        ((float4*)ws)[tid + i * 256] = ((const float4*)wv)[tid + i * 256];
    __syncthreads();
    int wvid = tid >> 6, lane = tid & 63;
    int n = blockIdx.x * 4 + wvid;
    float4 xr[3];
    #pragma unroll
    for (int r = 0; r < 3; ++r) xr[r] = x4[(size_t)n * 192 + lane + 64 * r];
    // emit bf16 copy of x (saves a separate conversion pass)
    #pragma unroll
    for (int r = 0; r < 3; ++r) {
        ushort4 o;
        o.x = bf16_bits(xr[r].x); o.y = bf16_bits(xr[r].y);
        o.z = bf16_bits(xr[r].z); o.w = bf16_bits(xr[r].w);
        xb4[(size_t)n * 192 + lane + 64 * r] = o;
    }
    #pragma unroll
    for (int j = 0; j < 16; ++j) {
        const float4* wj = (const float4*)(ws + j * 768);
        float s = 0.f;
        #pragma unroll
        for (int r = 0; r < 3; ++r) {
            float4 wc = wj[lane + 64 * r];
            s += xr[r].x * wc.x + xr[r].y * wc.y + xr[r].z * wc.z + xr[r].w * wc.w;
        }
        #pragma unroll
        for (int off = 32; off > 0; off >>= 1) s += __shfl_down(s, off, 64);
        if (lane == 0) {
            if (j < 8) as_out[n * 8 + j] = s;
            else       ad_out[n * 8 + (j - 8)] = s;
        }
    }
}

// ---------------- FUSED: per-node softmax (8 heads) + 8-head aggregation -> zAB bf16 ----------------
__global__ __launch_bounds__(192) void agg8_fused_kernel(
    const ushort4* __restrict__ xb4,  // [N][192] bf16 x (gather-halved)
    const float* __restrict__ as1,    // [N][8]
    const float* __restrict__ ad1,    // [N][8]
    const int* __restrict__ src,
    const int* __restrict__ row_ofs,
    const int* __restrict__ perm,
    float* __restrict__ e1g,          // [E][8] global fallback alpha
    __hip_bfloat16* __restrict__ zAB, // [N][8*768]
    int D4) {
    __shared__ float alds[MAXD * 8];
    __shared__ float mh[8], dh[8];
    int n = blockIdx.x;
    int s = row_ofs[n], t = row_ofs[n + 1];
    int d = t - s;
    int tid = threadIdx.x;
    bool big = d > MAXD;
    if (!big) {
        int eh = tid & 7, ei = tid >> 3;  // ei in 0..23
        float adn = ad1[n * 8 + eh];
        for (int base = 0; base < d; base += 24) {
            int j = base + ei;
            if (j < d) {
                int e = perm[s + j];
                float v = as1[src[e] * 8 + eh] + adn;
                v = v > 0.f ? v : 0.2f * v;
                alds[j * 8 + eh] = v;
            }
        }
        __syncthreads();
        if (tid < 8) {
            float m = -INFINITY;
            for (int j = 0; j < d; ++j) m = fmaxf(m, alds[j * 8 + tid]);
            float den = 0.f;
            for (int j = 0; j < d; ++j) den += __expf(alds[j * 8 + tid] - m);
            mh[tid] = m; dh[tid] = 1.f / (den + 1e-16f);
        }
        __syncthreads();
        for (int base = 0; base < d; base += 24) {
            int j = base + ei;
            if (j < d) alds[j * 8 + eh] = __expf(alds[j * 8 + eh] - mh[eh]) * dh[eh];
        }
        __syncthreads();
    } else {
        if (tid < 8) {
            int hh = tid;
            float adn = ad1[n * 8 + hh];
            float m = -INFINITY;
            for (int j = s; j < t; ++j) {
                float v = as1[src[perm[j]] * 8 + hh] + adn;
                v = v > 0.f ? v : 0.2f * v;
                m = fmaxf(m, v);
            }
            float den = 0.f;
            for (int j = s; j < t; ++j) {
                float v = as1[src[perm[j]] * 8 + hh] + adn;
                v = v > 0.f ? v : 0.2f * v;
                den += __expf(v - m);
            }
            float inv = 1.f / (den + 1e-16f);
            for (int j = s; j < t; ++j) {
                int e = perm[j];
                float v = as1[src[e] * 8 + hh] + adn;
                v = v > 0.f ? v : 0.2f * v;
                e1g[(size_t)e * 8 + hh] = __expf(v - m) * inv;
            }
        }
        __syncthreads();
    }

    // aggregation: thread j handles bf16x4 column j for all 8 heads.
    // 2-wide edge loop (proven form; 4-wide unroll measured -10us from reg pressure).
    int j = tid;
    float4 acc[8];
    #pragma unroll
    for (int h = 0; h < 8; ++h) acc[h] = make_float4(0.f, 0.f, 0.f, 0.f);
    int k = s;
    for (; k + 1 < t; k += 2) {
        int e0 = perm[k], e1 = perm[k + 1];
        ushort4 u0 = xb4[(size_t)src[e0] * D4 + j];
        ushort4 u1 = xb4[(size_t)src[e1] * D4 + j];
        float4 v0 = make_float4(bfu(u0.x), bfu(u0.y), bfu(u0.z), bfu(u0.w));
        float4 v1 = make_float4(bfu(u1.x), bfu(u1.y), bfu(u1.z), bfu(u1.w));
        const float* a0 = big ? &e1g[(size_t)e0 * 8] : &alds[(k - s) * 8];
        const float* a1 = big ? &e1g[(size_t)e1 * 8] : &alds[(k + 1 - s) * 8];
        #pragma unroll
        for (int h = 0; h < 8; ++h) {
            float a = a0[h], b = a1[h];
            acc[h].x += a * v0.x + b * v1.x;
            acc[h].y += a * v0.y + b * v1.y;
            acc[h].z += a * v0.z + b * v1.z;
            acc[h].w += a * v0.w + b * v1.w;
        }
    }
    if (k < t) {
        int e0 = perm[k];
        ushort4 u0 = xb4[(size_t)src[e0] * D4 + j];
        float4 v0 = make_float4(bfu(u0.x), bfu(u0.y), bfu(u0.z), bfu(u0.w));
        const float* a0 = big ? &e1g[(size_t)e0 * 8] : &alds[(k - s) * 8];
        #pragma unroll
        for (int h = 0; h < 8; ++h) {
            float a = a0[h];
            acc[h].x += a * v0.x; acc[h].y += a * v0.y;
            acc[h].z += a * v0.z; acc[h].w += a * v0.w;
        }
    }
    int D = D4 * 4;
    #pragma unroll
    for (int h = 0; h < 8; ++h) {
        size_t o = (size_t)n * 8 * D + (size_t)h * D + j * 4;
        ushort4 st;
        st.x = bf16_bits(acc[h].x); st.y = bf16_bits(acc[h].y);
        st.z = bf16_bits(acc[h].z); st.w = bf16_bits(acc[h].w);
        *reinterpret_cast<ushort4*>(&zAB[o]) = st;
    }
}

// ---------------- FUSED: layer-2 softmax (H=1) + output aggregation (+bias) ----------------
__global__ __launch_bounds__(192) void out_fused_kernel(
    const ushort4* __restrict__ featb,  // h2b [N][192] bf16 (gather-halved)
    const float* __restrict__ as2,      // [N]
    const float* __restrict__ ad2,      // [N]
    const int* __restrict__ src,
    const int* __restrict__ row_ofs,
    const int* __restrict__ perm,
    float* __restrict__ e2g,            // [E] global fallback alpha
    const float4* __restrict__ bias4,
    float4* __restrict__ out4, int D4) {
    __shared__ float alds[MAXD];
    __shared__ float minv[2];
    int n = blockIdx.x;
    int s = row_ofs[n], t = row_ofs[n + 1];
    int d = t - s;
    int tid = threadIdx.x;
    bool big = d > MAXD;
    if (!big) {
        float adn = ad2[n];
        if (tid < d) {
            float v = as2[src[perm[s + tid]]] + adn;
            v = v > 0.f ? v : 0.2f * v;
            alds[tid] = v;
        }
        __syncthreads();
        if (tid == 0) {
            float m = -INFINITY;
            for (int j = 0; j < d; ++j) m = fmaxf(m, alds[j]);
            float den = 0.f;
            for (int j = 0; j < d; ++j) den += __expf(alds[j] - m);
            minv[0] = m; minv[1] = 1.f / (den + 1e-16f);
        }
        __syncthreads();
        if (tid < d) alds[tid] = __expf(alds[tid] - minv[0]) * minv[1];
        __syncthreads();
    } else {
        if (tid == 0) {
            float adn = ad2[n];
            float m = -INFINITY;
            for (int j = s; j < t; ++j) {
                float v = as2[src[perm[j]]] + adn;
                v = v > 0.f ? v : 0.2f * v;
                m = fmaxf(m, v);
            }
            float den = 0.f;
            for (int j = s; j < t; ++j) {
                float v = as2[src[perm[j]]] + adn;
                v = v > 0.f ? v : 0.2f * v;
                den += __expf(v - m);
            }
            float inv = 1.f / (den + 1e-16f);
            for (int j = s; j < t; ++j) {
                int e = perm[j];
                float v = as2[src[e]] + adn;
                v = v > 0.f ? v : 0.2f * v;
                e2g[e] = __expf(v - m) * inv;
            }
        }
        __syncthreads();
    }

    int j = tid;
    float4 acc = make_float4(0.f, 0.f, 0.f, 0.f);
    int k = s;
    for (; k + 1 < t; k += 2) {
        int e0 = perm[k], e1 = perm[k + 1];
        float a = big ? e2g[e0] : alds[k - s];
        float b = big ? e2g[e1] : alds[k + 1 - s];
        ushort4 u0 = featb[(size_t)src[e0] * D4 + j];
        ushort4 u1 = featb[(size_t)src[e1] * D4 + j];
        acc.x += a * bfu(u0.x) + b * bfu(u1.x);
        acc.y += a * bfu(u0.y) + b * bfu(u1.y);
        acc.z += a * bfu(u0.z) + b * bfu(u1.z);
        acc.w += a * bfu(u0.w) + b * bfu(u1.w);
    }
    if (k < t) {
        int e0 = perm[k];
        float a = big ? e2g[e0] : alds[k - s];
        ushort4 u0 = featb[(size_t)src[e0] * D4 + j];
        acc.x += a * bfu(u0.x); acc.y += a * bfu(u0.y);
        acc.z += a * bfu(u0.z); acc.w += a * bfu(u0.w);
    }
    float4 b = bias4[j];
    acc.x += b.x; acc.y += b.y; acc.z += b.z; acc.w += b.w;
    out4[(size_t)n * D4 + j] = acc;
}

// ---------------- fused: h2 = p0+p1 (split-K S=2, bf16 partials) ; as2/ad2 dots ----------------
__global__ __launch_bounds__(192) void reduce_dot_kernel(
    const ushort4* __restrict__ parts,  // [2][N][192] bf16x4
    const float4* __restrict__ as_w, const float4* __restrict__ ad_w,
    ushort4* __restrict__ h2b,          // [N][192] bf16 out
    float* __restrict__ as_out, float* __restrict__ ad_out, int NC4) {
    int n = blockIdx.x;
    int j = threadIdx.x;
    size_t idx = (size_t)n * 192 + j;
    ushort4 q0 = parts[idx];
    ushort4 q1 = parts[(size_t)NC4 + idx];
    float4 a;
    a.x = bfu(q0.x) + bfu(q1.x);
    a.y = bfu(q0.y) + bfu(q1.y);
    a.z = bfu(q0.z) + bfu(q1.z);
    a.w = bfu(q0.w) + bfu(q1.w);
    ushort4 st;
    st.x = bf16_bits(a.x); st.y = bf16_bits(a.y);
    st.z = bf16_bits(a.z); st.w = bf16_bits(a.w);
    h2b[idx] = st;
    float4 ws = as_w[j], wd = ad_w[j];
    float ss = a.x * ws.x + a.y * ws.y + a.z * ws.z + a.w * ws.w;
    float sd = a.x * wd.x + a.y * wd.y + a.z * wd.z + a.w * wd.w;
    #pragma unroll
    for (int off = 32; off > 0; off >>= 1) {
        ss += __shfl_down(ss, off, 64);
        sd += __shfl_down(sd, off, 64);
    }
    __shared__ float red_s[3], red_d[3];
    int wv = j >> 6, lane = j & 63;
    if (lane == 0) { red_s[wv] = ss; red_d[wv] = sd; }
    __syncthreads();
    if (j == 0) {
        as_out[n] = red_s[0] + red_s[1] + red_s[2];
        ad_out[n] = red_d[0] + red_d[1] + red_d[2];
    }
}

// ---------------- shared GEMM machinery ----------------
__device__ inline void gload_lds16(const void* g, void* l) {
    __builtin_amdgcn_global_load_lds((const __attribute__((address_space(1))) unsigned int*)g,
                                     (__attribute__((address_space(3))) unsigned int*)l, 16, 0, 0);
}

#define FENCE() asm volatile("" ::: "memory")
#define BAR() do { FENCE(); __builtin_amdgcn_s_barrier(); FENCE(); } while (0)
#define WAIT_LGKM() asm volatile("s_waitcnt lgkmcnt(0)" ::: "memory")
#define WAIT_VM0() asm volatile("s_waitcnt vmcnt(0)" ::: "memory")

// ---------------- bf16 MFMA GEMM, 256x192 tile, BK=64, 2-phase (generalized: bias/ELU/bz-strides) ----------------
// Session finding: this 48-tiles-per-CU configuration (2-phase, 1 fill per block, full-machine
// rounds) sustains ~1.98us/K-tile vs gemm256's ~2.9 — now serves BOTH GEMMs:
//   GEMM1: GX=4,GY=32,GZ=8 (1024 blocks, 12 tiles each) = 48 tiles/CU, bias+ELU epilogue.
//   GEMM2: GX=4,GY=32,GZ=2 (256 blocks, 48 tiles each) = 48 tiles/CU, raw bf16 partials.
// K-accumulation order per output element identical to gemm256 -> bit-identical results.
#define SA192(b, kt) do { \
    _Pragma("unroll") for (int q = 0; q < 4; ++q) \
        gload_lds16(gA0 + (size_t)q * lstrA + (size_t)(kt) * 64, dA + (b) * 16384 + q * 4096); \
} while (0)

#define SB192(b, kt) do { \
    _Pragma("unroll") for (int q = 0; q < 3; ++q) \
        gload_lds16(gB0 + (size_t)q * lstrB + (size_t)(kt) * 64, dB + (b) * 12288 + q * 4096); \
} while (0)

#define LA192(b, MQ) do { \
    const short* _p = Asb + (b) * 16384 + arb + (MQ) * (128 * 64); \
    _Pragma("unroll") for (int mi = 0; mi < 4; ++mi) { \
        af[mi][0] = *(const s16x8*)(_p + mi * (16 * 64) + csw0); \
        af[mi][1] = *(const s16x8*)(_p + mi * (16 * 64) + csw1); \
    } \
} while (0)

#define LB192(b) do { \
    const short* _p = Bsb + (b) * 12288 + brb; \
    _Pragma("unroll") for (int ni = 0; ni < 3; ++ni) { \
        bfr[ni][0] = *(const s16x8*)(_p + ni * (16 * 64) + csw0); \
        bfr[ni][1] = *(const s16x8*)(_p + ni * (16 * 64) + csw1); \
    } \
} while (0)

#define MM192(MQ) do { \
    __builtin_amdgcn_s_setprio(1); \
    _Pragma("unroll") for (int ks = 0; ks < 2; ++ks) \
        _Pragma("unroll") for (int mi = 0; mi < 4; ++mi) \
            _Pragma("unroll") for (int ni = 0; ni < 3; ++ni) \
                acc[MQ][mi][ni] = __builtin_amdgcn_mfma_f32_16x16x32_bf16( \
                    af[mi][ks], bfr[ni][ks], acc[MQ][mi][ni], 0, 0, 0); \
    __builtin_amdgcn_s_setprio(0); \
} while (0)

__global__ __launch_bounds__(512, 2) void gemm192_kernel(
    const __hip_bfloat16* __restrict__ A,   // [M][lda]
    const __hip_bfloat16* __restrict__ BT,  // [N][ldb]
    int lda, int ldb, int ldc,
    int K, int kofs_per_z,
    const float* __restrict__ bias,
    __hip_bfloat16* __restrict__ Cb,        // bf16 out
    int flags,                              // 1 = elu
    long bsA, long bsBT, long bsC, long bsBias,
    int GX, int GY) {
    extern __shared__ __align__(16) short lds[];
    short* Asb = lds;            // [2][256][64] = 32768 shorts
    short* Bsb = lds + 32768;    // [2][192][64] = 24576 shorts

    int lin = blockIdx.x;
    int xcd = lin & 7;
    int u = lin >> 3;
    int bx = u % GX;
    int cg = u / GX;
    int cc = cg * 8 + xcd;
    int by = cc % GY;
    int bz = cc / GY;

    int kofs = bz * kofs_per_z;
    A += (size_t)bz * bsA;
    BT += (size_t)bz * bsBT;
    Cb += (size_t)bz * bsC;
    if (bias) bias += (size_t)bz * bsBias;

    int tid = threadIdx.x;
    int lane = tid & 63;
    int wid = tid >> 6;
    int wm = wid >> 2;      // 0..1
    int wn = wid & 3;       // 0..3
    int ml = lane & 15;
    int g  = lane >> 4;

    int row0 = by * 256;
    int col0 = bx * 192;

    int sr = tid >> 3;
    int scl = (tid & 7) ^ (sr & 7);
    const __hip_bfloat16* gA0 = A + (size_t)(row0 + sr) * lda + kofs + scl * 8;
    const __hip_bfloat16* gB0 = BT + (size_t)(col0 + sr) * ldb + kofs + scl * 8;
    size_t lstrA = (size_t)64 * lda;
    size_t lstrB = (size_t)64 * ldb;
    short* dA = Asb + tid * 8;
    short* dB = Bsb + tid * 8;

    int arb = (wm * 64 + ml) * 64;
    int brb = (wn * 48 + ml) * 64;
    int csw0 = ((g) ^ (ml & 7)) * 8;
    int csw1 = ((4 + g) ^ (ml & 7)) * 8;

    f32x4 acc[2][4][3];
    #pragma unroll
    for (int a0 = 0; a0 < 2; ++a0)
    #pragma unroll
    for (int b0 = 0; b0 < 4; ++b0)
    #pragma unroll
    for (int c0 = 0; c0 < 3; ++c0) acc[a0][b0][c0] = (f32x4){0.f, 0.f, 0.f, 0.f};

    s16x8 af[4][2];
    s16x8 bfr[3][2];

    int nkt = K / 64;

    SA192(0, 0); SB192(0, 0);
    WAIT_VM0();
    BAR();

    for (int t = 0; t < nkt; ++t) {
        int cur = t & 1;
        if (t + 1 < nkt) { SA192(cur ^ 1, t + 1); SB192(cur ^ 1, t + 1); }
        LA192(cur, 0); LB192(cur);
        WAIT_LGKM();
        MM192(0);
        LA192(cur, 1);
        WAIT_LGKM();
        MM192(1);
        WAIT_VM0();   // next buffer fully landed (stages had the whole iteration)
        BAR();
    }

    #pragma unroll
    for (int mq = 0; mq < 2; ++mq)
    #pragma unroll
    for (int mi = 0; mi < 4; ++mi)
    #pragma unroll
    for (int ni = 0; ni < 3; ++ni) {
        int row = row0 + mq * 128 + wm * 64 + mi * 16 + g * 4;
        int col = col0 + wn * 48 + ni * 16 + ml;
        float bv = bias ? bias[col] : 0.f;
        #pragma unroll
        for (int r = 0; r < 4; ++r) {
            float v = acc[mq][mi][ni][r] + bv;
            if (flags & 1) {
                float ev = __expf(v) - 1.f;  // elu (select, no branch)
                v = v > 0.f ? v : ev;
            }
            Cb[(size_t)(row + r) * ldc + col] = __float2bfloat16(v);
        }
    }
}

// ---------------- launch ----------------
extern "C" void kernel_launch(void* const* d_in, const int* in_sizes, int n_in,
                              void* d_out, int out_size, void* d_ws, size_t ws_size,
                              hipStream_t stream) {
    const int N = 8192, E = 65536, DIN = 768, C = 768, H1n = 8;
    const int HC1 = H1n * C;  // 6144

    const float* x    = (const float*)d_in[0];
    const float* W1   = (const float*)d_in[1];
    const float* a_s1 = (const float*)d_in[2];
    const float* a_d1 = (const float*)d_in[3];
    const float* b1   = (const float*)d_in[4];
    const float* W2   = (const float*)d_in[5];
    const float* a_s2 = (const float*)d_in[6];
    const float* a_d2 = (const float*)d_in[7];
    const float* b2   = (const float*)d_in[8];
    const int*   edges = (const int*)d_in[9];
    const int* src = edges;
    const int* dst = edges + E;

    // ---- workspace layout ----
    char* w = (char*)d_ws;
    auto alloc = [&](size_t bytes) -> void* {
        void* p = (void*)w;
        w += (bytes + 255) & ~(size_t)255;
        return p;
    };
    __hip_bfloat16* zAB = (__hip_bfloat16*)alloc((size_t)N * HC1 * 2);      // 100.7 MB
    __hip_bfloat16* o1  = (__hip_bfloat16*)alloc((size_t)N * HC1 * 2);      // 100.7 MB
    ushort4* xb4        = (ushort4*)alloc((size_t)N * DIN * 2);             // 12.6 MB
    ushort4* h2b        = (ushort4*)alloc((size_t)N * C * 2);               // 12.6 MB
    __hip_bfloat16* W1T = (__hip_bfloat16*)alloc((size_t)HC1 * DIN * 2);    // 9.4 MB
    __hip_bfloat16* W2T = (__hip_bfloat16*)alloc((size_t)C * HC1 * 2);      // 9.4 MB
    float* wv      = (float*)alloc((size_t)16 * DIN * 4);
    float* as1     = (float*)alloc((size_t)N * H1n * 4);
    float* ad1     = (float*)alloc((size_t)N * H1n * 4);
    float* e1      = (float*)alloc((size_t)E * H1n * 4);
    float* as2     = (float*)alloc((size_t)N * 4);
    float* ad2     = (float*)alloc((size_t)N * 4);
    float* e2      = (float*)alloc((size_t)E * 4);
    int*   counts  = (int*)alloc((size_t)N * 4);
    int*   cursor  = (int*)alloc((size_t)N * 4);
    int*   row_ofs = (int*)alloc((size_t)(N + 1) * 4);
    int*   perm    = (int*)alloc((size_t)E * 4);

    // split-K bf16 partials (S=2) alias zAB (dead after GEMM1): 25 MB << 100 MB
    __hip_bfloat16* partials = zAB;

    (void)hipFuncSetAttribute((const void*)gemm192_kernel,
                              hipFuncAttributeMaxDynamicSharedMemorySize, 131072);

    // ---- merged preprocessing: zero + W1/W2 transpose + wvec (one launch) ----
    // 4608 (W1T) + 4608 (W2T) + 1536 (wvec) + 32 (zero) = 10784 blocks
    prep_kernel<<<10784, 256, 0, stream>>>(W1, W2, W1T, W2T, a_s1, a_d1,
                                           wv, wv + 8 * DIN, counts, cursor,
                                           DIN, H1n, C, N);

    // ---- Layer 1 attention coefficients (+ xb4 emission) ----
    alpha16_kernel<<<N / 4, 256, 0, stream>>>((const float4*)x, wv, as1, ad1, xb4);

    // ---- CSR by dst ----
    hist_kernel<<<(E + 255) / 256, 256, 0, stream>>>(dst, counts, E);
    scan_kernel<<<1, SCAN_T, 0, stream>>>(counts, row_ofs, N);
    scatter_kernel<<<(E + 255) / 256, 256, 0, stream>>>(dst, row_ofs, cursor, perm, E);

    // ---- fused softmax + 8-head aggregation: xb -> zAB (bf16) ----
    agg8_fused_kernel<<<N, 192, 0, stream>>>(xb4, as1, ad1, src, row_ofs, perm,
                                             e1, zAB, DIN / 4);

    // ---- GEMM1: all 8 heads; o1 = ELU(z @ W1 + b1); 4x32x8 = 1024 blocks (48 tiles/CU) ----
    {
        int GX = C / 192, GY = N / 256;  // 4 x 32, GZ = 8 heads
        gemm192_kernel<<<GX * GY * H1n, 512, 131072, stream>>>(
            zAB, W1T,
            HC1, DIN, HC1,
            DIN, /*kofs_per_z=*/0,
            b1, o1, /*flags=*/1,
            /*bsA=*/C, /*bsBT=*/(long)C * DIN, /*bsC=*/C, /*bsBias=*/C,
            GX, GY);
    }
    // ---- GEMM2: K=6144 split-K S=2 into bf16 partials; 4x32x2 = 256 blocks ----
    {
        int GX = C / 192, GY = N / 256;  // 4 x 32, GZ = 2
        int Kslice = HC1 / 2;            // 3072 -> 48 K-tiles/block
        gemm192_kernel<<<GX * GY * 2, 512, 131072, stream>>>(
            o1, W2T,
            HC1, HC1, C,
            Kslice, /*kofs_per_z=*/Kslice,
            nullptr, partials, /*flags=*/0,
            /*bsA=*/0, /*bsBT=*/0, /*bsC=*/(long)N * C, /*bsBias=*/0,
            GX, GY);
    }

    // ---- fused: h2b = bf16(p0 + p1) ; as2/ad2 = h2 . a_s2 / a_d2 ----
    reduce_dot_kernel<<<N, 192, 0, stream>>>((const ushort4*)partials, (const float4*)a_s2,
                                             (const float4*)a_d2, h2b, as2, ad2, N * C / 4);

    // ---- fused layer-2 softmax + output aggregation ----
    out_fused_kernel<<<N, 192, 0, stream>>>(h2b, as2, ad2, src, row_ofs, perm,
                                            e2, (const float4*)b2, (float4*)d_out, C / 4);
}

// Round 14
// 380.685 us; speedup vs baseline: 4.3269x; 1.0288x over previous
//
#include <hip/hip_runtime.h>
#include <hip/hip_bf16.h>
#include <math.h>

typedef __attribute__((ext_vector_type(4))) float f32x4;
typedef __attribute__((ext_vector_type(8))) short s16x8;

#define MAXD 192  // fast-path degree cap for fused softmax (LDS alpha buffer)

#define SCAN_T 1024
__global__ __launch_bounds__(SCAN_T) void scan_kernel(const int* __restrict__ counts,
                                                      int* __restrict__ row_ofs, int Nn) {
    __shared__ int part[SCAN_T];
    int tid = threadIdx.x;
    int chunk = Nn / SCAN_T;
    int base = tid * chunk;
    int sum = 0;
    for (int i = 0; i < chunk; ++i) sum += counts[base + i];
    part[tid] = sum;
    __syncthreads();
    for (int off = 1; off < SCAN_T; off <<= 1) {
        int v = part[tid];
        int u = (tid >= off) ? part[tid - off] : 0;
        __syncthreads();
        part[tid] = v + u;
        __syncthreads();
    }
    if (tid == SCAN_T - 1) row_ofs[Nn] = part[tid];
    int acc = part[tid] - sum;  // exclusive prefix
    for (int i = 0; i < chunk; ++i) { row_ofs[base + i] = acc; acc += counts[base + i]; }
}

// scatter + pre-gathered src index (sperm[slot] = src[e]) — removes one dependent-load
// level from every edge gather downstream (perm->src->row becomes sperm->row).
__global__ void scatter_kernel(const int* __restrict__ dst, const int* __restrict__ src,
                               const int* __restrict__ row_ofs,
                               int* __restrict__ cursor, int* __restrict__ perm,
                               int* __restrict__ sperm, int E) {
    int e = blockIdx.x * blockDim.x + threadIdx.x;
    if (e < E) {
        int d = dst[e];
        int pos = atomicAdd(&cursor[d], 1);
        int slot = row_ofs[d] + pos;
        perm[slot] = e;
        sperm[slot] = src[e];
    }
}

// ---------------- helpers ----------------
__device__ inline unsigned short bf16_bits(float f) {
    __hip_bfloat16 b = __float2bfloat16(f);
    return *reinterpret_cast<unsigned short*>(&b);
}
__device__ inline float bfu(unsigned short u) {
    return __uint_as_float(((unsigned)u) << 16);
}

// ---------------- MERGED preprocessing: zero2 + transpose(W1) + transpose(W2) + wvec ----------------
__device__ inline void transpose_body(const float* __restrict__ src, __hip_bfloat16* __restrict__ dst,
                                      int R, int Cc, int bx, int by, int tx, int ty,
                                      float (*tile)[33]) {
    #pragma unroll
    for (int i = 0; i < 32; i += 8)
        tile[ty + i][tx] = src[(size_t)(by + ty + i) * Cc + (bx + tx)];
    __syncthreads();
    #pragma unroll
    for (int i = 0; i < 32; i += 8)
        dst[(size_t)(bx + ty + i) * R + (by + tx)] = __float2bfloat16(tile[tx][ty + i]);
}

__global__ __launch_bounds__(256) void prep_kernel(
    const float* __restrict__ W1, const float* __restrict__ W2,
    __hip_bfloat16* __restrict__ W1T, __hip_bfloat16* __restrict__ W2T,
    const float* __restrict__ a_s1, const float* __restrict__ a_d1,
    float* __restrict__ w_as, float* __restrict__ w_ad,
    int* __restrict__ counts, int* __restrict__ cursor,
    int DIN, int H, int C, int Nn) {
    __shared__ float tile[32][33];
    int bid = blockIdx.x;
    int tid = threadIdx.x;
    // W1 transpose: src [768][6144], grid 192x24
    if (bid < 4608) {
        int bx = (bid % 192) * 32;
        int by = (bid / 192) * 32;
        transpose_body(W1, W1T, DIN, H * C, bx, by, tid & 31, tid >> 5, tile);
        return;
    }
    bid -= 4608;
    // W2 transpose: src [6144][768], grid 24x192
    if (bid < 4608) {
        int bx = (bid % 24) * 32;
        int by = (bid / 24) * 32;
        transpose_body(W2, W2T, H * C, C, bx, by, tid & 31, tid >> 5, tile);
        return;
    }
    bid -= 4608;
    // wvec: 1536 blocks x 256 = 6144 waves, one per (h,i)
    if (bid < 1536) {
        int gid = bid * 256 + tid;
        int wid = gid >> 6;
        int lane = tid & 63;
        if (wid >= H * DIN) return;
        int h = wid / DIN, i = wid % DIN;
        const float* wp = W1 + (size_t)i * H * C + (size_t)h * C;
        const float* sp = a_s1 + (size_t)h * C;
        const float* dp = a_d1 + (size_t)h * C;
        float ss = 0.f, sd = 0.f;
        for (int c = lane; c < C; c += 64) {
            float v = wp[c];
            ss += v * sp[c];
            sd += v * dp[c];
        }
        #pragma unroll
        for (int off = 32; off > 0; off >>= 1) {
            ss += __shfl_down(ss, off, 64);
            sd += __shfl_down(sd, off, 64);
        }
        if (lane == 0) { w_as[wid] = ss; w_ad[wid] = sd; }
        return;
    }
    bid -= 1536;
    // zero counts/cursor: 32 blocks
    {
        int i = bid * 256 + tid;
        if (i < Nn) { counts[i] = 0; cursor[i] = 0; }
    }
}

// ---------------- layer-1 alpha dots + xb4 emission (+ merged hist range) ----------------
// Blocks [0,2048): alpha16 body (one wave per node). Blocks [2048,2304): hist atomics
// (counts zeroed by the preceding prep launch; ranges independent).
__global__ __launch_bounds__(256) void alpha16_kernel(const float4* __restrict__ x4,
                                                      const float* __restrict__ wv,
                                                      float* __restrict__ as_out,
                                                      float* __restrict__ ad_out,
                                                      ushort4* __restrict__ xb4,
                                                      const int* __restrict__ dst,
                                                      int* __restrict__ counts, int E) {
    int bid = blockIdx.x;
    int tid = threadIdx.x;
    if (bid >= 2048) {
        int e = (bid - 2048) * 256 + tid;
        if (e < E) atomicAdd(&counts[dst[e]], 1);
        return;
    }
    __shared__ float ws[16 * 768];
    #pragma unroll
    for (int i = 0; i < 12; ++i)
        ((float4*)ws)[tid + i * 256] = ((const float4*)wv)[tid + i * 256];
    __syncthreads();
    int wvid = tid >> 6, lane = tid & 63;
    int n = bid * 4 + wvid;
    float4 xr[3];
    #pragma unroll
    for (int r = 0; r < 3; ++r) xr[r] = x4[(size_t)n * 192 + lane + 64 * r];
    // emit bf16 copy of x (saves a separate conversion pass)
    #pragma unroll
    for (int r = 0; r < 3; ++r) {
        ushort4 o;
        o.x = bf16_bits(xr[r].x); o.y = bf16_bits(xr[r].y);
        o.z = bf16_bits(xr[r].z); o.w = bf16_bits(xr[r].w);
        xb4[(size_t)n * 192 + lane + 64 * r] = o;
    }
    #pragma unroll
    for (int j = 0; j < 16; ++j) {
        const float4* wj = (const float4*)(ws + j * 768);
        float s = 0.f;
        #pragma unroll
        for (int r = 0; r < 3; ++r) {
            float4 wc = wj[lane + 64 * r];
            s += xr[r].x * wc.x + xr[r].y * wc.y + xr[r].z * wc.z + xr[r].w * wc.w;
        }
        #pragma unroll
        for (int off = 32; off > 0; off >>= 1) s += __shfl_down(s, off, 64);
        if (lane == 0) {
            if (j < 8) as_out[n * 8 + j] = s;
            else       ad_out[n * 8 + (j - 8)] = s;
        }
    }
}

// ---------------- FUSED: per-node softmax (8 heads) + 8-head aggregation -> zAB bf16 ----------------
__global__ __launch_bounds__(192) void agg8_fused_kernel(
    const ushort4* __restrict__ xb4,  // [N][192] bf16 x (gather-halved)
    const float* __restrict__ as1,    // [N][8]
    const float* __restrict__ ad1,    // [N][8]
    const int* __restrict__ row_ofs,
    const int* __restrict__ perm,     // edge ids (big-path e1g indexing only)
    const int* __restrict__ sperm,    // pre-gathered src node ids
    float* __restrict__ e1g,          // [E][8] global fallback alpha
    __hip_bfloat16* __restrict__ zAB, // [N][8*768]
    int D4) {
    __shared__ float alds[MAXD * 8];
    __shared__ float mh[8], dh[8];
    int n = blockIdx.x;
    int s = row_ofs[n], t = row_ofs[n + 1];
    int d = t - s;
    int tid = threadIdx.x;
    bool big = d > MAXD;
    if (!big) {
        int eh = tid & 7, ei = tid >> 3;  // ei in 0..23
        float adn = ad1[n * 8 + eh];
        for (int base = 0; base < d; base += 24) {
            int j = base + ei;
            if (j < d) {
                int sn = sperm[s + j];
                float v = as1[sn * 8 + eh] + adn;
                v = v > 0.f ? v : 0.2f * v;
                alds[j * 8 + eh] = v;
            }
        }
        __syncthreads();
        if (tid < 8) {
            float m = -INFINITY;
            for (int j = 0; j < d; ++j) m = fmaxf(m, alds[j * 8 + tid]);
            float den = 0.f;
            for (int j = 0; j < d; ++j) den += __expf(alds[j * 8 + tid] - m);
            mh[tid] = m; dh[tid] = 1.f / (den + 1e-16f);
        }
        __syncthreads();
        for (int base = 0; base < d; base += 24) {
            int j = base + ei;
            if (j < d) alds[j * 8 + eh] = __expf(alds[j * 8 + eh] - mh[eh]) * dh[eh];
        }
        __syncthreads();
    } else {
        if (tid < 8) {
            int hh = tid;
            float adn = ad1[n * 8 + hh];
            float m = -INFINITY;
            for (int j = s; j < t; ++j) {
                float v = as1[sperm[j] * 8 + hh] + adn;
                v = v > 0.f ? v : 0.2f * v;
                m = fmaxf(m, v);
            }
            float den = 0.f;
            for (int j = s; j < t; ++j) {
                float v = as1[sperm[j] * 8 + hh] + adn;
                v = v > 0.f ? v : 0.2f * v;
                den += __expf(v - m);
            }
            float inv = 1.f / (den + 1e-16f);
            for (int j = s; j < t; ++j) {
                int e = perm[j];
                float v = as1[sperm[j] * 8 + hh] + adn;
                v = v > 0.f ? v : 0.2f * v;
                e1g[(size_t)e * 8 + hh] = __expf(v - m) * inv;
            }
        }
        __syncthreads();
    }

    // aggregation: thread j handles bf16x4 column j for all 8 heads.
    // 2-wide edge loop; gather address chain is now sperm->row (one level shorter).
    int j = tid;
    float4 acc[8];
    #pragma unroll
    for (int h = 0; h < 8; ++h) acc[h] = make_float4(0.f, 0.f, 0.f, 0.f);
    int k = s;
    if (!big) {
        for (; k + 1 < t; k += 2) {
            int n0 = sperm[k], n1 = sperm[k + 1];
            ushort4 u0 = xb4[(size_t)n0 * D4 + j];
            ushort4 u1 = xb4[(size_t)n1 * D4 + j];
            float4 v0 = make_float4(bfu(u0.x), bfu(u0.y), bfu(u0.z), bfu(u0.w));
            float4 v1 = make_float4(bfu(u1.x), bfu(u1.y), bfu(u1.z), bfu(u1.w));
            const float* a0 = &alds[(k - s) * 8];
            const float* a1 = &alds[(k + 1 - s) * 8];
            #pragma unroll
            for (int h = 0; h < 8; ++h) {
                float a = a0[h], b = a1[h];
                acc[h].x += a * v0.x + b * v1.x;
                acc[h].y += a * v0.y + b * v1.y;
                acc[h].z += a * v0.z + b * v1.z;
                acc[h].w += a * v0.w + b * v1.w;
            }
        }
        if (k < t) {
            int n0 = sperm[k];
            ushort4 u0 = xb4[(size_t)n0 * D4 + j];
            float4 v0 = make_float4(bfu(u0.x), bfu(u0.y), bfu(u0.z), bfu(u0.w));
            const float* a0 = &alds[(k - s) * 8];
            #pragma unroll
            for (int h = 0; h < 8; ++h) {
                float a = a0[h];
                acc[h].x += a * v0.x; acc[h].y += a * v0.y;
                acc[h].z += a * v0.z; acc[h].w += a * v0.w;
            }
        }
    } else {
        for (; k < t; ++k) {
            int e0 = perm[k];
            int n0 = sperm[k];
            ushort4 u0 = xb4[(size_t)n0 * D4 + j];
            float4 v0 = make_float4(bfu(u0.x), bfu(u0.y), bfu(u0.z), bfu(u0.w));
            const float* a0 = &e1g[(size_t)e0 * 8];
            #pragma unroll
            for (int h = 0; h < 8; ++h) {
                float a = a0[h];
                acc[h].x += a * v0.x; acc[h].y += a * v0.y;
                acc[h].z += a * v0.z; acc[h].w += a * v0.w;
            }
        }
    }
    int D = D4 * 4;
    #pragma unroll
    for (int h = 0; h < 8; ++h) {
        size_t o = (size_t)n * 8 * D + (size_t)h * D + j * 4;
        ushort4 st;
        st.x = bf16_bits(acc[h].x); st.y = bf16_bits(acc[h].y);
        st.z = bf16_bits(acc[h].z); st.w = bf16_bits(acc[h].w);
        *reinterpret_cast<ushort4*>(&zAB[o]) = st;
    }
}

// ---------------- FUSED: layer-2 softmax (H=1) + output aggregation (+bias) ----------------
__global__ __launch_bounds__(192) void out_fused_kernel(
    const ushort4* __restrict__ featb,  // h2b [N][192] bf16 (gather-halved)
    const float* __restrict__ as2,      // [N]
    const float* __restrict__ ad2,      // [N]
    const int* __restrict__ row_ofs,
    const int* __restrict__ perm,
    const int* __restrict__ sperm,
    float* __restrict__ e2g,            // [E] global fallback alpha
    const float4* __restrict__ bias4,
    float4* __restrict__ out4, int D4) {
    __shared__ float alds[MAXD];
    __shared__ float minv[2];
    int n = blockIdx.x;
    int s = row_ofs[n], t = row_ofs[n + 1];
    int d = t - s;
    int tid = threadIdx.x;
    bool big = d > MAXD;
    if (!big) {
        float adn = ad2[n];
        if (tid < d) {
            float v = as2[sperm[s + tid]] + adn;
            v = v > 0.f ? v : 0.2f * v;
            alds[tid] = v;
        }
        __syncthreads();
        if (tid == 0) {
            float m = -INFINITY;
            for (int j = 0; j < d; ++j) m = fmaxf(m, alds[j]);
            float den = 0.f;
            for (int j = 0; j < d; ++j) den += __expf(alds[j] - m);
            minv[0] = m; minv[1] = 1.f / (den + 1e-16f);
        }
        __syncthreads();
        if (tid < d) alds[tid] = __expf(alds[tid] - minv[0]) * minv[1];
        __syncthreads();
    } else {
        if (tid == 0) {
            float adn = ad2[n];
            float m = -INFINITY;
            for (int j = s; j < t; ++j) {
                float v = as2[sperm[j]] + adn;
                v = v > 0.f ? v : 0.2f * v;
                m = fmaxf(m, v);
            }
            float den = 0.f;
            for (int j = s; j < t; ++j) {
                float v = as2[sperm[j]] + adn;
                v = v > 0.f ? v : 0.2f * v;
                den += __expf(v - m);
            }
            float inv = 1.f / (den + 1e-16f);
            for (int j = s; j < t; ++j) {
                int e = perm[j];
                float v = as2[sperm[j]] + adn;
                v = v > 0.f ? v : 0.2f * v;
                e2g[e] = __expf(v - m) * inv;
            }
        }
        __syncthreads();
    }

    int j = tid;
    float4 acc = make_float4(0.f, 0.f, 0.f, 0.f);
    int k = s;
    if (!big) {
        for (; k + 1 < t; k += 2) {
            int n0 = sperm[k], n1 = sperm[k + 1];
            float a = alds[k - s];
            float b = alds[k + 1 - s];
            ushort4 u0 = featb[(size_t)n0 * D4 + j];
            ushort4 u1 = featb[(size_t)n1 * D4 + j];
            acc.x += a * bfu(u0.x) + b * bfu(u1.x);
            acc.y += a * bfu(u0.y) + b * bfu(u1.y);
            acc.z += a * bfu(u0.z) + b * bfu(u1.z);
            acc.w += a * bfu(u0.w) + b * bfu(u1.w);
        }
        if (k < t) {
            int n0 = sperm[k];
            float a = alds[k - s];
            ushort4 u0 = featb[(size_t)n0 * D4 + j];
            acc.x += a * bfu(u0.x); acc.y += a * bfu(u0.y);
            acc.z += a * bfu(u0.z); acc.w += a * bfu(u0.w);
        }
    } else {
        for (; k < t; ++k) {
            int e0 = perm[k];
            int n0 = sperm[k];
            float a = e2g[e0];
            ushort4 u0 = featb[(size_t)n0 * D4 + j];
            acc.x += a * bfu(u0.x); acc.y += a * bfu(u0.y);
            acc.z += a * bfu(u0.z); acc.w += a * bfu(u0.w);
        }
    }
    float4 b = bias4[j];
    acc.x += b.x; acc.y += b.y; acc.z += b.z; acc.w += b.w;
    out4[(size_t)n * D4 + j] = acc;
}

// ---------------- fused: h2 = p0+p1 (split-K S=2, bf16 partials) ; as2/ad2 dots ----------------
__global__ __launch_bounds__(192) void reduce_dot_kernel(
    const ushort4* __restrict__ parts,  // [2][N][192] bf16x4
    const float4* __restrict__ as_w, const float4* __restrict__ ad_w,
    ushort4* __restrict__ h2b,          // [N][192] bf16 out
    float* __restrict__ as_out, float* __restrict__ ad_out, int NC4) {
    int n = blockIdx.x;
    int j = threadIdx.x;
    size_t idx = (size_t)n * 192 + j;
    ushort4 q0 = parts[idx];
    ushort4 q1 = parts[(size_t)NC4 + idx];
    float4 a;
    a.x = bfu(q0.x) + bfu(q1.x);
    a.y = bfu(q0.y) + bfu(q1.y);
    a.z = bfu(q0.z) + bfu(q1.z);
    a.w = bfu(q0.w) + bfu(q1.w);
    ushort4 st;
    st.x = bf16_bits(a.x); st.y = bf16_bits(a.y);
    st.z = bf16_bits(a.z); st.w = bf16_bits(a.w);
    h2b[idx] = st;
    float4 ws = as_w[j], wd = ad_w[j];
    float ss = a.x * ws.x + a.y * ws.y + a.z * ws.z + a.w * ws.w;
    float sd = a.x * wd.x + a.y * wd.y + a.z * wd.z + a.w * wd.w;
    #pragma unroll
    for (int off = 32; off > 0; off >>= 1) {
        ss += __shfl_down(ss, off, 64);
        sd += __shfl_down(sd, off, 64);
    }
    __shared__ float red_s[3], red_d[3];
    int wv = j >> 6, lane = j & 63;
    if (lane == 0) { red_s[wv] = ss; red_d[wv] = sd; }
    __syncthreads();
    if (j == 0) {
        as_out[n] = red_s[0] + red_s[1] + red_s[2];
        ad_out[n] = red_d[0] + red_d[1] + red_d[2];
    }
}

// ---------------- shared GEMM machinery ----------------
__device__ inline void gload_lds16(const void* g, void* l) {
    __builtin_amdgcn_global_load_lds((const __attribute__((address_space(1))) unsigned int*)g,
                                     (__attribute__((address_space(3))) unsigned int*)l, 16, 0, 0);
}

#define FENCE() asm volatile("" ::: "memory")
#define BAR() do { FENCE(); __builtin_amdgcn_s_barrier(); FENCE(); } while (0)
#define WAIT_LGKM() asm volatile("s_waitcnt lgkmcnt(0)" ::: "memory")
#define WAIT_VM0() asm volatile("s_waitcnt vmcnt(0)" ::: "memory")

// ---------------- bf16 MFMA GEMM, 256x192 tile, BK=64, 2-phase (serves BOTH GEMMs) ----------------
#define SA192(b, kt) do { \
    _Pragma("unroll") for (int q = 0; q < 4; ++q) \
        gload_lds16(gA0 + (size_t)q * lstrA + (size_t)(kt) * 64, dA + (b) * 16384 + q * 4096); \
} while (0)

#define SB192(b, kt) do { \
    _Pragma("unroll") for (int q = 0; q < 3; ++q) \
        gload_lds16(gB0 + (size_t)q * lstrB + (size_t)(kt) * 64, dB + (b) * 12288 + q * 4096); \
} while (0)

#define LA192(b, MQ) do { \
    const short* _p = Asb + (b) * 16384 + arb + (MQ) * (128 * 64); \
    _Pragma("unroll") for (int mi = 0; mi < 4; ++mi) { \
        af[mi][0] = *(const s16x8*)(_p + mi * (16 * 64) + csw0); \
        af[mi][1] = *(const s16x8*)(_p + mi * (16 * 64) + csw1); \
    } \
} while (0)

#define LB192(b) do { \
    const short* _p = Bsb + (b) * 12288 + brb; \
    _Pragma("unroll") for (int ni = 0; ni < 3; ++ni) { \
        bfr[ni][0] = *(const s16x8*)(_p + ni * (16 * 64) + csw0); \
        bfr[ni][1] = *(const s16x8*)(_p + ni * (16 * 64) + csw1); \
    } \
} while (0)

#define MM192(MQ) do { \
    __builtin_amdgcn_s_setprio(1); \
    _Pragma("unroll") for (int ks = 0; ks < 2; ++ks) \
        _Pragma("unroll") for (int mi = 0; mi < 4; ++mi) \
            _Pragma("unroll") for (int ni = 0; ni < 3; ++ni) \
                acc[MQ][mi][ni] = __builtin_amdgcn_mfma_f32_16x16x32_bf16( \
                    af[mi][ks], bfr[ni][ks], acc[MQ][mi][ni], 0, 0, 0); \
    __builtin_amdgcn_s_setprio(0); \
} while (0)

__global__ __launch_bounds__(512, 2) void gemm192_kernel(
    const __hip_bfloat16* __restrict__ A,   // [M][lda]
    const __hip_bfloat16* __restrict__ BT,  // [N][ldb]
    int lda, int ldb, int ldc,
    int K, int kofs_per_z,
    const float* __restrict__ bias,
    __hip_bfloat16* __restrict__ Cb,        // bf16 out
    int flags,                              // 1 = elu
    long bsA, long bsBT, long bsC, long bsBias,
    int GX, int GY) {
    extern __shared__ __align__(16) short lds[];
    short* Asb = lds;            // [2][256][64] = 32768 shorts
    short* Bsb = lds + 32768;    // [2][192][64] = 24576 shorts

    int lin = blockIdx.x;
    int xcd = lin & 7;
    int u = lin >> 3;
    int bx = u % GX;
    int cg = u / GX;
    int cc = cg * 8 + xcd;
    int by = cc % GY;
    int bz = cc / GY;

    int kofs = bz * kofs_per_z;
    A += (size_t)bz * bsA;
    BT += (size_t)bz * bsBT;
    Cb += (size_t)bz * bsC;
    if (bias) bias += (size_t)bz * bsBias;

    int tid = threadIdx.x;
    int lane = tid & 63;
    int wid = tid >> 6;
    int wm = wid >> 2;      // 0..1
    int wn = wid & 3;       // 0..3
    int ml = lane & 15;
    int g  = lane >> 4;

    int row0 = by * 256;
    int col0 = bx * 192;

    int sr = tid >> 3;
    int scl = (tid & 7) ^ (sr & 7);
    const __hip_bfloat16* gA0 = A + (size_t)(row0 + sr) * lda + kofs + scl * 8;
    const __hip_bfloat16* gB0 = BT + (size_t)(col0 + sr) * ldb + kofs + scl * 8;
    size_t lstrA = (size_t)64 * lda;
    size_t lstrB = (size_t)64 * ldb;
    short* dA = Asb + tid * 8;
    short* dB = Bsb + tid * 8;

    int arb = (wm * 64 + ml) * 64;
    int brb = (wn * 48 + ml) * 64;
    int csw0 = ((g) ^ (ml & 7)) * 8;
    int csw1 = ((4 + g) ^ (ml & 7)) * 8;

    f32x4 acc[2][4][3];
    #pragma unroll
    for (int a0 = 0; a0 < 2; ++a0)
    #pragma unroll
    for (int b0 = 0; b0 < 4; ++b0)
    #pragma unroll
    for (int c0 = 0; c0 < 3; ++c0) acc[a0][b0][c0] = (f32x4){0.f, 0.f, 0.f, 0.f};

    s16x8 af[4][2];
    s16x8 bfr[3][2];

    int nkt = K / 64;

    SA192(0, 0); SB192(0, 0);
    WAIT_VM0();
    BAR();

    for (int t = 0; t < nkt; ++t) {
        int cur = t & 1;
        if (t + 1 < nkt) { SA192(cur ^ 1, t + 1); SB192(cur ^ 1, t + 1); }
        LA192(cur, 0); LB192(cur);
        WAIT_LGKM();
        MM192(0);
        LA192(cur, 1);
        WAIT_LGKM();
        MM192(1);
        WAIT_VM0();   // next buffer fully landed (stages had the whole iteration)
        BAR();
    }

    #pragma unroll
    for (int mq = 0; mq < 2; ++mq)
    #pragma unroll
    for (int mi = 0; mi < 4; ++mi)
    #pragma unroll
    for (int ni = 0; ni < 3; ++ni) {
        int row = row0 + mq * 128 + wm * 64 + mi * 16 + g * 4;
        int col = col0 + wn * 48 + ni * 16 + ml;
        float bv = bias ? bias[col] : 0.f;
        #pragma unroll
        for (int r = 0; r < 4; ++r) {
            float v = acc[mq][mi][ni][r] + bv;
            if (flags & 1) {
                float ev = __expf(v) - 1.f;  // elu (select, no branch)
                v = v > 0.f ? v : ev;
            }
            Cb[(size_t)(row + r) * ldc + col] = __float2bfloat16(v);
        }
    }
}

// ---------------- launch ----------------
extern "C" void kernel_launch(void* const* d_in, const int* in_sizes, int n_in,
                              void* d_out, int out_size, void* d_ws, size_t ws_size,
                              hipStream_t stream) {
    const int N = 8192, E = 65536, DIN = 768, C = 768, H1n = 8;
    const int HC1 = H1n * C;  // 6144

    const float* x    = (const float*)d_in[0];
    const float* W1   = (const float*)d_in[1];
    const float* a_s1 = (const float*)d_in[2];
    const float* a_d1 = (const float*)d_in[3];
    const float* b1   = (const float*)d_in[4];
    const float* W2   = (const float*)d_in[5];
    const float* a_s2 = (const float*)d_in[6];
    const float* a_d2 = (const float*)d_in[7];
    const float* b2   = (const float*)d_in[8];
    const int*   edges = (const int*)d_in[9];
    const int* src = edges;
    const int* dst = edges + E;

    // ---- workspace layout ----
    char* w = (char*)d_ws;
    auto alloc = [&](size_t bytes) -> void* {
        void* p = (void*)w;
        w += (bytes + 255) & ~(size_t)255;
        return p;
    };
    __hip_bfloat16* zAB = (__hip_bfloat16*)alloc((size_t)N * HC1 * 2);      // 100.7 MB
    __hip_bfloat16* o1  = (__hip_bfloat16*)alloc((size_t)N * HC1 * 2);      // 100.7 MB
    ushort4* xb4        = (ushort4*)alloc((size_t)N * DIN * 2);             // 12.6 MB
    ushort4* h2b        = (ushort4*)alloc((size_t)N * C * 2);               // 12.6 MB
    __hip_bfloat16* W1T = (__hip_bfloat16*)alloc((size_t)HC1 * DIN * 2);    // 9.4 MB
    __hip_bfloat16* W2T = (__hip_bfloat16*)alloc((size_t)C * HC1 * 2);      // 9.4 MB
    float* wv      = (float*)alloc((size_t)16 * DIN * 4);
    float* as1     = (float*)alloc((size_t)N * H1n * 4);
    float* ad1     = (float*)alloc((size_t)N * H1n * 4);
    float* e1      = (float*)alloc((size_t)E * H1n * 4);
    float* as2     = (float*)alloc((size_t)N * 4);
    float* ad2     = (float*)alloc((size_t)N * 4);
    float* e2      = (float*)alloc((size_t)E * 4);
    int*   counts  = (int*)alloc((size_t)N * 4);
    int*   cursor  = (int*)alloc((size_t)N * 4);
    int*   row_ofs = (int*)alloc((size_t)(N + 1) * 4);
    int*   perm    = (int*)alloc((size_t)E * 4);
    int*   sperm   = (int*)alloc((size_t)E * 4);

    // split-K bf16 partials (S=2) alias zAB (dead after GEMM1): 25 MB << 100 MB
    __hip_bfloat16* partials = zAB;

    (void)hipFuncSetAttribute((const void*)gemm192_kernel,
                              hipFuncAttributeMaxDynamicSharedMemorySize, 131072);

    // ---- merged preprocessing: zero + W1/W2 transpose + wvec (one launch) ----
    prep_kernel<<<10784, 256, 0, stream>>>(W1, W2, W1T, W2T, a_s1, a_d1,
                                           wv, wv + 8 * DIN, counts, cursor,
                                           DIN, H1n, C, N);

    // ---- alpha16 (+ merged hist range: blocks [2048,2304)) ----
    alpha16_kernel<<<2304, 256, 0, stream>>>((const float4*)x, wv, as1, ad1, xb4,
                                             dst, counts, E);

    // ---- CSR by dst: scan + scatter (+sperm pre-gather) ----
    scan_kernel<<<1, SCAN_T, 0, stream>>>(counts, row_ofs, N);
    scatter_kernel<<<(E + 255) / 256, 256, 0, stream>>>(dst, src, row_ofs, cursor,
                                                        perm, sperm, E);

    // ---- fused softmax + 8-head aggregation: xb -> zAB (bf16) ----
    agg8_fused_kernel<<<N, 192, 0, stream>>>(xb4, as1, ad1, row_ofs, perm, sperm,
                                             e1, zAB, DIN / 4);

    // ---- GEMM1: all 8 heads; o1 = ELU(z @ W1 + b1); 4x32x8 = 1024 blocks ----
    {
        int GX = C / 192, GY = N / 256;  // 4 x 32, GZ = 8 heads
        gemm192_kernel<<<GX * GY * H1n, 512, 131072, stream>>>(
            zAB, W1T,
            HC1, DIN, HC1,
            DIN, /*kofs_per_z=*/0,
            b1, o1, /*flags=*/1,
            /*bsA=*/C, /*bsBT=*/(long)C * DIN, /*bsC=*/C, /*bsBias=*/C,
            GX, GY);
    }
    // ---- GEMM2: K=6144 split-K S=2 into bf16 partials; 4x32x2 = 256 blocks ----
    {
        int GX = C / 192, GY = N / 256;  // 4 x 32, GZ = 2
        int Kslice = HC1 / 2;            // 3072 -> 48 K-tiles/block
        gemm192_kernel<<<GX * GY * 2, 512, 131072, stream>>>(
            o1, W2T,
            HC1, HC1, C,
            Kslice, /*kofs_per_z=*/Kslice,
            nullptr, partials, /*flags=*/0,
            /*bsA=*/0, /*bsBT=*/0, /*bsC=*/(long)N * C, /*bsBias=*/0,
            GX, GY);
    }

    // ---- fused: h2b = bf16(p0 + p1) ; as2/ad2 = h2 . a_s2 / a_d2 ----
    reduce_dot_kernel<<<N, 192, 0, stream>>>((const ushort4*)partials, (const float4*)a_s2,
                                             (const float4*)a_d2, h2b, as2, ad2, N * C / 4);

    // ---- fused layer-2 softmax + output aggregation ----
    out_fused_kernel<<<N, 192, 0, stream>>>(h2b, as2, ad2, row_ofs, perm, sperm,
                                            e2, (const float4*)b2, (float4*)d_out, C / 4);
}